// Round 2
// baseline (8950.205 us; speedup 1.0000x reference)
//
#include <hip/hip_runtime.h>

#define P_ 3
#define N_ 100000
#define M_ 30000
#define E_ 200000
#define C_ 5
#define FP_ 64
#define FN_ 32
#define PFP_ (P_*FP_)    // 192
#define FPFN_ (FP_+FN_)  // 96
#define ND_ 32           // nodes per decoder block

// ---------------- Stage 1: scatter planar features to nexus (concat layout) ----
// n_cat[m][c][p*FP + f] += x[p][src][c][f] over edges of plane p.
__global__ void k_scatter_up(const float* __restrict__ x,
                             const int* __restrict__ esrc,
                             const int* __restrict__ edst,
                             float* __restrict__ ncat) {
  int pe = blockIdx.x;            // p*E + e
  int t  = threadIdx.x;           // 0..319  (C*FP)
  int p  = pe / E_;
  int src = esrc[pe];
  int dst = edst[pe];
  int c = t >> 6, f = t & 63;
  float v = x[(((long long)p * N_ + src) * C_ + c) * FP_ + f];
  atomicAdd(&ncat[((long long)dst * C_ + c) * PFP_ + p * FP_ + f], v);
}

// ---------------- Stage 2: per-nexus 2-layer class MLP ------------------------
// block = 160 threads, one per (c,j). grid = M.
__global__ void k_nexus(const float* __restrict__ ncat,
                        const float* __restrict__ Wn1, const float* __restrict__ bn1,
                        const float* __restrict__ Wn2, const float* __restrict__ bn2,
                        float* __restrict__ nout) {
  __shared__ float sfeat[C_ * PFP_];   // 960 floats
  __shared__ float sh[C_ * FN_];       // 160 floats
  int m = blockIdx.x;
  int t = threadIdx.x;                 // 0..159
  for (int i = t; i < C_ * PFP_; i += C_ * FN_)
    sfeat[i] = ncat[(long long)m * C_ * PFP_ + i];
  __syncthreads();
  int c = t / FN_, j = t % FN_;
  const float* w = &Wn1[(c * FN_ + j) * PFP_];
  float acc = bn1[c * FN_ + j];
  #pragma unroll 8
  for (int i = 0; i < PFP_; ++i) acc += sfeat[c * PFP_ + i] * w[i];
  sh[t] = tanhf(acc);
  __syncthreads();
  const float* w2 = &Wn2[(c * FN_ + j) * FN_];
  float acc2 = bn2[c * FN_ + j];
  #pragma unroll
  for (int i = 0; i < FN_; ++i) acc2 += sh[c * FN_ + i] * w2[i];
  nout[(long long)m * (C_ * FN_) + t] = tanhf(acc2);
}

// ---------------- Stage 3: per-edge softmax gate + scatter to src -------------
// one thread per (p,e).
__global__ void k_edge(const float* __restrict__ x,
                       const float* __restrict__ nbuf,
                       const int* __restrict__ esrc, const int* __restrict__ edst,
                       const float* __restrict__ We, const float* __restrict__ be,
                       float* __restrict__ sbuf, float* __restrict__ cnt) {
  int idx = blockIdx.x * blockDim.x + threadIdx.x;
  if (idx >= P_ * E_) return;
  int p = idx / E_, e = idx % E_;
  int src = esrc[p * E_ + e];
  int dst = edst[p * E_ + e];
  const float* xi = &x[((long long)p * N_ + src) * C_ * FP_];
  const float* nj = &nbuf[(long long)dst * C_ * FN_];
  float logit[C_];
  #pragma unroll
  for (int c = 0; c < C_; ++c) {
    const float* w = &We[(p * C_ + c) * FPFN_];
    float a = be[p * C_ + c];
    #pragma unroll 8
    for (int i = 0; i < FP_; ++i) a += xi[c * FP_ + i] * w[i];
    #pragma unroll 8
    for (int i = 0; i < FN_; ++i) a += nj[c * FN_ + i] * w[FP_ + i];
    logit[c] = a;
  }
  float mx = logit[0];
  #pragma unroll
  for (int c = 1; c < C_; ++c) mx = fmaxf(mx, logit[c]);
  float se = 0.f;
  #pragma unroll
  for (int c = 0; c < C_; ++c) { logit[c] = expf(logit[c] - mx); se += logit[c]; }
  float inv = 1.f / se;
  float* sp = &sbuf[((long long)p * N_ + src) * C_ * FN_];
  #pragma unroll
  for (int c = 0; c < C_; ++c) {
    float wgt = logit[c] * inv;
    #pragma unroll 8
    for (int j = 0; j < FN_; ++j)
      atomicAdd(&sp[c * FN_ + j], wgt * nj[c * FN_ + j]);
  }
  atomicAdd(&cnt[p * N_ + src], 1.0f);
}

// ---------------- Stage 4: per-node 2-layer decoder ---------------------------
// block = 320 threads, one per (c,k); weights register-cached; ND_ nodes/block.
__global__ __launch_bounds__(320) void k_decode(
    const float* __restrict__ x, const float* __restrict__ sbuf,
    const float* __restrict__ cnt,
    const float* __restrict__ Wd1, const float* __restrict__ bd1,
    const float* __restrict__ Wd2, const float* __restrict__ bd2,
    float* __restrict__ out) {
  __shared__ float feat[C_][FPFN_];   // 5*96
  __shared__ float hsh[C_][FP_];      // 5*64
  int bp = blockIdx.x;
  int p  = bp / (N_ / ND_);
  int nb = bp % (N_ / ND_);
  int t = threadIdx.x;                // 0..319
  int c = t >> 6, k = t & 63;

  float w1[FPFN_], w2[FP_];
  const float* w1g = &Wd1[(((long long)p * C_ + c) * FP_ + k) * FPFN_];
  #pragma unroll
  for (int i = 0; i < FPFN_; ++i) w1[i] = w1g[i];
  float b1 = bd1[(p * C_ + c) * FP_ + k];
  const float* w2g = &Wd2[(((long long)p * C_ + c) * FP_ + k) * FP_];
  #pragma unroll
  for (int i = 0; i < FP_; ++i) w2[i] = w2g[i];
  float b2 = bd2[(p * C_ + c) * FP_ + k];

  for (int nd = 0; nd < ND_; ++nd) {
    int node = nb * ND_ + nd;
    // stage feat: x part (320 floats) + aggr part (160 floats)
    feat[c][k] = x[(((long long)p * N_ + node) * C_ + c) * FP_ + k];
    if (t < C_ * FN_) {
      int cc = t / FN_, j = t % FN_;
      float cn = cnt[p * N_ + node];
      float invc = 1.0f / fmaxf(cn, 1.0f);
      feat[cc][FP_ + j] = sbuf[(((long long)p * N_ + node) * C_ + cc) * FN_ + j] * invc;
    }
    __syncthreads();
    float a = b1;
    #pragma unroll
    for (int i = 0; i < FPFN_; ++i) a += feat[c][i] * w1[i];
    hsh[c][k] = tanhf(a);
    __syncthreads();
    float o = b2;
    #pragma unroll
    for (int i = 0; i < FP_; ++i) o += hsh[c][i] * w2[i];
    out[(((long long)p * N_ + node) * C_ + c) * FP_ + k] = tanhf(o);
    __syncthreads();
  }
}

extern "C" void kernel_launch(void* const* d_in, const int* in_sizes, int n_in,
                              void* d_out, int out_size, void* d_ws, size_t ws_size,
                              hipStream_t stream) {
  const float* x   = (const float*)d_in[0];
  // d_in[1] = nexus: unused by the reference forward pass
  const int* esrc  = (const int*)d_in[2];
  const int* edst  = (const int*)d_in[3];
  const float* Wn1 = (const float*)d_in[4];
  const float* bn1 = (const float*)d_in[5];
  const float* Wn2 = (const float*)d_in[6];
  const float* bn2 = (const float*)d_in[7];
  const float* We  = (const float*)d_in[8];
  const float* be  = (const float*)d_in[9];
  const float* Wd1 = (const float*)d_in[10];
  const float* bd1 = (const float*)d_in[11];
  const float* Wd2 = (const float*)d_in[12];
  const float* bd2 = (const float*)d_in[13];
  float* out = (float*)d_out;
  float* ws  = (float*)d_ws;

  // workspace layout (floats):
  //   [0, 48,000,000)        bufA: n_cat (28.8M used) then reused as sbuf (48M)
  //   [48,000,000, 52,800,000)  n  (M*C*FN = 4.8M)
  //   [52,800,000, 53,100,000)  cnt (P*N = 0.3M)
  float* ncat = ws;
  float* sbuf = ws;
  float* nbuf = ws + 48000000;
  float* cnt  = ws + 52800000;

  hipMemsetAsync(ncat, 0, 115200000ull, stream);             // zero n_cat
  k_scatter_up<<<P_ * E_, C_ * FP_, 0, stream>>>(x, esrc, edst, ncat);
  k_nexus<<<M_, C_ * FN_, 0, stream>>>(ncat, Wn1, bn1, Wn2, bn2, nbuf);
  hipMemsetAsync(sbuf, 0, 192000000ull, stream);             // zero s
  hipMemsetAsync(cnt, 0, 1200000ull, stream);                // zero cnt
  k_edge<<<(P_ * E_ + 255) / 256, 256, 0, stream>>>(x, nbuf, esrc, edst, We, be, sbuf, cnt);
  k_decode<<<P_ * (N_ / ND_), 320, 0, stream>>>(x, sbuf, cnt, Wd1, bd1, Wd2, bd2, out);
}

// Round 3
// 3666.032 us; speedup vs baseline: 2.4414x; 2.4414x over previous
//
#include <hip/hip_runtime.h>
#include <hip/hip_fp16.h>

#define P_ 3
#define N_ 100000
#define M_ 30000
#define E_ 200000
#define C_ 5
#define FP_ 64
#define FN_ 32
#define PFP_ 192     // P*FP
#define FPFN_ 96     // FP+FN
#define ND_ 32       // nodes per decoder block
#define PE_ 600000   // P*E
#define PN_ 300000   // P*N
#define PM_ 90000    // P*M

__device__ __forceinline__ float fast_tanh(float v) {
  float x = fminf(fmaxf(v, -15.0f), 15.0f);
  float t = __expf(2.0f * x);
  return __fdividef(t - 1.0f, t + 1.0f);
}

// ====================== CSR build ======================
__global__ void k_count(const int* __restrict__ esrc, const int* __restrict__ edst,
                        int* __restrict__ cnt_src, int* __restrict__ cnt_dst) {
  int i = blockIdx.x * 256 + threadIdx.x;
  if (i >= PE_) return;
  int p = i / E_;
  atomicAdd(&cnt_src[p * N_ + esrc[i]], 1);
  atomicAdd(&cnt_dst[p * M_ + edst[i]], 1);
}

// 3-pass exclusive scan (1024 elems/block)
__global__ void k_scan1(const int* __restrict__ in, int* __restrict__ out,
                        int* __restrict__ aux, int n) {
  __shared__ int lds[256];
  int b = blockIdx.x, t = threadIdx.x;
  int base = b * 1024 + t * 4;
  int v0 = (base + 0 < n) ? in[base + 0] : 0;
  int v1 = (base + 1 < n) ? in[base + 1] : 0;
  int v2 = (base + 2 < n) ? in[base + 2] : 0;
  int v3 = (base + 3 < n) ? in[base + 3] : 0;
  lds[t] = v0 + v1 + v2 + v3;
  __syncthreads();
  for (int off = 1; off < 256; off <<= 1) {
    int xv = (t >= off) ? lds[t - off] : 0;
    __syncthreads();
    lds[t] += xv;
    __syncthreads();
  }
  if (t == 255) aux[b] = lds[255];
  int run = (t == 0) ? 0 : lds[t - 1];
  if (base + 0 < n) out[base + 0] = run; run += v0;
  if (base + 1 < n) out[base + 1] = run; run += v1;
  if (base + 2 < n) out[base + 2] = run; run += v2;
  if (base + 3 < n) out[base + 3] = run;
}

__global__ void k_scan2(int* __restrict__ aux, int nb, int* __restrict__ off_end) {
  __shared__ int lds[1024];
  int t = threadIdx.x;
  lds[t] = (t < nb) ? aux[t] : 0;
  __syncthreads();
  for (int off = 1; off < 1024; off <<= 1) {
    int xv = (t >= off) ? lds[t - off] : 0;
    __syncthreads();
    lds[t] += xv;
    __syncthreads();
  }
  if (t < nb) aux[t] = (t == 0) ? 0 : lds[t - 1];
  if (t == 0) off_end[0] = lds[nb - 1];
}

__global__ void k_scan3(int* __restrict__ out, const int* __restrict__ aux, int n) {
  int i = blockIdx.x * 256 + threadIdx.x;
  if (i < n) out[i] += aux[i >> 10];
}

__global__ void k_fill(const int* __restrict__ esrc, const int* __restrict__ edst,
                       int* __restrict__ cur_src, int* __restrict__ cur_dst,
                       int* __restrict__ list_src, int* __restrict__ list_dst) {
  int i = blockIdx.x * 256 + threadIdx.x;
  if (i >= PE_) return;
  int p = i / E_;
  int s = esrc[i], d = edst[i];
  int ps = atomicAdd(&cur_src[p * N_ + s], 1);
  list_src[ps] = d;
  int pd = atomicAdd(&cur_dst[p * M_ + d], 1);
  list_dst[pd] = s;
}

// ====================== xdot: per-node x part of edge logit ======================
// xdot[pn*C + c] = dot(We[p,c,0:64], x[pn, c, :])
__global__ void k_xdot(const float* __restrict__ x, const float* __restrict__ We,
                       float* __restrict__ xdot) {
  int t = threadIdx.x;
  int pn = blockIdx.x * 4 + (t >> 6);
  if (pn >= PN_) return;
  int lane = t & 63;
  int p = pn / N_;
  const float* row = &x[(long long)pn * (C_ * FP_)];
  #pragma unroll
  for (int c = 0; c < C_; ++c) {
    float v = row[c * FP_ + lane] * We[(p * C_ + c) * FPFN_ + lane];
    #pragma unroll
    for (int off = 32; off > 0; off >>= 1) v += __shfl_down(v, off);
    if (lane == 0) xdot[pn * C_ + c] = v;
  }
}

// ====================== fused nexus: gather + 2-layer MLP + ndot ======================
__global__ __launch_bounds__(320) void k_nexus(
    const float* __restrict__ x,
    const int* __restrict__ off_dst, const int* __restrict__ list_dst,
    const float* __restrict__ Wn1, const float* __restrict__ bn1,
    const float* __restrict__ Wn2, const float* __restrict__ bn2,
    const float* __restrict__ We,
    float* __restrict__ nout, float* __restrict__ ndot) {
  __shared__ __align__(16) float sfeat[C_][PFP_];  // [c][p*64+k]
  __shared__ __align__(16) float sh1[C_][FN_];
  __shared__ __align__(16) float sh2[C_][FN_];
  int m = blockIdx.x;
  int t = threadIdx.x;               // 0..319 = c*64+k
  int c = t >> 6, k = t & 63;

  float acc[P_];
  #pragma unroll
  for (int p = 0; p < P_; ++p) {
    int o0 = off_dst[p * M_ + m];
    int o1 = off_dst[p * M_ + m + 1];
    float a = 0.f;
    for (int e = o0; e < o1; ++e) {
      int src = list_dst[e];
      a += x[(long long)(p * N_ + src) * (C_ * FP_) + t];
    }
    acc[p] = a;
  }
  #pragma unroll
  for (int p = 0; p < P_; ++p) sfeat[c][p * FP_ + k] = acc[p];
  __syncthreads();

  if (t < C_ * FN_) {
    int cc = t >> 5, j = t & 31;
    const float4* f4 = (const float4*)&sfeat[cc][0];
    const float4* w4 = (const float4*)&Wn1[(cc * FN_ + j) * PFP_];
    float a = bn1[cc * FN_ + j];
    #pragma unroll
    for (int i = 0; i < PFP_ / 4; ++i) {
      float4 f = f4[i], w = w4[i];
      a += f.x * w.x + f.y * w.y + f.z * w.z + f.w * w.w;
    }
    sh1[cc][j] = fast_tanh(a);
  }
  __syncthreads();
  if (t < C_ * FN_) {
    int cc = t >> 5, j = t & 31;
    const float4* f4 = (const float4*)&sh1[cc][0];
    const float4* w4 = (const float4*)&Wn2[(cc * FN_ + j) * FN_];
    float a = bn2[cc * FN_ + j];
    #pragma unroll
    for (int i = 0; i < FN_ / 4; ++i) {
      float4 f = f4[i], w = w4[i];
      a += f.x * w.x + f.y * w.y + f.z * w.z + f.w * w.w;
    }
    float nv = fast_tanh(a);
    sh2[cc][j] = nv;
    nout[(long long)m * (C_ * FN_) + t] = nv;
  }
  __syncthreads();
  if (t < P_ * C_) {                 // ndot[p][m][c] = We[p,c,64:96] . n[m,c,:]
    int p = t / C_, cc = t % C_;
    const float* w = &We[(p * C_ + cc) * FPFN_ + FP_];
    float a = 0.f;
    #pragma unroll
    for (int j = 0; j < FN_; ++j) a += sh2[cc][j] * w[j];
    ndot[(long long)(p * M_ + m) * C_ + cc] = a;
  }
}

// ====================== aggr: softmax-gated mean over src-CSR ======================
// one wave per (p,n); lanes: c0=lane>>5, j=lane&31 -> covers rows [c][j]
__global__ void k_aggr(const float* __restrict__ nout,
                       const int* __restrict__ off_src, const int* __restrict__ list_src,
                       const float* __restrict__ xdot, const float* __restrict__ ndot,
                       const float* __restrict__ be,
                       __half* __restrict__ aggr) {
  int t = threadIdx.x;
  int pn = blockIdx.x * 4 + (t >> 6);
  if (pn >= PN_) return;
  int lane = t & 63;
  int p = pn / N_;
  int o0 = off_src[pn], o1 = off_src[pn + 1];
  float base_c[C_];
  #pragma unroll
  for (int c = 0; c < C_; ++c) base_c[c] = xdot[pn * C_ + c] + be[p * C_ + c];

  float a0 = 0.f, a1 = 0.f, a2 = 0.f;
  for (int e = o0; e < o1; ++e) {
    int dst = list_src[e];
    const float* nr = &nout[(long long)dst * (C_ * FN_)];
    const float* nd = &ndot[(long long)(p * M_ + dst) * C_];
    float l[C_];
    #pragma unroll
    for (int c = 0; c < C_; ++c) l[c] = base_c[c] + nd[c];
    float mx = fmaxf(fmaxf(fmaxf(l[0], l[1]), fmaxf(l[2], l[3])), l[4]);
    float s = 0.f;
    #pragma unroll
    for (int c = 0; c < C_; ++c) { l[c] = __expf(l[c] - mx); s += l[c]; }
    float inv = __fdividef(1.0f, s);
    float wA = ((lane & 32) ? l[1] : l[0]) * inv;
    float wB = ((lane & 32) ? l[3] : l[2]) * inv;
    a0 += wA * nr[lane];
    a1 += wB * nr[64 + lane];
    if (lane < 32) a2 += l[4] * inv * nr[128 + lane];
  }
  float invd = __fdividef(1.0f, fmaxf((float)(o1 - o0), 1.0f));
  __half* out = &aggr[(long long)pn * (C_ * FN_)];
  out[lane]      = __float2half(a0 * invd);
  out[64 + lane] = __float2half(a1 * invd);
  if (lane < 32) out[128 + lane] = __float2half(a2 * invd);
}

// ====================== decoder ======================
__global__ __launch_bounds__(320) void k_decode(
    const float* __restrict__ x, const __half* __restrict__ aggr,
    const float* __restrict__ Wd1, const float* __restrict__ bd1,
    const float* __restrict__ Wd2, const float* __restrict__ bd2,
    float* __restrict__ out) {
  __shared__ __align__(16) float feat[C_][FPFN_];
  __shared__ __align__(16) float hsh[C_][FP_];
  int bp = blockIdx.x;
  int p  = bp / (N_ / ND_);
  int nb = bp % (N_ / ND_);
  int t = threadIdx.x;               // 0..319
  int c = t >> 6, k = t & 63;

  float w1[FPFN_], w2[FP_];
  const float* w1g = &Wd1[(((long long)p * C_ + c) * FP_ + k) * FPFN_];
  #pragma unroll
  for (int i = 0; i < FPFN_; ++i) w1[i] = w1g[i];
  float b1 = bd1[(p * C_ + c) * FP_ + k];
  const float* w2g = &Wd2[(((long long)p * C_ + c) * FP_ + k) * FP_];
  #pragma unroll
  for (int i = 0; i < FP_; ++i) w2[i] = w2g[i];
  float b2 = bd2[(p * C_ + c) * FP_ + k];

  for (int nd = 0; nd < ND_; ++nd) {
    int node = nb * ND_ + nd;
    long long row = (long long)(p * N_ + node);
    feat[c][k] = x[row * (C_ * FP_) + t];
    if (t < C_ * FN_) {
      int cc = t >> 5, j = t & 31;
      feat[cc][FP_ + j] = __half2float(aggr[row * (C_ * FN_) + t]);
    }
    __syncthreads();
    const float4* f4 = (const float4*)&feat[c][0];
    float a = b1;
    #pragma unroll
    for (int i = 0; i < FPFN_ / 4; ++i) {
      float4 f = f4[i];
      a += f.x * w1[4*i] + f.y * w1[4*i+1] + f.z * w1[4*i+2] + f.w * w1[4*i+3];
    }
    hsh[c][k] = fast_tanh(a);
    __syncthreads();
    const float4* h4 = (const float4*)&hsh[c][0];
    float o = b2;
    #pragma unroll
    for (int i = 0; i < FP_ / 4; ++i) {
      float4 f = h4[i];
      o += f.x * w2[4*i] + f.y * w2[4*i+1] + f.z * w2[4*i+2] + f.w * w2[4*i+3];
    }
    out[row * (C_ * FP_) + t] = fast_tanh(o);
    __syncthreads();
  }
}

// ====================== launch ======================
// workspace layout (4-byte words):
#define WS_AGGR  0ll          // half[48,000,000] = 24,000,000 words
#define WS_NOUT  24000000ll   // float[4,800,000]
#define WS_XDOT  28800000ll   // float[1,500,000]
#define WS_NDOT  30300000ll   // float[450,000]
#define WS_OFFS  30750000ll   // int[300,001]
#define WS_OFFD  31050001ll   // int[90,001]
#define WS_CURS  31140002ll   // int[300,000] (counts then cursors)
#define WS_CURD  31440002ll   // int[90,000]
#define WS_LISTS 31530002ll   // int[600,000]
#define WS_LISTD 32130002ll   // int[600,000]
#define WS_AUX1  32730002ll   // int[512]
#define WS_AUX2  32730514ll   // int[512]

extern "C" void kernel_launch(void* const* d_in, const int* in_sizes, int n_in,
                              void* d_out, int out_size, void* d_ws, size_t ws_size,
                              hipStream_t stream) {
  const float* x   = (const float*)d_in[0];
  const int* esrc  = (const int*)d_in[2];
  const int* edst  = (const int*)d_in[3];
  const float* Wn1 = (const float*)d_in[4];
  const float* bn1 = (const float*)d_in[5];
  const float* Wn2 = (const float*)d_in[6];
  const float* bn2 = (const float*)d_in[7];
  const float* We  = (const float*)d_in[8];
  const float* be  = (const float*)d_in[9];
  const float* Wd1 = (const float*)d_in[10];
  const float* bd1 = (const float*)d_in[11];
  const float* Wd2 = (const float*)d_in[12];
  const float* bd2 = (const float*)d_in[13];
  float* out = (float*)d_out;

  float* wsf = (float*)d_ws;
  int*   wsi = (int*)d_ws;
  __half* aggr = (__half*)d_ws;
  float* nout = wsf + WS_NOUT;
  float* xdot = wsf + WS_XDOT;
  float* ndot = wsf + WS_NDOT;
  int* off_src = wsi + WS_OFFS;
  int* off_dst = wsi + WS_OFFD;
  int* cur_src = wsi + WS_CURS;
  int* cur_dst = wsi + WS_CURD;
  int* list_src = wsi + WS_LISTS;
  int* list_dst = wsi + WS_LISTD;
  int* aux1 = wsi + WS_AUX1;
  int* aux2 = wsi + WS_AUX2;

  // ---- CSR build ----
  hipMemsetAsync(cur_src, 0, PN_ * sizeof(int), stream);
  hipMemsetAsync(cur_dst, 0, PM_ * sizeof(int), stream);
  k_count<<<(PE_ + 255) / 256, 256, 0, stream>>>(esrc, edst, cur_src, cur_dst);
  {
    int nb_s = (PN_ + 1023) / 1024;   // 293
    int nb_d = (PM_ + 1023) / 1024;   // 88
    k_scan1<<<nb_s, 256, 0, stream>>>(cur_src, off_src, aux1, PN_);
    k_scan1<<<nb_d, 256, 0, stream>>>(cur_dst, off_dst, aux2, PM_);
    k_scan2<<<1, 1024, 0, stream>>>(aux1, nb_s, off_src + PN_);
    k_scan2<<<1, 1024, 0, stream>>>(aux2, nb_d, off_dst + PM_);
    k_scan3<<<(PN_ + 255) / 256, 256, 0, stream>>>(off_src, aux1, PN_);
    k_scan3<<<(PM_ + 255) / 256, 256, 0, stream>>>(off_dst, aux2, PM_);
  }
  hipMemcpyAsync(cur_src, off_src, PN_ * sizeof(int), hipMemcpyDeviceToDevice, stream);
  hipMemcpyAsync(cur_dst, off_dst, PM_ * sizeof(int), hipMemcpyDeviceToDevice, stream);
  k_fill<<<(PE_ + 255) / 256, 256, 0, stream>>>(esrc, edst, cur_src, cur_dst,
                                                list_src, list_dst);

  // ---- stages ----
  k_xdot<<<(PN_ + 3) / 4, 256, 0, stream>>>(x, We, xdot);
  k_nexus<<<M_, 320, 0, stream>>>(x, off_dst, list_dst, Wn1, bn1, Wn2, bn2, We,
                                  nout, ndot);
  k_aggr<<<(PN_ + 3) / 4, 256, 0, stream>>>(nout, off_src, list_src, xdot, ndot,
                                            be, aggr);
  k_decode<<<P_ * (N_ / ND_), 320, 0, stream>>>(x, aggr, Wd1, bd1, Wd2, bd2, out);
}

// Round 4
// 3221.588 us; speedup vs baseline: 2.7782x; 1.1380x over previous
//
#include <hip/hip_runtime.h>
#include <hip/hip_fp16.h>

#define P_ 3
#define N_ 100000
#define M_ 30000
#define E_ 200000
#define C_ 5
#define FP_ 64
#define FN_ 32
#define PFP_ 192     // P*FP
#define FPFN_ 96     // FP+FN
#define ND_ 32       // nodes per decoder block
#define PE_ 600000   // P*E
#define PN_ 300000   // P*N
#define PM_ 90000    // P*M

__device__ __forceinline__ float fast_tanh(float v) {
  float x = fminf(fmaxf(v, -15.0f), 15.0f);
  float t = __expf(2.0f * x);
  return __fdividef(t - 1.0f, t + 1.0f);
}

// ====================== CSR build ======================
__global__ void k_count(const int* __restrict__ esrc, const int* __restrict__ edst,
                        int* __restrict__ cnt_src, int* __restrict__ cnt_dst) {
  int i = blockIdx.x * 256 + threadIdx.x;
  if (i >= PE_) return;
  int p = i / E_;
  atomicAdd(&cnt_src[p * N_ + esrc[i]], 1);
  atomicAdd(&cnt_dst[p * M_ + edst[i]], 1);
}

// 3-pass exclusive scan (1024 elems/block)
__global__ void k_scan1(const int* __restrict__ in, int* __restrict__ out,
                        int* __restrict__ aux, int n) {
  __shared__ int lds[256];
  int b = blockIdx.x, t = threadIdx.x;
  int base = b * 1024 + t * 4;
  int v0 = (base + 0 < n) ? in[base + 0] : 0;
  int v1 = (base + 1 < n) ? in[base + 1] : 0;
  int v2 = (base + 2 < n) ? in[base + 2] : 0;
  int v3 = (base + 3 < n) ? in[base + 3] : 0;
  lds[t] = v0 + v1 + v2 + v3;
  __syncthreads();
  for (int off = 1; off < 256; off <<= 1) {
    int xv = (t >= off) ? lds[t - off] : 0;
    __syncthreads();
    lds[t] += xv;
    __syncthreads();
  }
  if (t == 255) aux[b] = lds[255];
  int run = (t == 0) ? 0 : lds[t - 1];
  if (base + 0 < n) out[base + 0] = run; run += v0;
  if (base + 1 < n) out[base + 1] = run; run += v1;
  if (base + 2 < n) out[base + 2] = run; run += v2;
  if (base + 3 < n) out[base + 3] = run;
}

__global__ void k_scan2(int* __restrict__ aux, int nb, int* __restrict__ off_end) {
  __shared__ int lds[1024];
  int t = threadIdx.x;
  lds[t] = (t < nb) ? aux[t] : 0;
  __syncthreads();
  for (int off = 1; off < 1024; off <<= 1) {
    int xv = (t >= off) ? lds[t - off] : 0;
    __syncthreads();
    lds[t] += xv;
    __syncthreads();
  }
  if (t < nb) aux[t] = (t == 0) ? 0 : lds[t - 1];
  if (t == 0) off_end[0] = lds[nb - 1];
}

__global__ void k_scan3(int* __restrict__ out, const int* __restrict__ aux, int n) {
  int i = blockIdx.x * 256 + threadIdx.x;
  if (i < n) out[i] += aux[i >> 10];
}

__global__ void k_fill(const int* __restrict__ esrc, const int* __restrict__ edst,
                       int* __restrict__ cur_src, int* __restrict__ cur_dst,
                       int* __restrict__ list_src, int* __restrict__ list_dst) {
  int i = blockIdx.x * 256 + threadIdx.x;
  if (i >= PE_) return;
  int p = i / E_;
  int s = esrc[i], d = edst[i];
  int ps = atomicAdd(&cur_src[p * N_ + s], 1);
  list_src[ps] = d;
  int pd = atomicAdd(&cur_dst[p * M_ + d], 1);
  list_dst[pd] = s;
}

// ====================== xdot: per-node x part of edge logit ======================
__global__ void k_xdot(const float* __restrict__ x, const float* __restrict__ We,
                       float* __restrict__ xdot) {
  int t = threadIdx.x;
  int pn = blockIdx.x * 4 + (t >> 6);
  if (pn >= PN_) return;
  int lane = t & 63;
  int p = pn / N_;
  const float* row = &x[(long long)pn * (C_ * FP_)];
  #pragma unroll
  for (int c = 0; c < C_; ++c) {
    float v = row[c * FP_ + lane] * We[(p * C_ + c) * FPFN_ + lane];
    #pragma unroll
    for (int off = 32; off > 0; off >>= 1) v += __shfl_down(v, off);
    if (lane == 0) xdot[pn * C_ + c] = v;
  }
}

// ====================== fused nexus: gather + 2-layer MLP + ndot ======================
__global__ __launch_bounds__(320) void k_nexus(
    const float* __restrict__ x,
    const int* __restrict__ off_dst, const int* __restrict__ list_dst,
    const float* __restrict__ Wn1, const float* __restrict__ bn1,
    const float* __restrict__ Wn2, const float* __restrict__ bn2,
    const float* __restrict__ We,
    float* __restrict__ nout, float* __restrict__ ndot) {
  __shared__ __align__(16) float sfeat[C_][PFP_];  // [c][p*64+k]
  __shared__ __align__(16) float sh1[C_][FN_];
  __shared__ __align__(16) float sh2[C_][FN_];
  int m = blockIdx.x;
  int t = threadIdx.x;               // 0..319 = c*64+k
  int c = t >> 6, k = t & 63;

  float acc[P_];
  #pragma unroll
  for (int p = 0; p < P_; ++p) {
    int o0 = off_dst[p * M_ + m];
    int o1 = off_dst[p * M_ + m + 1];
    float a = 0.f;
    for (int e = o0; e < o1; ++e) {
      int src = list_dst[e];
      a += x[(long long)(p * N_ + src) * (C_ * FP_) + t];
    }
    acc[p] = a;
  }
  #pragma unroll
  for (int p = 0; p < P_; ++p) sfeat[c][p * FP_ + k] = acc[p];
  __syncthreads();

  if (t < C_ * FN_) {
    int cc = t >> 5, j = t & 31;
    const float4* f4 = (const float4*)&sfeat[cc][0];
    const float4* w4 = (const float4*)&Wn1[(cc * FN_ + j) * PFP_];
    float a = bn1[cc * FN_ + j];
    #pragma unroll
    for (int i = 0; i < PFP_ / 4; ++i) {
      float4 f = f4[i], w = w4[i];
      a += f.x * w.x + f.y * w.y + f.z * w.z + f.w * w.w;
    }
    sh1[cc][j] = fast_tanh(a);
  }
  __syncthreads();
  if (t < C_ * FN_) {
    int cc = t >> 5, j = t & 31;
    const float4* f4 = (const float4*)&sh1[cc][0];
    const float4* w4 = (const float4*)&Wn2[(cc * FN_ + j) * FN_];
    float a = bn2[cc * FN_ + j];
    #pragma unroll
    for (int i = 0; i < FN_ / 4; ++i) {
      float4 f = f4[i], w = w4[i];
      a += f.x * w.x + f.y * w.y + f.z * w.z + f.w * w.w;
    }
    float nv = fast_tanh(a);
    sh2[cc][j] = nv;
    nout[(long long)m * (C_ * FN_) + t] = nv;
  }
  __syncthreads();
  if (t < P_ * C_) {                 // ndot[p][m][c] = We[p,c,64:96] . n[m,c,:]
    int p = t / C_, cc = t % C_;
    const float* w = &We[(p * C_ + cc) * FPFN_ + FP_];
    float a = 0.f;
    #pragma unroll
    for (int j = 0; j < FN_; ++j) a += sh2[cc][j] * w[j];
    ndot[(long long)(p * M_ + m) * C_ + cc] = a;
  }
}

// ====================== aggr: softmax-gated mean over src-CSR ======================
__global__ void k_aggr(const float* __restrict__ nout,
                       const int* __restrict__ off_src, const int* __restrict__ list_src,
                       const float* __restrict__ xdot, const float* __restrict__ ndot,
                       const float* __restrict__ be,
                       __half* __restrict__ aggr) {
  int t = threadIdx.x;
  int pn = blockIdx.x * 4 + (t >> 6);
  if (pn >= PN_) return;
  int lane = t & 63;
  int p = pn / N_;
  int o0 = off_src[pn], o1 = off_src[pn + 1];
  float base_c[C_];
  #pragma unroll
  for (int c = 0; c < C_; ++c) base_c[c] = xdot[pn * C_ + c] + be[p * C_ + c];

  float a0 = 0.f, a1 = 0.f, a2 = 0.f;
  for (int e = o0; e < o1; ++e) {
    int dst = list_src[e];
    const float* nr = &nout[(long long)dst * (C_ * FN_)];
    const float* nd = &ndot[(long long)(p * M_ + dst) * C_];
    float l[C_];
    #pragma unroll
    for (int c = 0; c < C_; ++c) l[c] = base_c[c] + nd[c];
    float mx = fmaxf(fmaxf(fmaxf(l[0], l[1]), fmaxf(l[2], l[3])), l[4]);
    float s = 0.f;
    #pragma unroll
    for (int c = 0; c < C_; ++c) { l[c] = __expf(l[c] - mx); s += l[c]; }
    float inv = __fdividef(1.0f, s);
    float wA = ((lane & 32) ? l[1] : l[0]) * inv;
    float wB = ((lane & 32) ? l[3] : l[2]) * inv;
    a0 += wA * nr[lane];
    a1 += wB * nr[64 + lane];
    if (lane < 32) a2 += l[4] * inv * nr[128 + lane];
  }
  float invd = __fdividef(1.0f, fmaxf((float)(o1 - o0), 1.0f));
  __half* out = &aggr[(long long)pn * (C_ * FN_)];
  out[lane]      = __float2half(a0 * invd);
  out[64 + lane] = __float2half(a1 * invd);
  if (lane < 32) out[128 + lane] = __float2half(a2 * invd);
}

// ====================== decoder layer 1 (no spill: only w1 in regs) ===========
// writes h = tanh(W1·feat + b1) into hbuf (= d_out, fp32)
__global__ __launch_bounds__(320, 2) void k_dec1(
    const float* __restrict__ x, const __half* __restrict__ aggr,
    const float* __restrict__ Wd1, const float* __restrict__ bd1,
    float* __restrict__ hbuf) {
  __shared__ __align__(16) float feat[C_][FPFN_];
  int bp = blockIdx.x;
  int p  = bp / (N_ / ND_);
  int nb = bp % (N_ / ND_);
  int t = threadIdx.x;               // 0..319
  int c = t >> 6, k = t & 63;

  float w1[FPFN_];
  const float* w1g = &Wd1[(((long long)p * C_ + c) * FP_ + k) * FPFN_];
  #pragma unroll
  for (int i = 0; i < FPFN_; ++i) w1[i] = w1g[i];
  float b1 = bd1[(p * C_ + c) * FP_ + k];

  for (int nd = 0; nd < ND_; ++nd) {
    long long row = (long long)(p * N_ + nb * ND_ + nd);
    feat[c][k] = x[row * (C_ * FP_) + t];
    if (t < C_ * FN_) {
      feat[t >> 5][FP_ + (t & 31)] = __half2float(aggr[row * (C_ * FN_) + t]);
    }
    __syncthreads();
    const float4* f4 = (const float4*)&feat[c][0];
    float a = b1;
    #pragma unroll
    for (int i = 0; i < FPFN_ / 4; ++i) {
      float4 f = f4[i];
      a += f.x * w1[4*i] + f.y * w1[4*i+1] + f.z * w1[4*i+2] + f.w * w1[4*i+3];
    }
    hbuf[row * (C_ * FP_) + t] = fast_tanh(a);
    __syncthreads();
  }
}

// ====================== decoder layer 2 (no spill: only w2 in regs) ===========
// in-place on io (= d_out): reads h rows to LDS, overwrites with tanh(W2·h + b2)
__global__ __launch_bounds__(320, 2) void k_dec2(
    const float* __restrict__ Wd2, const float* __restrict__ bd2,
    float* __restrict__ io) {
  __shared__ __align__(16) float hsh[C_][FP_];
  int bp = blockIdx.x;
  int p  = bp / (N_ / ND_);
  int nb = bp % (N_ / ND_);
  int t = threadIdx.x;               // 0..319
  int c = t >> 6, k = t & 63;

  float w2[FP_];
  const float* w2g = &Wd2[(((long long)p * C_ + c) * FP_ + k) * FP_];
  #pragma unroll
  for (int i = 0; i < FP_; ++i) w2[i] = w2g[i];
  float b2 = bd2[(p * C_ + c) * FP_ + k];

  for (int nd = 0; nd < ND_; ++nd) {
    long long row = (long long)(p * N_ + nb * ND_ + nd);
    hsh[c][k] = io[row * (C_ * FP_) + t];
    __syncthreads();
    const float4* h4 = (const float4*)&hsh[c][0];
    float o = b2;
    #pragma unroll
    for (int i = 0; i < FP_ / 4; ++i) {
      float4 f = h4[i];
      o += f.x * w2[4*i] + f.y * w2[4*i+1] + f.z * w2[4*i+2] + f.w * w2[4*i+3];
    }
    __syncthreads();   // all LDS reads done before anyone overwrites its source row
    io[row * (C_ * FP_) + t] = fast_tanh(o);
  }
}

// ====================== launch ======================
// workspace layout (4-byte words):
#define WS_AGGR  0ll          // half[48,000,000] = 24,000,000 words
#define WS_NOUT  24000000ll   // float[4,800,000]
#define WS_XDOT  28800000ll   // float[1,500,000]
#define WS_NDOT  30300000ll   // float[450,000]
#define WS_OFFS  30750000ll   // int[300,001]
#define WS_OFFD  31050001ll   // int[90,001]
#define WS_CURS  31140002ll   // int[300,000] (counts then cursors)
#define WS_CURD  31440002ll   // int[90,000]
#define WS_LISTS 31530002ll   // int[600,000]
#define WS_LISTD 32130002ll   // int[600,000]
#define WS_AUX1  32730002ll   // int[512]
#define WS_AUX2  32730514ll   // int[512]

extern "C" void kernel_launch(void* const* d_in, const int* in_sizes, int n_in,
                              void* d_out, int out_size, void* d_ws, size_t ws_size,
                              hipStream_t stream) {
  const float* x   = (const float*)d_in[0];
  const int* esrc  = (const int*)d_in[2];
  const int* edst  = (const int*)d_in[3];
  const float* Wn1 = (const float*)d_in[4];
  const float* bn1 = (const float*)d_in[5];
  const float* Wn2 = (const float*)d_in[6];
  const float* bn2 = (const float*)d_in[7];
  const float* We  = (const float*)d_in[8];
  const float* be  = (const float*)d_in[9];
  const float* Wd1 = (const float*)d_in[10];
  const float* bd1 = (const float*)d_in[11];
  const float* Wd2 = (const float*)d_in[12];
  const float* bd2 = (const float*)d_in[13];
  float* out = (float*)d_out;

  float* wsf = (float*)d_ws;
  int*   wsi = (int*)d_ws;
  __half* aggr = (__half*)d_ws;
  float* nout = wsf + WS_NOUT;
  float* xdot = wsf + WS_XDOT;
  float* ndot = wsf + WS_NDOT;
  int* off_src = wsi + WS_OFFS;
  int* off_dst = wsi + WS_OFFD;
  int* cur_src = wsi + WS_CURS;
  int* cur_dst = wsi + WS_CURD;
  int* list_src = wsi + WS_LISTS;
  int* list_dst = wsi + WS_LISTD;
  int* aux1 = wsi + WS_AUX1;
  int* aux2 = wsi + WS_AUX2;

  // ---- CSR build ----
  hipMemsetAsync(cur_src, 0, PN_ * sizeof(int), stream);
  hipMemsetAsync(cur_dst, 0, PM_ * sizeof(int), stream);
  k_count<<<(PE_ + 255) / 256, 256, 0, stream>>>(esrc, edst, cur_src, cur_dst);
  {
    int nb_s = (PN_ + 1023) / 1024;   // 293
    int nb_d = (PM_ + 1023) / 1024;   // 88
    k_scan1<<<nb_s, 256, 0, stream>>>(cur_src, off_src, aux1, PN_);
    k_scan1<<<nb_d, 256, 0, stream>>>(cur_dst, off_dst, aux2, PM_);
    k_scan2<<<1, 1024, 0, stream>>>(aux1, nb_s, off_src + PN_);
    k_scan2<<<1, 1024, 0, stream>>>(aux2, nb_d, off_dst + PM_);
    k_scan3<<<(PN_ + 255) / 256, 256, 0, stream>>>(off_src, aux1, PN_);
    k_scan3<<<(PM_ + 255) / 256, 256, 0, stream>>>(off_dst, aux2, PM_);
  }
  hipMemcpyAsync(cur_src, off_src, PN_ * sizeof(int), hipMemcpyDeviceToDevice, stream);
  hipMemcpyAsync(cur_dst, off_dst, PM_ * sizeof(int), hipMemcpyDeviceToDevice, stream);
  k_fill<<<(PE_ + 255) / 256, 256, 0, stream>>>(esrc, edst, cur_src, cur_dst,
                                                list_src, list_dst);

  // ---- stages ----
  k_xdot<<<(PN_ + 3) / 4, 256, 0, stream>>>(x, We, xdot);
  k_nexus<<<M_, 320, 0, stream>>>(x, off_dst, list_dst, Wn1, bn1, Wn2, bn2, We,
                                  nout, ndot);
  k_aggr<<<(PN_ + 3) / 4, 256, 0, stream>>>(nout, off_src, list_src, xdot, ndot,
                                            be, aggr);
  k_dec1<<<P_ * (N_ / ND_), 320, 0, stream>>>(x, aggr, Wd1, bd1, out);
  k_dec2<<<P_ * (N_ / ND_), 320, 0, stream>>>(Wd2, bd2, out);
}

// Round 5
// 1847.076 us; speedup vs baseline: 4.8456x; 1.7442x over previous
//
#include <hip/hip_runtime.h>
#include <hip/hip_fp16.h>

#define P_ 3
#define N_ 100000
#define M_ 30000
#define E_ 200000
#define C_ 5
#define FP_ 64
#define FN_ 32
#define PFP_ 192     // P*FP
#define FPFN_ 96     // FP+FN
#define PE_ 600000   // P*E
#define PN_ 300000   // P*N
#define PM_ 90000    // P*M
#define NT_ 64       // nodes per decoder tile
#define TILES_ ((N_ + NT_ - 1) / NT_)   // 1563

__device__ __forceinline__ float fast_tanh(float v) {
  float x = fminf(fmaxf(v, -15.0f), 15.0f);
  float t = __expf(2.0f * x);
  return __fdividef(t - 1.0f, t + 1.0f);
}

// ====================== CSR build ======================
__global__ void k_count(const int* __restrict__ esrc, const int* __restrict__ edst,
                        int* __restrict__ cnt_src, int* __restrict__ cnt_dst) {
  int i = blockIdx.x * 256 + threadIdx.x;
  if (i >= PE_) return;
  int p = i / E_;
  atomicAdd(&cnt_src[p * N_ + esrc[i]], 1);
  atomicAdd(&cnt_dst[p * M_ + edst[i]], 1);
}

// 3-pass exclusive scan (1024 elems/block)
__global__ void k_scan1(const int* __restrict__ in, int* __restrict__ out,
                        int* __restrict__ aux, int n) {
  __shared__ int lds[256];
  int b = blockIdx.x, t = threadIdx.x;
  int base = b * 1024 + t * 4;
  int v0 = (base + 0 < n) ? in[base + 0] : 0;
  int v1 = (base + 1 < n) ? in[base + 1] : 0;
  int v2 = (base + 2 < n) ? in[base + 2] : 0;
  int v3 = (base + 3 < n) ? in[base + 3] : 0;
  lds[t] = v0 + v1 + v2 + v3;
  __syncthreads();
  for (int off = 1; off < 256; off <<= 1) {
    int xv = (t >= off) ? lds[t - off] : 0;
    __syncthreads();
    lds[t] += xv;
    __syncthreads();
  }
  if (t == 255) aux[b] = lds[255];
  int run = (t == 0) ? 0 : lds[t - 1];
  if (base + 0 < n) out[base + 0] = run; run += v0;
  if (base + 1 < n) out[base + 1] = run; run += v1;
  if (base + 2 < n) out[base + 2] = run; run += v2;
  if (base + 3 < n) out[base + 3] = run;
}

__global__ void k_scan2(int* __restrict__ aux, int nb, int* __restrict__ off_end) {
  __shared__ int lds[1024];
  int t = threadIdx.x;
  lds[t] = (t < nb) ? aux[t] : 0;
  __syncthreads();
  for (int off = 1; off < 1024; off <<= 1) {
    int xv = (t >= off) ? lds[t - off] : 0;
    __syncthreads();
    lds[t] += xv;
    __syncthreads();
  }
  if (t < nb) aux[t] = (t == 0) ? 0 : lds[t - 1];
  if (t == 0) off_end[0] = lds[nb - 1];
}

__global__ void k_scan3(int* __restrict__ out, const int* __restrict__ aux, int n) {
  int i = blockIdx.x * 256 + threadIdx.x;
  if (i < n) out[i] += aux[i >> 10];
}

__global__ void k_fill(const int* __restrict__ esrc, const int* __restrict__ edst,
                       int* __restrict__ cur_src, int* __restrict__ cur_dst,
                       int* __restrict__ list_src, int* __restrict__ list_dst) {
  int i = blockIdx.x * 256 + threadIdx.x;
  if (i >= PE_) return;
  int p = i / E_;
  int s = esrc[i], d = edst[i];
  int ps = atomicAdd(&cur_src[p * N_ + s], 1);
  list_src[ps] = d;
  int pd = atomicAdd(&cur_dst[p * M_ + d], 1);
  list_dst[pd] = s;
}

// ====================== xdot: per-node x part of edge logit ======================
__global__ void k_xdot(const float* __restrict__ x, const float* __restrict__ We,
                       float* __restrict__ xdot) {
  int t = threadIdx.x;
  int pn = blockIdx.x * 4 + (t >> 6);
  if (pn >= PN_) return;
  int lane = t & 63;
  int p = pn / N_;
  const float* row = &x[(long long)pn * (C_ * FP_)];
  #pragma unroll
  for (int c = 0; c < C_; ++c) {
    float v = row[c * FP_ + lane] * We[(p * C_ + c) * FPFN_ + lane];
    #pragma unroll
    for (int off = 32; off > 0; off >>= 1) v += __shfl_down(v, off);
    if (lane == 0) xdot[pn * C_ + c] = v;
  }
}

// ====================== fused nexus: gather + 2-layer MLP + ndot ======================
__global__ __launch_bounds__(320) void k_nexus(
    const float* __restrict__ x,
    const int* __restrict__ off_dst, const int* __restrict__ list_dst,
    const float* __restrict__ Wn1, const float* __restrict__ bn1,
    const float* __restrict__ Wn2, const float* __restrict__ bn2,
    const float* __restrict__ We,
    float* __restrict__ nout, float* __restrict__ ndot) {
  __shared__ __align__(16) float sfeat[C_][PFP_];  // [c][p*64+k]
  __shared__ __align__(16) float sh1[C_][FN_];
  __shared__ __align__(16) float sh2[C_][FN_];
  int m = blockIdx.x;
  int t = threadIdx.x;               // 0..319 = c*64+k
  int c = t >> 6, k = t & 63;

  float acc[P_];
  #pragma unroll
  for (int p = 0; p < P_; ++p) {
    int o0 = off_dst[p * M_ + m];
    int o1 = off_dst[p * M_ + m + 1];
    float a = 0.f;
    for (int e = o0; e < o1; ++e) {
      int src = list_dst[e];
      a += x[(long long)(p * N_ + src) * (C_ * FP_) + t];
    }
    acc[p] = a;
  }
  #pragma unroll
  for (int p = 0; p < P_; ++p) sfeat[c][p * FP_ + k] = acc[p];
  __syncthreads();

  if (t < C_ * FN_) {
    int cc = t >> 5, j = t & 31;
    const float4* f4 = (const float4*)&sfeat[cc][0];
    const float4* w4 = (const float4*)&Wn1[(cc * FN_ + j) * PFP_];
    float a = bn1[cc * FN_ + j];
    #pragma unroll
    for (int i = 0; i < PFP_ / 4; ++i) {
      float4 f = f4[i], w = w4[i];
      a += f.x * w.x + f.y * w.y + f.z * w.z + f.w * w.w;
    }
    sh1[cc][j] = fast_tanh(a);
  }
  __syncthreads();
  if (t < C_ * FN_) {
    int cc = t >> 5, j = t & 31;
    const float4* f4 = (const float4*)&sh1[cc][0];
    const float4* w4 = (const float4*)&Wn2[(cc * FN_ + j) * FN_];
    float a = bn2[cc * FN_ + j];
    #pragma unroll
    for (int i = 0; i < FN_ / 4; ++i) {
      float4 f = f4[i], w = w4[i];
      a += f.x * w.x + f.y * w.y + f.z * w.z + f.w * w.w;
    }
    float nv = fast_tanh(a);
    sh2[cc][j] = nv;
    nout[(long long)m * (C_ * FN_) + t] = nv;
  }
  __syncthreads();
  if (t < P_ * C_) {                 // ndot[p][m][c] = We[p,c,64:96] . n[m,c,:]
    int p = t / C_, cc = t % C_;
    const float* w = &We[(p * C_ + cc) * FPFN_ + FP_];
    float a = 0.f;
    #pragma unroll
    for (int j = 0; j < FN_; ++j) a += sh2[cc][j] * w[j];
    ndot[(long long)(p * M_ + m) * C_ + cc] = a;
  }
}

// ====================== aggr: softmax-gated mean over src-CSR ======================
__global__ void k_aggr(const float* __restrict__ nout,
                       const int* __restrict__ off_src, const int* __restrict__ list_src,
                       const float* __restrict__ xdot, const float* __restrict__ ndot,
                       const float* __restrict__ be,
                       __half* __restrict__ aggr) {
  int t = threadIdx.x;
  int pn = blockIdx.x * 4 + (t >> 6);
  if (pn >= PN_) return;
  int lane = t & 63;
  int p = pn / N_;
  int o0 = off_src[pn], o1 = off_src[pn + 1];
  float base_c[C_];
  #pragma unroll
  for (int c = 0; c < C_; ++c) base_c[c] = xdot[pn * C_ + c] + be[p * C_ + c];

  float a0 = 0.f, a1 = 0.f, a2 = 0.f;
  for (int e = o0; e < o1; ++e) {
    int dst = list_src[e];
    const float* nr = &nout[(long long)dst * (C_ * FN_)];
    const float* nd = &ndot[(long long)(p * M_ + dst) * C_];
    float l[C_];
    #pragma unroll
    for (int c = 0; c < C_; ++c) l[c] = base_c[c] + nd[c];
    float mx = fmaxf(fmaxf(fmaxf(l[0], l[1]), fmaxf(l[2], l[3])), l[4]);
    float s = 0.f;
    #pragma unroll
    for (int c = 0; c < C_; ++c) { l[c] = __expf(l[c] - mx); s += l[c]; }
    float inv = __fdividef(1.0f, s);
    float wA = ((lane & 32) ? l[1] : l[0]) * inv;
    float wB = ((lane & 32) ? l[3] : l[2]) * inv;
    a0 += wA * nr[lane];
    a1 += wB * nr[64 + lane];
    if (lane < 32) a2 += l[4] * inv * nr[128 + lane];
  }
  float invd = __fdividef(1.0f, fmaxf((float)(o1 - o0), 1.0f));
  __half* out = &aggr[(long long)pn * (C_ * FN_)];
  out[lane]      = __float2half(a0 * invd);
  out[64 + lane] = __float2half(a1 * invd);
  if (lane < 32) out[128 + lane] = __float2half(a2 * invd);
}

// ====================== fused decoder (fp16 packed math, no big reg arrays) ====
// block = (p, c, 64-node tile); 256 threads.
// wave w: node parity w>>1; k = (w&1)*32 + (l&31); g = l>>5 splits the dot.
// Per lane: 24 half2 L1 weights + 16 half2 L2 weights (static, no spill).
__global__ __launch_bounds__(256, 4) void k_dec(
    const float* __restrict__ x, const __half* __restrict__ aggr,
    const float* __restrict__ Wd1, const float* __restrict__ bd1,
    const float* __restrict__ Wd2, const float* __restrict__ bd2,
    float* __restrict__ out) {
  __shared__ __half featS[NT_ * 104];   // [node][104], 96 used (x:64 | aggr:32)
  __shared__ __half hS[NT_ * 72];       // [node][72], 64 used
  int bp = blockIdx.x;
  int pc = bp / TILES_;
  int tile = bp % TILES_;
  int p = pc / C_, c = pc % C_;
  int base = tile * NT_;
  int rows = min(NT_, N_ - base);

  int t = threadIdx.x;
  int w = t >> 6;            // wave 0..3
  int l = t & 63;
  int k = (w & 1) * 32 + (l & 31);   // output index 0..63
  int g = l >> 5;                    // inner-dim half 0/1
  int par = w >> 1;                  // node parity

  // ---- per-lane weights as fp16 pairs ----
  __half2 w1h[24], w2h[16];
  {
    const float* wr = &Wd1[((size_t)(p * C_ + c) * FP_ + k) * FPFN_ + g * 48];
    #pragma unroll
    for (int j = 0; j < 24; ++j) w1h[j] = __floats2half2_rn(wr[2 * j], wr[2 * j + 1]);
    const float* w2r = &Wd2[((size_t)(p * C_ + c) * FP_ + k) * FP_ + g * 32];
    #pragma unroll
    for (int j = 0; j < 16; ++j) w2h[j] = __floats2half2_rn(w2r[2 * j], w2r[2 * j + 1]);
  }
  float b1 = bd1[(p * C_ + c) * FP_ + k];
  float b2 = bd2[(p * C_ + c) * FP_ + k];

  // ---- stage feat tile: x -> fp16, aggr (already fp16) copied ----
  {
    int node = t >> 2, q = t & 3;
    if (node < rows) {
      size_t row = (size_t)(p * N_ + base + node);
      const float4* xr = (const float4*)&x[row * (C_ * FP_) + c * FP_ + q * 16];
      __half2* fw = (__half2*)&featS[node * 104 + q * 16];
      #pragma unroll
      for (int i = 0; i < 4; ++i) {
        float4 v = xr[i];
        fw[2 * i]     = __floats2half2_rn(v.x, v.y);
        fw[2 * i + 1] = __floats2half2_rn(v.z, v.w);
      }
      const __half* ar = &aggr[row * (C_ * FN_) + c * FN_ + q * 8];
      *(float4*)&featS[node * 104 + 64 + q * 8] = *(const float4*)ar;
    }
  }
  __syncthreads();

  // ---- layer 1: h = tanh(W1 . feat + b1), h kept in LDS as fp16 ----
  for (int nd = par; nd < rows; nd += 2) {
    const __half2* f2 = (const __half2*)&featS[nd * 104 + g * 48];
    __half2 acc = __floats2half2_rn(0.f, 0.f);
    #pragma unroll
    for (int j = 0; j < 24; ++j) acc = __hfma2(f2[j], w1h[j], acc);
    float s = __low2float(acc) + __high2float(acc);
    s += __shfl_xor(s, 32);
    if (g == 0) hS[nd * 72 + k] = __float2half(fast_tanh(s + b1));
  }
  __syncthreads();

  // ---- layer 2: out = tanh(W2 . h + b2) ----
  for (int nd = par; nd < rows; nd += 2) {
    const __half2* h2 = (const __half2*)&hS[nd * 72 + g * 32];
    __half2 acc = __floats2half2_rn(0.f, 0.f);
    #pragma unroll
    for (int j = 0; j < 16; ++j) acc = __hfma2(h2[j], w2h[j], acc);
    float s = __low2float(acc) + __high2float(acc);
    s += __shfl_xor(s, 32);
    if (g == 0) {
      size_t row = (size_t)(p * N_ + base + nd);
      out[row * (C_ * FP_) + c * FP_ + k] = fast_tanh(s + b2);
    }
  }
}

// ====================== launch ======================
// workspace layout (4-byte words):
#define WS_AGGR  0ll          // half[48,000,000] = 24,000,000 words
#define WS_NOUT  24000000ll   // float[4,800,000]
#define WS_XDOT  28800000ll   // float[1,500,000]
#define WS_NDOT  30300000ll   // float[450,000]
#define WS_OFFS  30750000ll   // int[300,001]
#define WS_OFFD  31050001ll   // int[90,001]
#define WS_CURS  31140002ll   // int[300,000] (counts then cursors)
#define WS_CURD  31440002ll   // int[90,000]
#define WS_LISTS 31530002ll   // int[600,000]
#define WS_LISTD 32130002ll   // int[600,000]
#define WS_AUX1  32730002ll   // int[512]
#define WS_AUX2  32730514ll   // int[512]

extern "C" void kernel_launch(void* const* d_in, const int* in_sizes, int n_in,
                              void* d_out, int out_size, void* d_ws, size_t ws_size,
                              hipStream_t stream) {
  const float* x   = (const float*)d_in[0];
  const int* esrc  = (const int*)d_in[2];
  const int* edst  = (const int*)d_in[3];
  const float* Wn1 = (const float*)d_in[4];
  const float* bn1 = (const float*)d_in[5];
  const float* Wn2 = (const float*)d_in[6];
  const float* bn2 = (const float*)d_in[7];
  const float* We  = (const float*)d_in[8];
  const float* be  = (const float*)d_in[9];
  const float* Wd1 = (const float*)d_in[10];
  const float* bd1 = (const float*)d_in[11];
  const float* Wd2 = (const float*)d_in[12];
  const float* bd2 = (const float*)d_in[13];
  float* out = (float*)d_out;

  float* wsf = (float*)d_ws;
  int*   wsi = (int*)d_ws;
  __half* aggr = (__half*)d_ws;
  float* nout = wsf + WS_NOUT;
  float* xdot = wsf + WS_XDOT;
  float* ndot = wsf + WS_NDOT;
  int* off_src = wsi + WS_OFFS;
  int* off_dst = wsi + WS_OFFD;
  int* cur_src = wsi + WS_CURS;
  int* cur_dst = wsi + WS_CURD;
  int* list_src = wsi + WS_LISTS;
  int* list_dst = wsi + WS_LISTD;
  int* aux1 = wsi + WS_AUX1;
  int* aux2 = wsi + WS_AUX2;

  // ---- CSR build ----
  hipMemsetAsync(cur_src, 0, PN_ * sizeof(int), stream);
  hipMemsetAsync(cur_dst, 0, PM_ * sizeof(int), stream);
  k_count<<<(PE_ + 255) / 256, 256, 0, stream>>>(esrc, edst, cur_src, cur_dst);
  {
    int nb_s = (PN_ + 1023) / 1024;   // 293
    int nb_d = (PM_ + 1023) / 1024;   // 88
    k_scan1<<<nb_s, 256, 0, stream>>>(cur_src, off_src, aux1, PN_);
    k_scan1<<<nb_d, 256, 0, stream>>>(cur_dst, off_dst, aux2, PM_);
    k_scan2<<<1, 1024, 0, stream>>>(aux1, nb_s, off_src + PN_);
    k_scan2<<<1, 1024, 0, stream>>>(aux2, nb_d, off_dst + PM_);
    k_scan3<<<(PN_ + 255) / 256, 256, 0, stream>>>(off_src, aux1, PN_);
    k_scan3<<<(PM_ + 255) / 256, 256, 0, stream>>>(off_dst, aux2, PM_);
  }
  hipMemcpyAsync(cur_src, off_src, PN_ * sizeof(int), hipMemcpyDeviceToDevice, stream);
  hipMemcpyAsync(cur_dst, off_dst, PM_ * sizeof(int), hipMemcpyDeviceToDevice, stream);
  k_fill<<<(PE_ + 255) / 256, 256, 0, stream>>>(esrc, edst, cur_src, cur_dst,
                                                list_src, list_dst);

  // ---- stages ----
  k_xdot<<<(PN_ + 3) / 4, 256, 0, stream>>>(x, We, xdot);
  k_nexus<<<M_, 320, 0, stream>>>(x, off_dst, list_dst, Wn1, bn1, Wn2, bn2, We,
                                  nout, ndot);
  k_aggr<<<(PN_ + 3) / 4, 256, 0, stream>>>(nout, off_src, list_src, xdot, ndot,
                                            be, aggr);
  k_dec<<<P_ * C_ * TILES_, 256, 0, stream>>>(x, aggr, Wd1, bd1, Wd2, bd2, out);
}

// Round 6
// 1722.517 us; speedup vs baseline: 5.1960x; 1.0723x over previous
//
#include <hip/hip_runtime.h>
#include <hip/hip_fp16.h>

#define P_ 3
#define N_ 100000
#define M_ 30000
#define E_ 200000
#define C_ 5
#define FP_ 64
#define FN_ 32
#define PFP_ 192     // P*FP
#define FPFN_ 96     // FP+FN
#define PE_ 600000   // P*E
#define PN_ 300000   // P*N
#define PM_ 90000    // P*M
#define NT_ 64       // nodes per decoder tile
#define TILES_ ((N_ + NT_ - 1) / NT_)   // 1563

__device__ __forceinline__ float fast_tanh(float v) {
  float x = fminf(fmaxf(v, -15.0f), 15.0f);
  float t = __expf(2.0f * x);
  return __fdividef(t - 1.0f, t + 1.0f);
}

// ====================== CSR build ======================
__global__ void k_count(const int* __restrict__ esrc, const int* __restrict__ edst,
                        int* __restrict__ cnt_src, int* __restrict__ cnt_dst) {
  int i = blockIdx.x * 256 + threadIdx.x;
  if (i >= PE_) return;
  int p = i / E_;
  atomicAdd(&cnt_src[p * N_ + esrc[i]], 1);
  atomicAdd(&cnt_dst[p * M_ + edst[i]], 1);
}

// 3-pass exclusive scan (1024 elems/block)
__global__ void k_scan1(const int* __restrict__ in, int* __restrict__ out,
                        int* __restrict__ aux, int n) {
  __shared__ int lds[256];
  int b = blockIdx.x, t = threadIdx.x;
  int base = b * 1024 + t * 4;
  int v0 = (base + 0 < n) ? in[base + 0] : 0;
  int v1 = (base + 1 < n) ? in[base + 1] : 0;
  int v2 = (base + 2 < n) ? in[base + 2] : 0;
  int v3 = (base + 3 < n) ? in[base + 3] : 0;
  lds[t] = v0 + v1 + v2 + v3;
  __syncthreads();
  for (int off = 1; off < 256; off <<= 1) {
    int xv = (t >= off) ? lds[t - off] : 0;
    __syncthreads();
    lds[t] += xv;
    __syncthreads();
  }
  if (t == 255) aux[b] = lds[255];
  int run = (t == 0) ? 0 : lds[t - 1];
  if (base + 0 < n) out[base + 0] = run; run += v0;
  if (base + 1 < n) out[base + 1] = run; run += v1;
  if (base + 2 < n) out[base + 2] = run; run += v2;
  if (base + 3 < n) out[base + 3] = run;
}

__global__ void k_scan2(int* __restrict__ aux, int nb, int* __restrict__ off_end) {
  __shared__ int lds[1024];
  int t = threadIdx.x;
  lds[t] = (t < nb) ? aux[t] : 0;
  __syncthreads();
  for (int off = 1; off < 1024; off <<= 1) {
    int xv = (t >= off) ? lds[t - off] : 0;
    __syncthreads();
    lds[t] += xv;
    __syncthreads();
  }
  if (t < nb) aux[t] = (t == 0) ? 0 : lds[t - 1];
  if (t == 0) off_end[0] = lds[nb - 1];
}

__global__ void k_scan3(int* __restrict__ out, const int* __restrict__ aux, int n) {
  int i = blockIdx.x * 256 + threadIdx.x;
  if (i < n) out[i] += aux[i >> 10];
}

__global__ void k_fill(const int* __restrict__ esrc, const int* __restrict__ edst,
                       int* __restrict__ cur_src, int* __restrict__ cur_dst,
                       int* __restrict__ list_src, int* __restrict__ list_dst) {
  int i = blockIdx.x * 256 + threadIdx.x;
  if (i >= PE_) return;
  int p = i / E_;
  int s = esrc[i], d = edst[i];
  int ps = atomicAdd(&cur_src[p * N_ + s], 1);
  list_src[ps] = d;
  int pd = atomicAdd(&cur_dst[p * M_ + d], 1);
  list_dst[pd] = s;
}

// ====================== xdot: per-node x part of edge logit ======================
__global__ void k_xdot(const float* __restrict__ x, const float* __restrict__ We,
                       float* __restrict__ xdot) {
  int t = threadIdx.x;
  int pn = blockIdx.x * 4 + (t >> 6);
  if (pn >= PN_) return;
  int lane = t & 63;
  int p = pn / N_;
  const float* row = &x[(long long)pn * (C_ * FP_)];
  #pragma unroll
  for (int c = 0; c < C_; ++c) {
    float v = row[c * FP_ + lane] * We[(p * C_ + c) * FPFN_ + lane];
    #pragma unroll
    for (int off = 32; off > 0; off >>= 1) v += __shfl_down(v, off);
    if (lane == 0) xdot[pn * C_ + c] = v;
  }
}

// ====================== fused nexus: gather + 2-layer MLP + ndot ======================
__global__ __launch_bounds__(320) void k_nexus(
    const float* __restrict__ x,
    const int* __restrict__ off_dst, const int* __restrict__ list_dst,
    const float* __restrict__ Wn1, const float* __restrict__ bn1,
    const float* __restrict__ Wn2, const float* __restrict__ bn2,
    const float* __restrict__ We,
    float* __restrict__ nout, float* __restrict__ ndot) {
  __shared__ __align__(16) float sfeat[C_][PFP_];  // [c][p*64+k]
  __shared__ __align__(16) float sh1[C_][FN_];
  __shared__ __align__(16) float sh2[C_][FN_];
  int m = blockIdx.x;
  int t = threadIdx.x;               // 0..319 = c*64+k
  int c = t >> 6, k = t & 63;

  // batched gather: 8 loads in flight per batch, one waitcnt each (latency fix)
  float acc[P_];
  #pragma unroll
  for (int p = 0; p < P_; ++p) {
    int o0 = off_dst[p * M_ + m];
    int o1 = off_dst[p * M_ + m + 1];
    const float* xp = x + (size_t)p * N_ * (C_ * FP_);
    float a = 0.f;
    for (int e0 = o0; e0 < o1; e0 += 8) {
      float v[8];
      #pragma unroll
      for (int j = 0; j < 8; ++j) {
        int e = e0 + j;
        int src = list_dst[e < o1 ? e : o0];   // clamped: load always issued
        float val = xp[(size_t)src * (C_ * FP_) + t];
        v[j] = (e < o1) ? val : 0.f;
      }
      #pragma unroll
      for (int j = 0; j < 8; ++j) a += v[j];
    }
    acc[p] = a;
  }
  #pragma unroll
  for (int p = 0; p < P_; ++p) sfeat[c][p * FP_ + k] = acc[p];
  __syncthreads();

  if (t < C_ * FN_) {
    int cc = t >> 5, j = t & 31;
    const float4* f4 = (const float4*)&sfeat[cc][0];
    const float4* w4 = (const float4*)&Wn1[(cc * FN_ + j) * PFP_];
    float a = bn1[cc * FN_ + j];
    #pragma unroll
    for (int i = 0; i < PFP_ / 4; ++i) {
      float4 f = f4[i], w = w4[i];
      a += f.x * w.x + f.y * w.y + f.z * w.z + f.w * w.w;
    }
    sh1[cc][j] = fast_tanh(a);
  }
  __syncthreads();
  if (t < C_ * FN_) {
    int cc = t >> 5, j = t & 31;
    const float4* f4 = (const float4*)&sh1[cc][0];
    const float4* w4 = (const float4*)&Wn2[(cc * FN_ + j) * FN_];
    float a = bn2[cc * FN_ + j];
    #pragma unroll
    for (int i = 0; i < FN_ / 4; ++i) {
      float4 f = f4[i], w = w4[i];
      a += f.x * w.x + f.y * w.y + f.z * w.z + f.w * w.w;
    }
    float nv = fast_tanh(a);
    sh2[cc][j] = nv;
    nout[(long long)m * (C_ * FN_) + t] = nv;
  }
  __syncthreads();
  if (t < P_ * C_) {                 // ndot[p][m][c] = We[p,c,64:96] . n[m,c,:]
    int p = t / C_, cc = t % C_;
    const float* w = &We[(p * C_ + cc) * FPFN_ + FP_];
    float a = 0.f;
    #pragma unroll
    for (int j = 0; j < FN_; ++j) a += sh2[cc][j] * w[j];
    ndot[(long long)(p * M_ + m) * C_ + cc] = a;
  }
}

// ====================== aggr: softmax-gated mean over src-CSR ======================
__global__ void k_aggr(const float* __restrict__ nout,
                       const int* __restrict__ off_src, const int* __restrict__ list_src,
                       const float* __restrict__ xdot, const float* __restrict__ ndot,
                       const float* __restrict__ be,
                       __half* __restrict__ aggr) {
  int t = threadIdx.x;
  int pn = blockIdx.x * 4 + (t >> 6);
  if (pn >= PN_) return;
  int lane = t & 63;
  int p = pn / N_;
  int o0 = off_src[pn], o1 = off_src[pn + 1];
  float base_c[C_];
  #pragma unroll
  for (int c = 0; c < C_; ++c) base_c[c] = xdot[pn * C_ + c] + be[p * C_ + c];

  float a0 = 0.f, a1 = 0.f, a2 = 0.f;
  for (int e = o0; e < o1; ++e) {
    int dst = list_src[e];
    const float* nr = &nout[(long long)dst * (C_ * FN_)];
    const float* nd = &ndot[(long long)(p * M_ + dst) * C_];
    float l[C_];
    #pragma unroll
    for (int c = 0; c < C_; ++c) l[c] = base_c[c] + nd[c];
    float mx = fmaxf(fmaxf(fmaxf(l[0], l[1]), fmaxf(l[2], l[3])), l[4]);
    float s = 0.f;
    #pragma unroll
    for (int c = 0; c < C_; ++c) { l[c] = __expf(l[c] - mx); s += l[c]; }
    float inv = __fdividef(1.0f, s);
    float wA = ((lane & 32) ? l[1] : l[0]) * inv;
    float wB = ((lane & 32) ? l[3] : l[2]) * inv;
    a0 += wA * nr[lane];
    a1 += wB * nr[64 + lane];
    if (lane < 32) a2 += l[4] * inv * nr[128 + lane];
  }
  float invd = __fdividef(1.0f, fmaxf((float)(o1 - o0), 1.0f));
  __half* out = &aggr[(long long)pn * (C_ * FN_)];
  out[lane]      = __float2half(a0 * invd);
  out[64 + lane] = __float2half(a1 * invd);
  if (lane < 32) out[128 + lane] = __float2half(a2 * invd);
}

// ====================== fused decoder (fp16 packed math, no big reg arrays) ====
__global__ __launch_bounds__(256, 4) void k_dec(
    const float* __restrict__ x, const __half* __restrict__ aggr,
    const float* __restrict__ Wd1, const float* __restrict__ bd1,
    const float* __restrict__ Wd2, const float* __restrict__ bd2,
    float* __restrict__ out) {
  __shared__ __half featS[NT_ * 104];   // [node][104], 96 used (x:64 | aggr:32)
  __shared__ __half hS[NT_ * 72];       // [node][72], 64 used
  int bp = blockIdx.x;
  int pc = bp / TILES_;
  int tile = bp % TILES_;
  int p = pc / C_, c = pc % C_;
  int base = tile * NT_;
  int rows = min(NT_, N_ - base);

  int t = threadIdx.x;
  int w = t >> 6;            // wave 0..3
  int l = t & 63;
  int k = (w & 1) * 32 + (l & 31);   // output index 0..63
  int g = l >> 5;                    // inner-dim half 0/1
  int par = w >> 1;                  // node parity

  __half2 w1h[24], w2h[16];
  {
    const float* wr = &Wd1[((size_t)(p * C_ + c) * FP_ + k) * FPFN_ + g * 48];
    #pragma unroll
    for (int j = 0; j < 24; ++j) w1h[j] = __floats2half2_rn(wr[2 * j], wr[2 * j + 1]);
    const float* w2r = &Wd2[((size_t)(p * C_ + c) * FP_ + k) * FP_ + g * 32];
    #pragma unroll
    for (int j = 0; j < 16; ++j) w2h[j] = __floats2half2_rn(w2r[2 * j], w2r[2 * j + 1]);
  }
  float b1 = bd1[(p * C_ + c) * FP_ + k];
  float b2 = bd2[(p * C_ + c) * FP_ + k];

  {
    int node = t >> 2, q = t & 3;
    if (node < rows) {
      size_t row = (size_t)(p * N_ + base + node);
      const float4* xr = (const float4*)&x[row * (C_ * FP_) + c * FP_ + q * 16];
      __half2* fw = (__half2*)&featS[node * 104 + q * 16];
      #pragma unroll
      for (int i = 0; i < 4; ++i) {
        float4 v = xr[i];
        fw[2 * i]     = __floats2half2_rn(v.x, v.y);
        fw[2 * i + 1] = __floats2half2_rn(v.z, v.w);
      }
      const __half* ar = &aggr[row * (C_ * FN_) + c * FN_ + q * 8];
      *(float4*)&featS[node * 104 + 64 + q * 8] = *(const float4*)ar;
    }
  }
  __syncthreads();

  for (int nd = par; nd < rows; nd += 2) {
    const __half2* f2 = (const __half2*)&featS[nd * 104 + g * 48];
    __half2 acc = __floats2half2_rn(0.f, 0.f);
    #pragma unroll
    for (int j = 0; j < 24; ++j) acc = __hfma2(f2[j], w1h[j], acc);
    float s = __low2float(acc) + __high2float(acc);
    s += __shfl_xor(s, 32);
    if (g == 0) hS[nd * 72 + k] = __float2half(fast_tanh(s + b1));
  }
  __syncthreads();

  for (int nd = par; nd < rows; nd += 2) {
    const __half2* h2 = (const __half2*)&hS[nd * 72 + g * 32];
    __half2 acc = __floats2half2_rn(0.f, 0.f);
    #pragma unroll
    for (int j = 0; j < 16; ++j) acc = __hfma2(h2[j], w2h[j], acc);
    float s = __low2float(acc) + __high2float(acc);
    s += __shfl_xor(s, 32);
    if (g == 0) {
      size_t row = (size_t)(p * N_ + base + nd);
      out[row * (C_ * FP_) + c * FP_ + k] = fast_tanh(s + b2);
    }
  }
}

// ====================== launch ======================
// workspace layout (4-byte words):
#define WS_AGGR  0ll          // half[48,000,000] = 24,000,000 words
#define WS_NOUT  24000000ll   // float[4,800,000]
#define WS_XDOT  28800000ll   // float[1,500,000]
#define WS_NDOT  30300000ll   // float[450,000]
#define WS_OFFS  30750000ll   // int[300,001]
#define WS_OFFD  31050001ll   // int[90,001]
#define WS_CURS  31140002ll   // int[300,000] (counts then cursors)
#define WS_CURD  31440002ll   // int[90,000]
#define WS_LISTS 31530002ll   // int[600,000]
#define WS_LISTD 32130002ll   // int[600,000]
#define WS_AUX1  32730002ll   // int[512]
#define WS_AUX2  32730514ll   // int[512]

extern "C" void kernel_launch(void* const* d_in, const int* in_sizes, int n_in,
                              void* d_out, int out_size, void* d_ws, size_t ws_size,
                              hipStream_t stream) {
  const float* x   = (const float*)d_in[0];
  const int* esrc  = (const int*)d_in[2];
  const int* edst  = (const int*)d_in[3];
  const float* Wn1 = (const float*)d_in[4];
  const float* bn1 = (const float*)d_in[5];
  const float* Wn2 = (const float*)d_in[6];
  const float* bn2 = (const float*)d_in[7];
  const float* We  = (const float*)d_in[8];
  const float* be  = (const float*)d_in[9];
  const float* Wd1 = (const float*)d_in[10];
  const float* bd1 = (const float*)d_in[11];
  const float* Wd2 = (const float*)d_in[12];
  const float* bd2 = (const float*)d_in[13];
  float* out = (float*)d_out;

  float* wsf = (float*)d_ws;
  int*   wsi = (int*)d_ws;
  __half* aggr = (__half*)d_ws;
  float* nout = wsf + WS_NOUT;
  float* xdot = wsf + WS_XDOT;
  float* ndot = wsf + WS_NDOT;
  int* off_src = wsi + WS_OFFS;
  int* off_dst = wsi + WS_OFFD;
  int* cur_src = wsi + WS_CURS;
  int* cur_dst = wsi + WS_CURD;
  int* list_src = wsi + WS_LISTS;
  int* list_dst = wsi + WS_LISTD;
  int* aux1 = wsi + WS_AUX1;
  int* aux2 = wsi + WS_AUX2;

  // ---- CSR build ----
  hipMemsetAsync(cur_src, 0, PN_ * sizeof(int), stream);
  hipMemsetAsync(cur_dst, 0, PM_ * sizeof(int), stream);
  k_count<<<(PE_ + 255) / 256, 256, 0, stream>>>(esrc, edst, cur_src, cur_dst);
  {
    int nb_s = (PN_ + 1023) / 1024;   // 293
    int nb_d = (PM_ + 1023) / 1024;   // 88
    k_scan1<<<nb_s, 256, 0, stream>>>(cur_src, off_src, aux1, PN_);
    k_scan1<<<nb_d, 256, 0, stream>>>(cur_dst, off_dst, aux2, PM_);
    k_scan2<<<1, 1024, 0, stream>>>(aux1, nb_s, off_src + PN_);
    k_scan2<<<1, 1024, 0, stream>>>(aux2, nb_d, off_dst + PM_);
    k_scan3<<<(PN_ + 255) / 256, 256, 0, stream>>>(off_src, aux1, PN_);
    k_scan3<<<(PM_ + 255) / 256, 256, 0, stream>>>(off_dst, aux2, PM_);
  }
  hipMemcpyAsync(cur_src, off_src, PN_ * sizeof(int), hipMemcpyDeviceToDevice, stream);
  hipMemcpyAsync(cur_dst, off_dst, PM_ * sizeof(int), hipMemcpyDeviceToDevice, stream);
  k_fill<<<(PE_ + 255) / 256, 256, 0, stream>>>(esrc, edst, cur_src, cur_dst,
                                                list_src, list_dst);

  // ---- stages ----
  k_xdot<<<(PN_ + 3) / 4, 256, 0, stream>>>(x, We, xdot);
  k_nexus<<<M_, 320, 0, stream>>>(x, off_dst, list_dst, Wn1, bn1, Wn2, bn2, We,
                                  nout, ndot);
  k_aggr<<<(PN_ + 3) / 4, 256, 0, stream>>>(nout, off_src, list_src, xdot, ndot,
                                            be, aggr);
  k_dec<<<P_ * C_ * TILES_, 256, 0, stream>>>(x, aggr, Wd1, bd1, Wd2, bd2, out);
}

// Round 7
// 1392.218 us; speedup vs baseline: 6.4287x; 1.2372x over previous
//
#include <hip/hip_runtime.h>
#include <hip/hip_fp16.h>

#define P_ 3
#define N_ 100000
#define M_ 30000
#define E_ 200000
#define C_ 5
#define FP_ 64
#define FN_ 32
#define PFP_ 192     // P*FP
#define FPFN_ 96     // FP+FN
#define PE_ 600000   // P*E
#define PN_ 300000   // P*N
#define PM_ 90000    // P*M
#define NT_ 64       // nodes per tile (decoder + proj)
#define TILES_ ((N_ + NT_ - 1) / NT_)   // 1563
#define CFN_ 160     // C*FN

__device__ __forceinline__ float fast_tanh(float v) {
  float x = fminf(fmaxf(v, -15.0f), 15.0f);
  float t = __expf(2.0f * x);
  return __fdividef(t - 1.0f, t + 1.0f);
}

// ====================== CSR build ======================
__global__ void k_count(const int* __restrict__ esrc, const int* __restrict__ edst,
                        int* __restrict__ cnt_src, int* __restrict__ cnt_dst) {
  int i = blockIdx.x * 256 + threadIdx.x;
  if (i >= PE_) return;
  int p = i / E_;
  atomicAdd(&cnt_src[p * N_ + esrc[i]], 1);
  atomicAdd(&cnt_dst[p * M_ + edst[i]], 1);
}

// 3-pass exclusive scan (1024 elems/block)
__global__ void k_scan1(const int* __restrict__ in, int* __restrict__ out,
                        int* __restrict__ aux, int n) {
  __shared__ int lds[256];
  int b = blockIdx.x, t = threadIdx.x;
  int base = b * 1024 + t * 4;
  int v0 = (base + 0 < n) ? in[base + 0] : 0;
  int v1 = (base + 1 < n) ? in[base + 1] : 0;
  int v2 = (base + 2 < n) ? in[base + 2] : 0;
  int v3 = (base + 3 < n) ? in[base + 3] : 0;
  lds[t] = v0 + v1 + v2 + v3;
  __syncthreads();
  for (int off = 1; off < 256; off <<= 1) {
    int xv = (t >= off) ? lds[t - off] : 0;
    __syncthreads();
    lds[t] += xv;
    __syncthreads();
  }
  if (t == 255) aux[b] = lds[255];
  int run = (t == 0) ? 0 : lds[t - 1];
  if (base + 0 < n) out[base + 0] = run; run += v0;
  if (base + 1 < n) out[base + 1] = run; run += v1;
  if (base + 2 < n) out[base + 2] = run; run += v2;
  if (base + 3 < n) out[base + 3] = run;
}

__global__ void k_scan2(int* __restrict__ aux, int nb, int* __restrict__ off_end) {
  __shared__ int lds[1024];
  int t = threadIdx.x;
  lds[t] = (t < nb) ? aux[t] : 0;
  __syncthreads();
  for (int off = 1; off < 1024; off <<= 1) {
    int xv = (t >= off) ? lds[t - off] : 0;
    __syncthreads();
    lds[t] += xv;
    __syncthreads();
  }
  if (t < nb) aux[t] = (t == 0) ? 0 : lds[t - 1];
  if (t == 0) off_end[0] = lds[nb - 1];
}

__global__ void k_scan3(int* __restrict__ out, const int* __restrict__ aux, int n) {
  int i = blockIdx.x * 256 + threadIdx.x;
  if (i < n) out[i] += aux[i >> 10];
}

__global__ void k_fill(const int* __restrict__ esrc, const int* __restrict__ edst,
                       int* __restrict__ cur_src, int* __restrict__ cur_dst,
                       int* __restrict__ list_src, int* __restrict__ list_dst) {
  int i = blockIdx.x * 256 + threadIdx.x;
  if (i >= PE_) return;
  int p = i / E_;
  int s = esrc[i], d = edst[i];
  int ps = atomicAdd(&cur_src[p * N_ + s], 1);
  list_src[ps] = d;
  int pd = atomicAdd(&cur_dst[p * M_ + d], 1);
  list_dst[pd] = s;
}

// ====================== xdot: per-node x part of edge logit ======================
__global__ void k_xdot(const float* __restrict__ x, const float* __restrict__ We,
                       float* __restrict__ xdot) {
  int t = threadIdx.x;
  int pn = blockIdx.x * 4 + (t >> 6);
  if (pn >= PN_) return;
  int lane = t & 63;
  int p = pn / N_;
  const float* row = &x[(long long)pn * (C_ * FP_)];
  #pragma unroll
  for (int c = 0; c < C_; ++c) {
    float v = row[c * FP_ + lane] * We[(p * C_ + c) * FPFN_ + lane];
    #pragma unroll
    for (int off = 32; off > 0; off >>= 1) v += __shfl_down(v, off);
    if (lane == 0) xdot[pn * C_ + c] = v;
  }
}

// ====================== projx: streaming y[p,n,c,j] = Wn1_p-block . x[p,n,c,:] ====
// block = 320 threads: g = node-parity group (2x160), u = c*32+j.
// x tile is a CONTIGUOUS span -> fully coalesced streaming read.
__global__ __launch_bounds__(320) void k_projx(
    const float* __restrict__ x, const float* __restrict__ Wn1,
    __half* __restrict__ y) {
  __shared__ __half xs[NT_ * 320];   // 40 KB
  int bp = blockIdx.x;
  int p = bp / TILES_, tile = bp % TILES_;
  int base = tile * NT_;
  int rows = min(NT_, N_ - base);
  int t = threadIdx.x;
  int g = t / CFN_, u = t % CFN_;
  int c = u >> 5;

  // per-thread weights: Wn1[(c*FN+j)*PFP + p*64 + i] as 32 half2 (static idx)
  __half2 w[32];
  {
    const float* wr = &Wn1[(size_t)u * PFP_ + p * FP_];
    #pragma unroll
    for (int i = 0; i < 32; ++i) w[i] = __floats2half2_rn(wr[2*i], wr[2*i+1]);
  }

  const float* xb = x + (size_t)(p * N_ + base) * (C_ * FP_);
  int tot = rows * 320;
  for (int f = t * 4; f < tot; f += 320 * 4) {
    float4 v = *(const float4*)(xb + f);
    __half2* dst = (__half2*)&xs[f];
    dst[0] = __floats2half2_rn(v.x, v.y);
    dst[1] = __floats2half2_rn(v.z, v.w);
  }
  __syncthreads();

  for (int r = g; r < rows; r += 2) {
    const __half2* xr = (const __half2*)&xs[r * 320 + c * FP_];
    __half2 acc = __floats2half2_rn(0.f, 0.f);
    #pragma unroll
    for (int i = 0; i < 32; ++i) acc = __hfma2(xr[i], w[i], acc);
    float s = __low2float(acc) + __high2float(acc);
    y[(size_t)(p * N_ + base + r) * CFN_ + u] = __float2half(s);
  }
}

// ====================== nexus: gather y (L3-resident) = layer-1 preact ==========
// block per m; 2x160 threads: g = edge-parity group, u = c*32+j.
__global__ __launch_bounds__(320) void k_nexus(
    const __half* __restrict__ y,
    const int* __restrict__ off_dst, const int* __restrict__ list_dst,
    const float* __restrict__ bn1,
    const float* __restrict__ Wn2, const float* __restrict__ bn2,
    const float* __restrict__ We,
    float* __restrict__ nout, float* __restrict__ ndot) {
  __shared__ float part[2][CFN_];
  __shared__ __align__(16) float h1S[CFN_];
  __shared__ __align__(16) float h2S[CFN_];
  int m = blockIdx.x;
  int t = threadIdx.x;
  int g = t / CFN_, u = t % CFN_;
  int c = u >> 5;

  float af = 0.f;
  #pragma unroll
  for (int p = 0; p < P_; ++p) {
    int o0 = off_dst[p * M_ + m];
    int o1 = off_dst[p * M_ + m + 1];
    const __half* yp = y + (size_t)p * N_ * CFN_;
    for (int e0 = o0 + g; e0 < o1; e0 += 8) {   // 4 edges per batch (stride 2)
      int e1 = e0 + 2, e2 = e0 + 4, e3 = e0 + 6;
      int s0 = list_dst[e0];
      int s1 = list_dst[e1 < o1 ? e1 : e0];
      int s2 = list_dst[e2 < o1 ? e2 : e0];
      int s3 = list_dst[e3 < o1 ? e3 : e0];
      float v0 = __half2float(yp[(size_t)s0 * CFN_ + u]);
      float v1 = __half2float(yp[(size_t)s1 * CFN_ + u]);
      float v2 = __half2float(yp[(size_t)s2 * CFN_ + u]);
      float v3 = __half2float(yp[(size_t)s3 * CFN_ + u]);
      af += v0;
      if (e1 < o1) af += v1;
      if (e2 < o1) af += v2;
      if (e3 < o1) af += v3;
    }
  }
  part[g][u] = af;
  __syncthreads();
  if (t < CFN_) {
    float pre = part[0][u] + part[1][u] + bn1[u];
    h1S[u] = fast_tanh(pre);
  }
  __syncthreads();
  if (t < CFN_) {
    const float4* f4 = (const float4*)&h1S[c * FN_];
    const float4* w4 = (const float4*)&Wn2[(size_t)u * FN_];
    float a = bn2[u];
    #pragma unroll
    for (int i = 0; i < FN_ / 4; ++i) {
      float4 f = f4[i], wv = w4[i];
      a += f.x * wv.x + f.y * wv.y + f.z * wv.z + f.w * wv.w;
    }
    float nv = fast_tanh(a);
    h2S[u] = nv;
    nout[(size_t)m * CFN_ + u] = nv;
  }
  __syncthreads();
  if (t < P_ * C_) {                 // ndot[p][m][c] = We[p,c,64:96] . n[m,c,:]
    int p = t / C_, cc = t % C_;
    const float* wv = &We[(p * C_ + cc) * FPFN_ + FP_];
    float a = 0.f;
    #pragma unroll
    for (int j = 0; j < FN_; ++j) a += h2S[cc * FN_ + j] * wv[j];
    ndot[(size_t)(p * M_ + m) * C_ + cc] = a;
  }
}

// ====================== aggr: softmax-gated mean over src-CSR ======================
__global__ void k_aggr(const float* __restrict__ nout,
                       const int* __restrict__ off_src, const int* __restrict__ list_src,
                       const float* __restrict__ xdot, const float* __restrict__ ndot,
                       const float* __restrict__ be,
                       __half* __restrict__ aggr) {
  int t = threadIdx.x;
  int pn = blockIdx.x * 4 + (t >> 6);
  if (pn >= PN_) return;
  int lane = t & 63;
  int p = pn / N_;
  int o0 = off_src[pn], o1 = off_src[pn + 1];
  float base_c[C_];
  #pragma unroll
  for (int c = 0; c < C_; ++c) base_c[c] = xdot[pn * C_ + c] + be[p * C_ + c];

  float a0 = 0.f, a1 = 0.f, a2 = 0.f;
  for (int e = o0; e < o1; ++e) {
    int dst = list_src[e];
    const float* nr = &nout[(long long)dst * (C_ * FN_)];
    const float* nd = &ndot[(long long)(p * M_ + dst) * C_];
    float l[C_];
    #pragma unroll
    for (int c = 0; c < C_; ++c) l[c] = base_c[c] + nd[c];
    float mx = fmaxf(fmaxf(fmaxf(l[0], l[1]), fmaxf(l[2], l[3])), l[4]);
    float s = 0.f;
    #pragma unroll
    for (int c = 0; c < C_; ++c) { l[c] = __expf(l[c] - mx); s += l[c]; }
    float inv = __fdividef(1.0f, s);
    float wA = ((lane & 32) ? l[1] : l[0]) * inv;
    float wB = ((lane & 32) ? l[3] : l[2]) * inv;
    a0 += wA * nr[lane];
    a1 += wB * nr[64 + lane];
    if (lane < 32) a2 += l[4] * inv * nr[128 + lane];
  }
  float invd = __fdividef(1.0f, fmaxf((float)(o1 - o0), 1.0f));
  __half* out = &aggr[(long long)pn * (C_ * FN_)];
  out[lane]      = __float2half(a0 * invd);
  out[64 + lane] = __float2half(a1 * invd);
  if (lane < 32) out[128 + lane] = __float2half(a2 * invd);
}

// ====================== fused decoder (fp16 packed math, no big reg arrays) ====
__global__ __launch_bounds__(256, 4) void k_dec(
    const float* __restrict__ x, const __half* __restrict__ aggr,
    const float* __restrict__ Wd1, const float* __restrict__ bd1,
    const float* __restrict__ Wd2, const float* __restrict__ bd2,
    float* __restrict__ out) {
  __shared__ __half featS[NT_ * 104];   // [node][104], 96 used (x:64 | aggr:32)
  __shared__ __half hS[NT_ * 72];       // [node][72], 64 used
  int bp = blockIdx.x;
  int pc = bp / TILES_;
  int tile = bp % TILES_;
  int p = pc / C_, c = pc % C_;
  int base = tile * NT_;
  int rows = min(NT_, N_ - base);

  int t = threadIdx.x;
  int w = t >> 6;            // wave 0..3
  int l = t & 63;
  int k = (w & 1) * 32 + (l & 31);   // output index 0..63
  int g = l >> 5;                    // inner-dim half 0/1
  int par = w >> 1;                  // node parity

  __half2 w1h[24], w2h[16];
  {
    const float* wr = &Wd1[((size_t)(p * C_ + c) * FP_ + k) * FPFN_ + g * 48];
    #pragma unroll
    for (int j = 0; j < 24; ++j) w1h[j] = __floats2half2_rn(wr[2 * j], wr[2 * j + 1]);
    const float* w2r = &Wd2[((size_t)(p * C_ + c) * FP_ + k) * FP_ + g * 32];
    #pragma unroll
    for (int j = 0; j < 16; ++j) w2h[j] = __floats2half2_rn(w2r[2 * j], w2r[2 * j + 1]);
  }
  float b1 = bd1[(p * C_ + c) * FP_ + k];
  float b2 = bd2[(p * C_ + c) * FP_ + k];

  {
    int node = t >> 2, q = t & 3;
    if (node < rows) {
      size_t row = (size_t)(p * N_ + base + node);
      const float4* xr = (const float4*)&x[row * (C_ * FP_) + c * FP_ + q * 16];
      __half2* fw = (__half2*)&featS[node * 104 + q * 16];
      #pragma unroll
      for (int i = 0; i < 4; ++i) {
        float4 v = xr[i];
        fw[2 * i]     = __floats2half2_rn(v.x, v.y);
        fw[2 * i + 1] = __floats2half2_rn(v.z, v.w);
      }
      const __half* ar = &aggr[row * (C_ * FN_) + c * FN_ + q * 8];
      *(float4*)&featS[node * 104 + 64 + q * 8] = *(const float4*)ar;
    }
  }
  __syncthreads();

  for (int nd = par; nd < rows; nd += 2) {
    const __half2* f2 = (const __half2*)&featS[nd * 104 + g * 48];
    __half2 acc = __floats2half2_rn(0.f, 0.f);
    #pragma unroll
    for (int j = 0; j < 24; ++j) acc = __hfma2(f2[j], w1h[j], acc);
    float s = __low2float(acc) + __high2float(acc);
    s += __shfl_xor(s, 32);
    if (g == 0) hS[nd * 72 + k] = __float2half(fast_tanh(s + b1));
  }
  __syncthreads();

  for (int nd = par; nd < rows; nd += 2) {
    const __half2* h2 = (const __half2*)&hS[nd * 72 + g * 32];
    __half2 acc = __floats2half2_rn(0.f, 0.f);
    #pragma unroll
    for (int j = 0; j < 16; ++j) acc = __hfma2(h2[j], w2h[j], acc);
    float s = __low2float(acc) + __high2float(acc);
    s += __shfl_xor(s, 32);
    if (g == 0) {
      size_t row = (size_t)(p * N_ + base + nd);
      out[row * (C_ * FP_) + c * FP_ + k] = fast_tanh(s + b2);
    }
  }
}

// ====================== launch ======================
// workspace layout (4-byte words):
//   [0, 24M words)  : y (half[48M]) during projx/nexus, THEN aggr (half[48M])
//                     (live ranges disjoint: y dead before k_aggr writes)
#define WS_AGGR  0ll          // half[48,000,000] = 24,000,000 words (also y)
#define WS_NOUT  24000000ll   // float[4,800,000]
#define WS_XDOT  28800000ll   // float[1,500,000]
#define WS_NDOT  30300000ll   // float[450,000]
#define WS_OFFS  30750000ll   // int[300,001]
#define WS_OFFD  31050001ll   // int[90,001]
#define WS_CURS  31140002ll   // int[300,000] (counts then cursors)
#define WS_CURD  31440002ll   // int[90,000]
#define WS_LISTS 31530002ll   // int[600,000]
#define WS_LISTD 32130002ll   // int[600,000]
#define WS_AUX1  32730002ll   // int[512]
#define WS_AUX2  32730514ll   // int[512]

extern "C" void kernel_launch(void* const* d_in, const int* in_sizes, int n_in,
                              void* d_out, int out_size, void* d_ws, size_t ws_size,
                              hipStream_t stream) {
  const float* x   = (const float*)d_in[0];
  const int* esrc  = (const int*)d_in[2];
  const int* edst  = (const int*)d_in[3];
  const float* Wn1 = (const float*)d_in[4];
  const float* bn1 = (const float*)d_in[5];
  const float* Wn2 = (const float*)d_in[6];
  const float* bn2 = (const float*)d_in[7];
  const float* We  = (const float*)d_in[8];
  const float* be  = (const float*)d_in[9];
  const float* Wd1 = (const float*)d_in[10];
  const float* bd1 = (const float*)d_in[11];
  const float* Wd2 = (const float*)d_in[12];
  const float* bd2 = (const float*)d_in[13];
  float* out = (float*)d_out;

  float* wsf = (float*)d_ws;
  int*   wsi = (int*)d_ws;
  __half* aggr = (__half*)d_ws;      // and y, time-shared
  __half* ybuf = (__half*)d_ws;
  float* nout = wsf + WS_NOUT;
  float* xdot = wsf + WS_XDOT;
  float* ndot = wsf + WS_NDOT;
  int* off_src = wsi + WS_OFFS;
  int* off_dst = wsi + WS_OFFD;
  int* cur_src = wsi + WS_CURS;
  int* cur_dst = wsi + WS_CURD;
  int* list_src = wsi + WS_LISTS;
  int* list_dst = wsi + WS_LISTD;
  int* aux1 = wsi + WS_AUX1;
  int* aux2 = wsi + WS_AUX2;

  // ---- CSR build ----
  hipMemsetAsync(cur_src, 0, PN_ * sizeof(int), stream);
  hipMemsetAsync(cur_dst, 0, PM_ * sizeof(int), stream);
  k_count<<<(PE_ + 255) / 256, 256, 0, stream>>>(esrc, edst, cur_src, cur_dst);
  {
    int nb_s = (PN_ + 1023) / 1024;   // 293
    int nb_d = (PM_ + 1023) / 1024;   // 88
    k_scan1<<<nb_s, 256, 0, stream>>>(cur_src, off_src, aux1, PN_);
    k_scan1<<<nb_d, 256, 0, stream>>>(cur_dst, off_dst, aux2, PM_);
    k_scan2<<<1, 1024, 0, stream>>>(aux1, nb_s, off_src + PN_);
    k_scan2<<<1, 1024, 0, stream>>>(aux2, nb_d, off_dst + PM_);
    k_scan3<<<(PN_ + 255) / 256, 256, 0, stream>>>(off_src, aux1, PN_);
    k_scan3<<<(PM_ + 255) / 256, 256, 0, stream>>>(off_dst, aux2, PM_);
  }
  hipMemcpyAsync(cur_src, off_src, PN_ * sizeof(int), hipMemcpyDeviceToDevice, stream);
  hipMemcpyAsync(cur_dst, off_dst, PM_ * sizeof(int), hipMemcpyDeviceToDevice, stream);
  k_fill<<<(PE_ + 255) / 256, 256, 0, stream>>>(esrc, edst, cur_src, cur_dst,
                                                list_src, list_dst);

  // ---- stages ----
  k_projx<<<P_ * TILES_, 320, 0, stream>>>(x, Wn1, ybuf);
  k_xdot<<<(PN_ + 3) / 4, 256, 0, stream>>>(x, We, xdot);
  k_nexus<<<M_, 320, 0, stream>>>(ybuf, off_dst, list_dst, bn1, Wn2, bn2, We,
                                  nout, ndot);
  k_aggr<<<(PN_ + 3) / 4, 256, 0, stream>>>(nout, off_src, list_src, xdot, ndot,
                                            be, aggr);
  k_dec<<<P_ * C_ * TILES_, 256, 0, stream>>>(x, aggr, Wd1, bd1, Wd2, bd2, out);
}

// Round 8
// 1158.382 us; speedup vs baseline: 7.7265x; 1.2019x over previous
//
#include <hip/hip_runtime.h>
#include <hip/hip_fp16.h>

#define P_ 3
#define N_ 100000
#define M_ 30000
#define E_ 200000
#define C_ 5
#define FP_ 64
#define FN_ 32
#define PFP_ 192     // P*FP
#define FPFN_ 96     // FP+FN
#define PE_ 600000   // P*E
#define PN_ 300000   // P*N
#define PM_ 90000    // P*M
#define NT_ 64       // nodes per projx tile
#define TILES_ ((N_ + NT_ - 1) / NT_)     // 1563
#define NTD_ 128     // nodes per decoder tile
#define TILESD_ ((N_ + NTD_ - 1) / NTD_)  // 782
#define CFN_ 160     // C*FN

typedef _Float16 f16x8 __attribute__((ext_vector_type(8)));
typedef float f32x4 __attribute__((ext_vector_type(4)));

__device__ __forceinline__ float fast_tanh(float v) {
  float x = fminf(fmaxf(v, -15.0f), 15.0f);
  float t = __expf(2.0f * x);
  return __fdividef(t - 1.0f, t + 1.0f);
}

__device__ __forceinline__ f16x8 ld8(const __half* p) {
  return *(const f16x8*)(const void*)p;
}

// ====================== CSR build ======================
__global__ void k_count(const int* __restrict__ esrc, const int* __restrict__ edst,
                        int* __restrict__ cnt_src, int* __restrict__ cnt_dst) {
  int i = blockIdx.x * 256 + threadIdx.x;
  if (i >= PE_) return;
  int p = i / E_;
  atomicAdd(&cnt_src[p * N_ + esrc[i]], 1);
  atomicAdd(&cnt_dst[p * M_ + edst[i]], 1);
}

// 3-pass exclusive scan (1024 elems/block)
__global__ void k_scan1(const int* __restrict__ in, int* __restrict__ out,
                        int* __restrict__ aux, int n) {
  __shared__ int lds[256];
  int b = blockIdx.x, t = threadIdx.x;
  int base = b * 1024 + t * 4;
  int v0 = (base + 0 < n) ? in[base + 0] : 0;
  int v1 = (base + 1 < n) ? in[base + 1] : 0;
  int v2 = (base + 2 < n) ? in[base + 2] : 0;
  int v3 = (base + 3 < n) ? in[base + 3] : 0;
  lds[t] = v0 + v1 + v2 + v3;
  __syncthreads();
  for (int off = 1; off < 256; off <<= 1) {
    int xv = (t >= off) ? lds[t - off] : 0;
    __syncthreads();
    lds[t] += xv;
    __syncthreads();
  }
  if (t == 255) aux[b] = lds[255];
  int run = (t == 0) ? 0 : lds[t - 1];
  if (base + 0 < n) out[base + 0] = run; run += v0;
  if (base + 1 < n) out[base + 1] = run; run += v1;
  if (base + 2 < n) out[base + 2] = run; run += v2;
  if (base + 3 < n) out[base + 3] = run;
}

__global__ void k_scan2(int* __restrict__ aux, int nb, int* __restrict__ off_end) {
  __shared__ int lds[1024];
  int t = threadIdx.x;
  lds[t] = (t < nb) ? aux[t] : 0;
  __syncthreads();
  for (int off = 1; off < 1024; off <<= 1) {
    int xv = (t >= off) ? lds[t - off] : 0;
    __syncthreads();
    lds[t] += xv;
    __syncthreads();
  }
  if (t < nb) aux[t] = (t == 0) ? 0 : lds[t - 1];
  if (t == 0) off_end[0] = lds[nb - 1];
}

__global__ void k_scan3(int* __restrict__ out, const int* __restrict__ aux, int n) {
  int i = blockIdx.x * 256 + threadIdx.x;
  if (i < n) out[i] += aux[i >> 10];
}

__global__ void k_fill(const int* __restrict__ esrc, const int* __restrict__ edst,
                       int* __restrict__ cur_src, int* __restrict__ cur_dst,
                       int* __restrict__ list_src, int* __restrict__ list_dst) {
  int i = blockIdx.x * 256 + threadIdx.x;
  if (i >= PE_) return;
  int p = i / E_;
  int s = esrc[i], d = edst[i];
  int ps = atomicAdd(&cur_src[p * N_ + s], 1);
  list_src[ps] = d;
  int pd = atomicAdd(&cur_dst[p * M_ + d], 1);
  list_dst[pd] = s;
}

// ====================== xdot: per-node x part of edge logit ======================
__global__ void k_xdot(const float* __restrict__ x, const float* __restrict__ We,
                       float* __restrict__ xdot) {
  int t = threadIdx.x;
  int pn = blockIdx.x * 4 + (t >> 6);
  if (pn >= PN_) return;
  int lane = t & 63;
  int p = pn / N_;
  const float* row = &x[(long long)pn * (C_ * FP_)];
  #pragma unroll
  for (int c = 0; c < C_; ++c) {
    float v = row[c * FP_ + lane] * We[(p * C_ + c) * FPFN_ + lane];
    #pragma unroll
    for (int off = 32; off > 0; off >>= 1) v += __shfl_down(v, off);
    if (lane == 0) xdot[pn * C_ + c] = v;
  }
}

// ====================== projx: streaming y[p,n,c,j] = Wn1_p-block . x[p,n,c,:] ====
__global__ __launch_bounds__(320) void k_projx(
    const float* __restrict__ x, const float* __restrict__ Wn1,
    __half* __restrict__ y) {
  __shared__ __half xs[NT_ * 320];   // 40 KB
  int bp = blockIdx.x;
  int p = bp / TILES_, tile = bp % TILES_;
  int base = tile * NT_;
  int rows = min(NT_, N_ - base);
  int t = threadIdx.x;
  int g = t / CFN_, u = t % CFN_;
  int c = u >> 5;

  __half2 w[32];
  {
    const float* wr = &Wn1[(size_t)u * PFP_ + p * FP_];
    #pragma unroll
    for (int i = 0; i < 32; ++i) w[i] = __floats2half2_rn(wr[2*i], wr[2*i+1]);
  }

  const float* xb = x + (size_t)(p * N_ + base) * (C_ * FP_);
  int tot = rows * 320;
  for (int f = t * 4; f < tot; f += 320 * 4) {
    float4 v = *(const float4*)(xb + f);
    __half2* dst = (__half2*)&xs[f];
    dst[0] = __floats2half2_rn(v.x, v.y);
    dst[1] = __floats2half2_rn(v.z, v.w);
  }
  __syncthreads();

  for (int r = g; r < rows; r += 2) {
    const __half2* xr = (const __half2*)&xs[r * 320 + c * FP_];
    __half2 acc = __floats2half2_rn(0.f, 0.f);
    #pragma unroll
    for (int i = 0; i < 32; ++i) acc = __hfma2(xr[i], w[i], acc);
    float s = __low2float(acc) + __high2float(acc);
    y[(size_t)(p * N_ + base + r) * CFN_ + u] = __float2half(s);
  }
}

// ====================== nexus: gather y (L3-resident) = layer-1 preact ==========
__global__ __launch_bounds__(320) void k_nexus(
    const __half* __restrict__ y,
    const int* __restrict__ off_dst, const int* __restrict__ list_dst,
    const float* __restrict__ bn1,
    const float* __restrict__ Wn2, const float* __restrict__ bn2,
    const float* __restrict__ We,
    float* __restrict__ nout, float* __restrict__ ndot) {
  __shared__ float part[2][CFN_];
  __shared__ __align__(16) float h1S[CFN_];
  __shared__ __align__(16) float h2S[CFN_];
  int m = blockIdx.x;
  int t = threadIdx.x;
  int g = t / CFN_, u = t % CFN_;
  int c = u >> 5;

  float af = 0.f;
  #pragma unroll
  for (int p = 0; p < P_; ++p) {
    int o0 = off_dst[p * M_ + m];
    int o1 = off_dst[p * M_ + m + 1];
    const __half* yp = y + (size_t)p * N_ * CFN_;
    for (int e0 = o0 + g; e0 < o1; e0 += 8) {
      int e1 = e0 + 2, e2 = e0 + 4, e3 = e0 + 6;
      int s0 = list_dst[e0];
      int s1 = list_dst[e1 < o1 ? e1 : e0];
      int s2 = list_dst[e2 < o1 ? e2 : e0];
      int s3 = list_dst[e3 < o1 ? e3 : e0];
      float v0 = __half2float(yp[(size_t)s0 * CFN_ + u]);
      float v1 = __half2float(yp[(size_t)s1 * CFN_ + u]);
      float v2 = __half2float(yp[(size_t)s2 * CFN_ + u]);
      float v3 = __half2float(yp[(size_t)s3 * CFN_ + u]);
      af += v0;
      if (e1 < o1) af += v1;
      if (e2 < o1) af += v2;
      if (e3 < o1) af += v3;
    }
  }
  part[g][u] = af;
  __syncthreads();
  if (t < CFN_) {
    float pre = part[0][u] + part[1][u] + bn1[u];
    h1S[u] = fast_tanh(pre);
  }
  __syncthreads();
  if (t < CFN_) {
    const float4* f4 = (const float4*)&h1S[c * FN_];
    const float4* w4 = (const float4*)&Wn2[(size_t)u * FN_];
    float a = bn2[u];
    #pragma unroll
    for (int i = 0; i < FN_ / 4; ++i) {
      float4 f = f4[i], wv = w4[i];
      a += f.x * wv.x + f.y * wv.y + f.z * wv.z + f.w * wv.w;
    }
    float nv = fast_tanh(a);
    h2S[u] = nv;
    nout[(size_t)m * CFN_ + u] = nv;
  }
  __syncthreads();
  if (t < P_ * C_) {
    int p = t / C_, cc = t % C_;
    const float* wv = &We[(p * C_ + cc) * FPFN_ + FP_];
    float a = 0.f;
    #pragma unroll
    for (int j = 0; j < FN_; ++j) a += h2S[cc * FN_ + j] * wv[j];
    ndot[(size_t)(p * M_ + m) * C_ + cc] = a;
  }
}

// ====================== aggr: softmax-gated mean over src-CSR ======================
__global__ void k_aggr(const float* __restrict__ nout,
                       const int* __restrict__ off_src, const int* __restrict__ list_src,
                       const float* __restrict__ xdot, const float* __restrict__ ndot,
                       const float* __restrict__ be,
                       __half* __restrict__ aggr) {
  int t = threadIdx.x;
  int pn = blockIdx.x * 4 + (t >> 6);
  if (pn >= PN_) return;
  int lane = t & 63;
  int p = pn / N_;
  int o0 = off_src[pn], o1 = off_src[pn + 1];
  float base_c[C_];
  #pragma unroll
  for (int c = 0; c < C_; ++c) base_c[c] = xdot[pn * C_ + c] + be[p * C_ + c];

  float a0 = 0.f, a1 = 0.f, a2 = 0.f;
  for (int e = o0; e < o1; ++e) {
    int dst = list_src[e];
    const float* nr = &nout[(long long)dst * (C_ * FN_)];
    const float* nd = &ndot[(long long)(p * M_ + dst) * C_];
    float l[C_];
    #pragma unroll
    for (int c = 0; c < C_; ++c) l[c] = base_c[c] + nd[c];
    float mx = fmaxf(fmaxf(fmaxf(l[0], l[1]), fmaxf(l[2], l[3])), l[4]);
    float s = 0.f;
    #pragma unroll
    for (int c = 0; c < C_; ++c) { l[c] = __expf(l[c] - mx); s += l[c]; }
    float inv = __fdividef(1.0f, s);
    float wA = ((lane & 32) ? l[1] : l[0]) * inv;
    float wB = ((lane & 32) ? l[3] : l[2]) * inv;
    a0 += wA * nr[lane];
    a1 += wB * nr[64 + lane];
    if (lane < 32) a2 += l[4] * inv * nr[128 + lane];
  }
  float invd = __fdividef(1.0f, fmaxf((float)(o1 - o0), 1.0f));
  __half* out = &aggr[(long long)pn * (C_ * FN_)];
  out[lane]      = __float2half(a0 * invd);
  out[64 + lane] = __float2half(a1 * invd);
  if (lane < 32) out[128 + lane] = __float2half(a2 * invd);
}

// ====================== MFMA decoder ==========================================
// block = (p, c, 128-node tile), 256 threads = 4 waves, each wave 32 nodes.
// L1: [32x96]x[96x64] via 24 mfma_16x16x32_f16; L2: [32x64]x[64x64] via 16.
// Fragments: A row=l&15, k=8*(l>>4)+j; B col=l&15, k=8*(l>>4)+j;
//            D col=l&15, row=4*(l>>4)+reg.
__global__ __launch_bounds__(256, 2) void k_dec(
    const float* __restrict__ x, const __half* __restrict__ aggr,
    const float* __restrict__ Wd1, const float* __restrict__ bd1,
    const float* __restrict__ Wd2, const float* __restrict__ bd2,
    float* __restrict__ out) {
  __shared__ __half featS[NTD_ * 104];   // 26.6 KB  (96 used: x 64 | aggr 32)
  __shared__ __half w1S[64 * 104];       // 13.3 KB  (96 used)
  __shared__ __half w2S[64 * 72];        // 9.2 KB   (64 used)
  __shared__ __half hS[NTD_ * 72];       // 18.4 KB  (64 used)

  int bp = blockIdx.x;
  int pc = bp / TILESD_;
  int tile = bp % TILESD_;
  int p = pc / C_, c = pc % C_;
  int base = tile * NTD_;
  int rows = min(NTD_, N_ - base);

  int t = threadIdx.x;
  int w = t >> 6, l = t & 63;
  int l15 = l & 15, l4 = l >> 4;

  // ---- stage W1, W2 (fp32 -> fp16, padded rows) ----
  {
    int r = t >> 2, q = t & 3;
    const float* w1r = &Wd1[((size_t)(p * C_ + c) * FP_ + r) * FPFN_ + q * 24];
    __half2* d1 = (__half2*)&w1S[r * 104 + q * 24];
    #pragma unroll
    for (int i = 0; i < 6; ++i) {
      float4 v = ((const float4*)w1r)[i];
      d1[2*i]   = __floats2half2_rn(v.x, v.y);
      d1[2*i+1] = __floats2half2_rn(v.z, v.w);
    }
    const float* w2r = &Wd2[((size_t)(p * C_ + c) * FP_ + r) * FP_ + q * 16];
    __half2* d2 = (__half2*)&w2S[r * 72 + q * 16];
    #pragma unroll
    for (int i = 0; i < 4; ++i) {
      float4 v = ((const float4*)w2r)[i];
      d2[2*i]   = __floats2half2_rn(v.x, v.y);
      d2[2*i+1] = __floats2half2_rn(v.z, v.w);
    }
  }
  // ---- stage feat: x (fp32->fp16) + aggr (fp16 copy) ----
  for (int idx = t; idx < NTD_ * 16; idx += 256) {
    int node = idx >> 4, fq = idx & 15;
    if (node < rows) {
      float4 v = *(const float4*)&x[(size_t)(p * N_ + base + node) * 320 + c * 64 + fq * 4];
      __half2* dst = (__half2*)&featS[node * 104 + fq * 4];
      dst[0] = __floats2half2_rn(v.x, v.y);
      dst[1] = __floats2half2_rn(v.z, v.w);
    }
  }
  for (int idx = t; idx < NTD_ * 4; idx += 256) {
    int node = idx >> 2, q = idx & 3;
    if (node < rows) {
      float4 v = *(const float4*)&aggr[(size_t)(p * N_ + base + node) * CFN_ + c * 32 + q * 8];
      *(float4*)&featS[node * 104 + 64 + q * 8] = v;
    }
  }
  __syncthreads();

  int rbase = w * 32;   // this wave's node window [rbase, rbase+32)

  // ---- L1: acc[rt][tt] += A(feat) x B(W1) ----
  f32x4 acc[2][4];
  #pragma unroll
  for (int tt = 0; tt < 4; ++tt) {
    float bv = bd1[(p * C_ + c) * FP_ + tt * 16 + l15];
    #pragma unroll
    for (int rt = 0; rt < 2; ++rt) acc[rt][tt] = (f32x4){bv, bv, bv, bv};
  }
  #pragma unroll
  for (int s = 0; s < 3; ++s) {
    f16x8 a0 = ld8(&featS[(rbase + l15) * 104 + s * 32 + l4 * 8]);
    f16x8 a1 = ld8(&featS[(rbase + 16 + l15) * 104 + s * 32 + l4 * 8]);
    #pragma unroll
    for (int tt = 0; tt < 4; ++tt) {
      f16x8 b = ld8(&w1S[(tt * 16 + l15) * 104 + s * 32 + l4 * 8]);
      acc[0][tt] = __builtin_amdgcn_mfma_f32_16x16x32_f16(a0, b, acc[0][tt], 0, 0, 0);
      acc[1][tt] = __builtin_amdgcn_mfma_f32_16x16x32_f16(a1, b, acc[1][tt], 0, 0, 0);
    }
  }
  // tanh -> hS (same-wave rows only; lgkmcnt ordering suffices, no barrier)
  #pragma unroll
  for (int rt = 0; rt < 2; ++rt)
    #pragma unroll
    for (int tt = 0; tt < 4; ++tt) {
      #pragma unroll
      for (int r = 0; r < 4; ++r) {
        int nrow = rbase + rt * 16 + l4 * 4 + r;
        hS[nrow * 72 + tt * 16 + l15] = __float2half(fast_tanh(acc[rt][tt][r]));
      }
    }

  // ---- L2: acc2 += A(hS) x B(W2) ----
  f32x4 acc2[2][4];
  #pragma unroll
  for (int tt = 0; tt < 4; ++tt) {
    float bv = bd2[(p * C_ + c) * FP_ + tt * 16 + l15];
    #pragma unroll
    for (int rt = 0; rt < 2; ++rt) acc2[rt][tt] = (f32x4){bv, bv, bv, bv};
  }
  #pragma unroll
  for (int s = 0; s < 2; ++s) {
    f16x8 a0 = ld8(&hS[(rbase + l15) * 72 + s * 32 + l4 * 8]);
    f16x8 a1 = ld8(&hS[(rbase + 16 + l15) * 72 + s * 32 + l4 * 8]);
    #pragma unroll
    for (int tt = 0; tt < 4; ++tt) {
      f16x8 b = ld8(&w2S[(tt * 16 + l15) * 72 + s * 32 + l4 * 8]);
      acc2[0][tt] = __builtin_amdgcn_mfma_f32_16x16x32_f16(a0, b, acc2[0][tt], 0, 0, 0);
      acc2[1][tt] = __builtin_amdgcn_mfma_f32_16x16x32_f16(a1, b, acc2[1][tt], 0, 0, 0);
    }
  }
  // tanh -> global
  #pragma unroll
  for (int rt = 0; rt < 2; ++rt)
    #pragma unroll
    for (int tt = 0; tt < 4; ++tt) {
      #pragma unroll
      for (int r = 0; r < 4; ++r) {
        int nrow = rbase + rt * 16 + l4 * 4 + r;
        int node = base + nrow;
        if (node < N_) {
          out[(size_t)(p * N_ + node) * 320 + c * 64 + tt * 16 + l15] =
              fast_tanh(acc2[rt][tt][r]);
        }
      }
    }
}

// ====================== launch ======================
// workspace layout (4-byte words):
//   [0, 24M words) : y (half[48M]) during projx/nexus, THEN aggr (half[48M])
#define WS_AGGR  0ll          // half[48,000,000] = 24,000,000 words (also y)
#define WS_NOUT  24000000ll   // float[4,800,000]
#define WS_XDOT  28800000ll   // float[1,500,000]
#define WS_NDOT  30300000ll   // float[450,000]
#define WS_OFFS  30750000ll   // int[300,001]
#define WS_OFFD  31050001ll   // int[90,001]
#define WS_CURS  31140002ll   // int[300,000]
#define WS_CURD  31440002ll   // int[90,000]
#define WS_LISTS 31530002ll   // int[600,000]
#define WS_LISTD 32130002ll   // int[600,000]
#define WS_AUX1  32730002ll   // int[512]
#define WS_AUX2  32730514ll   // int[512]

extern "C" void kernel_launch(void* const* d_in, const int* in_sizes, int n_in,
                              void* d_out, int out_size, void* d_ws, size_t ws_size,
                              hipStream_t stream) {
  const float* x   = (const float*)d_in[0];
  const int* esrc  = (const int*)d_in[2];
  const int* edst  = (const int*)d_in[3];
  const float* Wn1 = (const float*)d_in[4];
  const float* bn1 = (const float*)d_in[5];
  const float* Wn2 = (const float*)d_in[6];
  const float* bn2 = (const float*)d_in[7];
  const float* We  = (const float*)d_in[8];
  const float* be  = (const float*)d_in[9];
  const float* Wd1 = (const float*)d_in[10];
  const float* bd1 = (const float*)d_in[11];
  const float* Wd2 = (const float*)d_in[12];
  const float* bd2 = (const float*)d_in[13];
  float* out = (float*)d_out;

  float* wsf = (float*)d_ws;
  int*   wsi = (int*)d_ws;
  __half* aggr = (__half*)d_ws;      // and y, time-shared
  __half* ybuf = (__half*)d_ws;
  float* nout = wsf + WS_NOUT;
  float* xdot = wsf + WS_XDOT;
  float* ndot = wsf + WS_NDOT;
  int* off_src = wsi + WS_OFFS;
  int* off_dst = wsi + WS_OFFD;
  int* cur_src = wsi + WS_CURS;
  int* cur_dst = wsi + WS_CURD;
  int* list_src = wsi + WS_LISTS;
  int* list_dst = wsi + WS_LISTD;
  int* aux1 = wsi + WS_AUX1;
  int* aux2 = wsi + WS_AUX2;

  // ---- CSR build ----
  hipMemsetAsync(cur_src, 0, PN_ * sizeof(int), stream);
  hipMemsetAsync(cur_dst, 0, PM_ * sizeof(int), stream);
  k_count<<<(PE_ + 255) / 256, 256, 0, stream>>>(esrc, edst, cur_src, cur_dst);
  {
    int nb_s = (PN_ + 1023) / 1024;   // 293
    int nb_d = (PM_ + 1023) / 1024;   // 88
    k_scan1<<<nb_s, 256, 0, stream>>>(cur_src, off_src, aux1, PN_);
    k_scan1<<<nb_d, 256, 0, stream>>>(cur_dst, off_dst, aux2, PM_);
    k_scan2<<<1, 1024, 0, stream>>>(aux1, nb_s, off_src + PN_);
    k_scan2<<<1, 1024, 0, stream>>>(aux2, nb_d, off_dst + PM_);
    k_scan3<<<(PN_ + 255) / 256, 256, 0, stream>>>(off_src, aux1, PN_);
    k_scan3<<<(PM_ + 255) / 256, 256, 0, stream>>>(off_dst, aux2, PM_);
  }
  hipMemcpyAsync(cur_src, off_src, PN_ * sizeof(int), hipMemcpyDeviceToDevice, stream);
  hipMemcpyAsync(cur_dst, off_dst, PM_ * sizeof(int), hipMemcpyDeviceToDevice, stream);
  k_fill<<<(PE_ + 255) / 256, 256, 0, stream>>>(esrc, edst, cur_src, cur_dst,
                                                list_src, list_dst);

  // ---- stages ----
  k_projx<<<P_ * TILES_, 320, 0, stream>>>(x, Wn1, ybuf);
  k_xdot<<<(PN_ + 3) / 4, 256, 0, stream>>>(x, We, xdot);
  k_nexus<<<M_, 320, 0, stream>>>(ybuf, off_dst, list_dst, bn1, Wn2, bn2, We,
                                  nout, ndot);
  k_aggr<<<(PN_ + 3) / 4, 256, 0, stream>>>(nout, off_src, list_src, xdot, ndot,
                                            be, aggr);
  k_dec<<<P_ * C_ * TILESD_, 256, 0, stream>>>(x, aggr, Wd1, bd1, Wd2, bd2, out);
}

// Round 9
// 968.894 us; speedup vs baseline: 9.2375x; 1.1956x over previous
//
#include <hip/hip_runtime.h>
#include <hip/hip_fp16.h>

#define P_ 3
#define N_ 100000
#define M_ 30000
#define E_ 200000
#define C_ 5
#define FP_ 64
#define FN_ 32
#define PFP_ 192     // P*FP
#define FPFN_ 96     // FP+FN
#define PE_ 600000   // P*E
#define PN_ 300000   // P*N
#define PM_ 90000    // P*M
#define NT_ 64       // nodes per projx tile
#define TILES_ ((N_ + NT_ - 1) / NT_)     // 1563
#define NTD_ 128     // nodes per decoder tile
#define TILESD_ ((N_ + NTD_ - 1) / NTD_)  // 782
#define CFN_ 160     // C*FN
#define NW1_ 92160   // 15*64*96
#define NW2_ 61440   // 15*64*64

typedef _Float16 f16x8 __attribute__((ext_vector_type(8)));
typedef float f32x4 __attribute__((ext_vector_type(4)));

__device__ __forceinline__ float fast_tanh(float v) {
  float x = fminf(fmaxf(v, -15.0f), 15.0f);
  float t = __expf(2.0f * x);
  return __fdividef(t - 1.0f, t + 1.0f);
}

__device__ __forceinline__ f16x8 ld8(const __half* p) {
  return *(const f16x8*)(const void*)p;
}

// ====================== CSR build ======================
__global__ void k_count(const int* __restrict__ esrc, const int* __restrict__ edst,
                        int* __restrict__ cnt_src, int* __restrict__ cnt_dst) {
  int i = blockIdx.x * 256 + threadIdx.x;
  if (i >= PE_) return;
  int p = i / E_;
  atomicAdd(&cnt_src[p * N_ + esrc[i]], 1);
  atomicAdd(&cnt_dst[p * M_ + edst[i]], 1);
}

// 3-pass exclusive scan (1024 elems/block)
__global__ void k_scan1(const int* __restrict__ in, int* __restrict__ out,
                        int* __restrict__ aux, int n) {
  __shared__ int lds[256];
  int b = blockIdx.x, t = threadIdx.x;
  int base = b * 1024 + t * 4;
  int v0 = (base + 0 < n) ? in[base + 0] : 0;
  int v1 = (base + 1 < n) ? in[base + 1] : 0;
  int v2 = (base + 2 < n) ? in[base + 2] : 0;
  int v3 = (base + 3 < n) ? in[base + 3] : 0;
  lds[t] = v0 + v1 + v2 + v3;
  __syncthreads();
  for (int off = 1; off < 256; off <<= 1) {
    int xv = (t >= off) ? lds[t - off] : 0;
    __syncthreads();
    lds[t] += xv;
    __syncthreads();
  }
  if (t == 255) aux[b] = lds[255];
  int run = (t == 0) ? 0 : lds[t - 1];
  if (base + 0 < n) out[base + 0] = run; run += v0;
  if (base + 1 < n) out[base + 1] = run; run += v1;
  if (base + 2 < n) out[base + 2] = run; run += v2;
  if (base + 3 < n) out[base + 3] = run;
}

__global__ void k_scan2(int* __restrict__ aux, int nb, int* __restrict__ off_end) {
  __shared__ int lds[1024];
  int t = threadIdx.x;
  lds[t] = (t < nb) ? aux[t] : 0;
  __syncthreads();
  for (int off = 1; off < 1024; off <<= 1) {
    int xv = (t >= off) ? lds[t - off] : 0;
    __syncthreads();
    lds[t] += xv;
    __syncthreads();
  }
  if (t < nb) aux[t] = (t == 0) ? 0 : lds[t - 1];
  if (t == 0) off_end[0] = lds[nb - 1];
}

__global__ void k_scan3(int* __restrict__ out, const int* __restrict__ aux, int n) {
  int i = blockIdx.x * 256 + threadIdx.x;
  if (i < n) out[i] += aux[i >> 10];
}

__global__ void k_fill(const int* __restrict__ esrc, const int* __restrict__ edst,
                       int* __restrict__ cur_src, int* __restrict__ cur_dst,
                       int* __restrict__ list_src, int* __restrict__ list_dst) {
  int i = blockIdx.x * 256 + threadIdx.x;
  if (i >= PE_) return;
  int p = i / E_;
  int s = esrc[i], d = edst[i];
  int ps = atomicAdd(&cur_src[p * N_ + s], 1);
  list_src[ps] = d;
  int pd = atomicAdd(&cur_dst[p * M_ + d], 1);
  list_dst[pd] = s;
}

// ====================== wconv: decoder weights fp32 -> fp16 (B-frag layout) ====
__global__ void k_wconv(const float* __restrict__ Wd1, const float* __restrict__ Wd2,
                        __half* __restrict__ w1h, __half* __restrict__ w2h) {
  int i = blockIdx.x * 256 + threadIdx.x;
  if (i < NW1_) w1h[i] = __float2half(Wd1[i]);
  if (i < NW2_) w2h[i] = __float2half(Wd2[i]);
}

// ====================== projx: y = Wn1_p-block . x  (+ fused xdot) =============
__global__ __launch_bounds__(320) void k_projx(
    const float* __restrict__ x, const float* __restrict__ Wn1,
    const float* __restrict__ We,
    __half* __restrict__ y, float* __restrict__ xdot) {
  __shared__ __half xs[NT_ * 320];   // 40 KB
  int bp = blockIdx.x;
  int p = bp / TILES_, tile = bp % TILES_;
  int base = tile * NT_;
  int rows = min(NT_, N_ - base);
  int t = threadIdx.x;
  int g = t / CFN_, u = t % CFN_;
  int c = u >> 5;

  __half2 w[32];
  {
    const float* wr = &Wn1[(size_t)u * PFP_ + p * FP_];
    #pragma unroll
    for (int i = 0; i < 32; ++i) w[i] = __floats2half2_rn(wr[2*i], wr[2*i+1]);
  }

  const float* xb = x + (size_t)(p * N_ + base) * (C_ * FP_);
  int tot = rows * 320;
  for (int f = t * 4; f < tot; f += 320 * 4) {
    float4 v = *(const float4*)(xb + f);
    __half2* dst = (__half2*)&xs[f];
    dst[0] = __floats2half2_rn(v.x, v.y);
    dst[1] = __floats2half2_rn(v.z, v.w);
  }
  __syncthreads();

  for (int r = g; r < rows; r += 2) {
    const __half2* xr = (const __half2*)&xs[r * 320 + c * FP_];
    __half2 acc = __floats2half2_rn(0.f, 0.f);
    #pragma unroll
    for (int i = 0; i < 32; ++i) acc = __hfma2(xr[i], w[i], acc);
    float s = __low2float(acc) + __high2float(acc);
    y[(size_t)(p * N_ + base + r) * CFN_ + u] = __float2half(s);
  }

  // fused xdot: t -> (cx = t>>6, node = t&63)
  {
    int cx = t >> 6, nodex = t & 63;
    if (nodex < rows) {
      const __half2* xr = (const __half2*)&xs[nodex * 320 + cx * FP_];
      const float2* wer = (const float2*)&We[(p * C_ + cx) * FPFN_];
      float s = 0.f;
      #pragma unroll
      for (int i = 0; i < 32; ++i) {
        float2 wv = wer[i];
        __half2 xv = xr[i];
        s += __low2float(xv) * wv.x + __high2float(xv) * wv.y;
      }
      xdot[(size_t)(p * N_ + base + nodex) * C_ + cx] = s;
    }
  }
}

// ====================== nexus: gather y (L3-resident) = layer-1 preact ==========
__global__ __launch_bounds__(320) void k_nexus(
    const __half* __restrict__ y,
    const int* __restrict__ off_dst, const int* __restrict__ list_dst,
    const float* __restrict__ bn1,
    const float* __restrict__ Wn2, const float* __restrict__ bn2,
    const float* __restrict__ We,
    float* __restrict__ nout, float* __restrict__ ndot) {
  __shared__ float part[2][CFN_];
  __shared__ __align__(16) float h1S[CFN_];
  __shared__ __align__(16) float h2S[CFN_];
  int m = blockIdx.x;
  int t = threadIdx.x;
  int g = t / CFN_, u = t % CFN_;
  int c = u >> 5;

  float af = 0.f;
  #pragma unroll
  for (int p = 0; p < P_; ++p) {
    int o0 = off_dst[p * M_ + m];
    int o1 = off_dst[p * M_ + m + 1];
    const __half* yp = y + (size_t)p * N_ * CFN_;
    for (int e0 = o0 + g; e0 < o1; e0 += 8) {
      int e1 = e0 + 2, e2 = e0 + 4, e3 = e0 + 6;
      int s0 = list_dst[e0];
      int s1 = list_dst[e1 < o1 ? e1 : e0];
      int s2 = list_dst[e2 < o1 ? e2 : e0];
      int s3 = list_dst[e3 < o1 ? e3 : e0];
      float v0 = __half2float(yp[(size_t)s0 * CFN_ + u]);
      float v1 = __half2float(yp[(size_t)s1 * CFN_ + u]);
      float v2 = __half2float(yp[(size_t)s2 * CFN_ + u]);
      float v3 = __half2float(yp[(size_t)s3 * CFN_ + u]);
      af += v0;
      if (e1 < o1) af += v1;
      if (e2 < o1) af += v2;
      if (e3 < o1) af += v3;
    }
  }
  part[g][u] = af;
  __syncthreads();
  if (t < CFN_) {
    float pre = part[0][u] + part[1][u] + bn1[u];
    h1S[u] = fast_tanh(pre);
  }
  __syncthreads();
  if (t < CFN_) {
    const float4* f4 = (const float4*)&h1S[c * FN_];
    const float4* w4 = (const float4*)&Wn2[(size_t)u * FN_];
    float a = bn2[u];
    #pragma unroll
    for (int i = 0; i < FN_ / 4; ++i) {
      float4 f = f4[i], wv = w4[i];
      a += f.x * wv.x + f.y * wv.y + f.z * wv.z + f.w * wv.w;
    }
    float nv = fast_tanh(a);
    h2S[u] = nv;
    nout[(size_t)m * CFN_ + u] = nv;
  }
  __syncthreads();
  if (t < P_ * C_) {
    int p = t / C_, cc = t % C_;
    const float* wv = &We[(p * C_ + cc) * FPFN_ + FP_];
    float a = 0.f;
    #pragma unroll
    for (int j = 0; j < FN_; ++j) a += h2S[cc * FN_ + j] * wv[j];
    ndot[(size_t)(p * M_ + m) * C_ + cc] = a;
  }
}

// ====================== aggr: softmax-gated mean over src-CSR ======================
__global__ void k_aggr(const float* __restrict__ nout,
                       const int* __restrict__ off_src, const int* __restrict__ list_src,
                       const float* __restrict__ xdot, const float* __restrict__ ndot,
                       const float* __restrict__ be,
                       __half* __restrict__ aggr) {
  int t = threadIdx.x;
  int pn = blockIdx.x * 4 + (t >> 6);
  if (pn >= PN_) return;
  int lane = t & 63;
  int p = pn / N_;
  int o0 = off_src[pn], o1 = off_src[pn + 1];
  float base_c[C_];
  #pragma unroll
  for (int c = 0; c < C_; ++c) base_c[c] = xdot[pn * C_ + c] + be[p * C_ + c];

  float a0 = 0.f, a1 = 0.f, a2 = 0.f;
  for (int e = o0; e < o1; ++e) {
    int dst = list_src[e];
    const float* nr = &nout[(long long)dst * (C_ * FN_)];
    const float* nd = &ndot[(long long)(p * M_ + dst) * C_];
    float l[C_];
    #pragma unroll
    for (int c = 0; c < C_; ++c) l[c] = base_c[c] + nd[c];
    float mx = fmaxf(fmaxf(fmaxf(l[0], l[1]), fmaxf(l[2], l[3])), l[4]);
    float s = 0.f;
    #pragma unroll
    for (int c = 0; c < C_; ++c) { l[c] = __expf(l[c] - mx); s += l[c]; }
    float inv = __fdividef(1.0f, s);
    float wA = ((lane & 32) ? l[1] : l[0]) * inv;
    float wB = ((lane & 32) ? l[3] : l[2]) * inv;
    a0 += wA * nr[lane];
    a1 += wB * nr[64 + lane];
    if (lane < 32) a2 += l[4] * inv * nr[128 + lane];
  }
  float invd = __fdividef(1.0f, fmaxf((float)(o1 - o0), 1.0f));
  __half* out = &aggr[(long long)pn * (C_ * FN_)];
  out[lane]      = __float2half(a0 * invd);
  out[64 + lane] = __float2half(a1 * invd);
  if (lane < 32) out[128 + lane] = __float2half(a2 * invd);
}

// ====================== MFMA decoder (weights direct from fp16 global) =========
// block = (p, c, 128-node tile), 256 threads = 4 waves, each wave 32 nodes.
// Fragments: A row=l&15, k=8*(l>>4)+j; B col=l&15, k=8*(l>>4)+j;
//            D col=l&15, row=4*(l>>4)+reg.
__global__ __launch_bounds__(256, 3) void k_dec(
    const float* __restrict__ x, const __half* __restrict__ aggr,
    const __half* __restrict__ w1h, const float* __restrict__ bd1,
    const __half* __restrict__ w2h, const float* __restrict__ bd2,
    float* __restrict__ out) {
  __shared__ __half featS[NTD_ * 104];   // 26.6 KB  (96 used: x 64 | aggr 32)
  __shared__ __half hS[NTD_ * 72];       // 18.4 KB  (64 used)

  int bp = blockIdx.x;
  int pc = bp / TILESD_;
  int tile = bp % TILESD_;
  int p = pc / C_, c = pc % C_;
  int base = tile * NTD_;
  int rows = min(NTD_, N_ - base);

  int t = threadIdx.x;
  int w = t >> 6, l = t & 63;
  int l15 = l & 15, l4 = l >> 4;

  // ---- stage feat: x (fp32->fp16) + aggr (fp16 copy) ----
  for (int idx = t; idx < NTD_ * 16; idx += 256) {
    int node = idx >> 4, fq = idx & 15;
    if (node < rows) {
      float4 v = *(const float4*)&x[(size_t)(p * N_ + base + node) * 320 + c * 64 + fq * 4];
      __half2* dst = (__half2*)&featS[node * 104 + fq * 4];
      dst[0] = __floats2half2_rn(v.x, v.y);
      dst[1] = __floats2half2_rn(v.z, v.w);
    }
  }
  for (int idx = t; idx < NTD_ * 4; idx += 256) {
    int node = idx >> 2, q = idx & 3;
    if (node < rows) {
      float4 v = *(const float4*)&aggr[(size_t)(p * N_ + base + node) * CFN_ + c * 32 + q * 8];
      *(float4*)&featS[node * 104 + 64 + q * 8] = v;
    }
  }
  __syncthreads();

  int rbase = w * 32;   // this wave's node window [rbase, rbase+32)
  const __half* w1g = w1h + (size_t)(p * C_ + c) * 64 * 96;
  const __half* w2g = w2h + (size_t)(p * C_ + c) * 64 * 64;

  // ---- L1: acc[rt][tt] += A(feat) x B(W1) ----
  f32x4 acc[2][4];
  #pragma unroll
  for (int tt = 0; tt < 4; ++tt) {
    float bv = bd1[(p * C_ + c) * FP_ + tt * 16 + l15];
    #pragma unroll
    for (int rt = 0; rt < 2; ++rt) acc[rt][tt] = (f32x4){bv, bv, bv, bv};
  }
  #pragma unroll
  for (int s = 0; s < 3; ++s) {
    f16x8 a0 = ld8(&featS[(rbase + l15) * 104 + s * 32 + l4 * 8]);
    f16x8 a1 = ld8(&featS[(rbase + 16 + l15) * 104 + s * 32 + l4 * 8]);
    #pragma unroll
    for (int tt = 0; tt < 4; ++tt) {
      f16x8 b = ld8(&w1g[(tt * 16 + l15) * 96 + s * 32 + l4 * 8]);
      acc[0][tt] = __builtin_amdgcn_mfma_f32_16x16x32_f16(a0, b, acc[0][tt], 0, 0, 0);
      acc[1][tt] = __builtin_amdgcn_mfma_f32_16x16x32_f16(a1, b, acc[1][tt], 0, 0, 0);
    }
  }
  // tanh -> hS (same-wave rows only; lgkmcnt ordering suffices, no barrier)
  #pragma unroll
  for (int rt = 0; rt < 2; ++rt)
    #pragma unroll
    for (int tt = 0; tt < 4; ++tt) {
      #pragma unroll
      for (int r = 0; r < 4; ++r) {
        int nrow = rbase + rt * 16 + l4 * 4 + r;
        hS[nrow * 72 + tt * 16 + l15] = __float2half(fast_tanh(acc[rt][tt][r]));
      }
    }

  // ---- L2: acc2 += A(hS) x B(W2) ----
  f32x4 acc2[2][4];
  #pragma unroll
  for (int tt = 0; tt < 4; ++tt) {
    float bv = bd2[(p * C_ + c) * FP_ + tt * 16 + l15];
    #pragma unroll
    for (int rt = 0; rt < 2; ++rt) acc2[rt][tt] = (f32x4){bv, bv, bv, bv};
  }
  #pragma unroll
  for (int s = 0; s < 2; ++s) {
    f16x8 a0 = ld8(&hS[(rbase + l15) * 72 + s * 32 + l4 * 8]);
    f16x8 a1 = ld8(&hS[(rbase + 16 + l15) * 72 + s * 32 + l4 * 8]);
    #pragma unroll
    for (int tt = 0; tt < 4; ++tt) {
      f16x8 b = ld8(&w2g[(tt * 16 + l15) * 64 + s * 32 + l4 * 8]);
      acc2[0][tt] = __builtin_amdgcn_mfma_f32_16x16x32_f16(a0, b, acc2[0][tt], 0, 0, 0);
      acc2[1][tt] = __builtin_amdgcn_mfma_f32_16x16x32_f16(a1, b, acc2[1][tt], 0, 0, 0);
    }
  }
  // tanh -> global
  #pragma unroll
  for (int rt = 0; rt < 2; ++rt)
    #pragma unroll
    for (int tt = 0; tt < 4; ++tt) {
      #pragma unroll
      for (int r = 0; r < 4; ++r) {
        int nrow = rbase + rt * 16 + l4 * 4 + r;
        int node = base + nrow;
        if (node < N_) {
          out[(size_t)(p * N_ + node) * 320 + c * 64 + tt * 16 + l15] =
              fast_tanh(acc2[rt][tt][r]);
        }
      }
    }
}

// ====================== launch ======================
// workspace layout (4-byte words):
//   [0, 24M words) : y (half[48M]) during projx/nexus, THEN aggr (half[48M])
#define WS_AGGR  0ll          // half[48,000,000] = 24,000,000 words (also y)
#define WS_NOUT  24000000ll   // float[4,800,000]
#define WS_XDOT  28800000ll   // float[1,500,000]
#define WS_NDOT  30300000ll   // float[450,000]
#define WS_OFFS  30750000ll   // int[300,001]
#define WS_OFFD  31050001ll   // int[90,001]
#define WS_CURS  31140002ll   // int[300,000]
#define WS_CURD  31440002ll   // int[90,000]
#define WS_LISTS 31530002ll   // int[600,000]
#define WS_LISTD 32130002ll   // int[600,000]
#define WS_AUX1  32730002ll   // int[512]
#define WS_AUX2  32730514ll   // int[512]
#define WS_W1H   32731026ll   // half[92,160] = 46,080 words
#define WS_W2H   32777106ll   // half[61,440] = 30,720 words

extern "C" void kernel_launch(void* const* d_in, const int* in_sizes, int n_in,
                              void* d_out, int out_size, void* d_ws, size_t ws_size,
                              hipStream_t stream) {
  const float* x   = (const float*)d_in[0];
  const int* esrc  = (const int*)d_in[2];
  const int* edst  = (const int*)d_in[3];
  const float* Wn1 = (const float*)d_in[4];
  const float* bn1 = (const float*)d_in[5];
  const float* Wn2 = (const float*)d_in[6];
  const float* bn2 = (const float*)d_in[7];
  const float* We  = (const float*)d_in[8];
  const float* be  = (const float*)d_in[9];
  const float* Wd1 = (const float*)d_in[10];
  const float* bd1 = (const float*)d_in[11];
  const float* Wd2 = (const float*)d_in[12];
  const float* bd2 = (const float*)d_in[13];
  float* out = (float*)d_out;

  float* wsf = (float*)d_ws;
  int*   wsi = (int*)d_ws;
  __half* aggr = (__half*)d_ws;      // and y, time-shared
  __half* ybuf = (__half*)d_ws;
  float* nout = wsf + WS_NOUT;
  float* xdot = wsf + WS_XDOT;
  float* ndot = wsf + WS_NDOT;
  int* off_src = wsi + WS_OFFS;
  int* off_dst = wsi + WS_OFFD;
  int* cur_src = wsi + WS_CURS;
  int* cur_dst = wsi + WS_CURD;
  int* list_src = wsi + WS_LISTS;
  int* list_dst = wsi + WS_LISTD;
  int* aux1 = wsi + WS_AUX1;
  int* aux2 = wsi + WS_AUX2;
  __half* w1h = (__half*)(wsi + WS_W1H);
  __half* w2h = (__half*)(wsi + WS_W2H);

  // ---- independent precompute ----
  k_wconv<<<(NW1_ + 255) / 256, 256, 0, stream>>>(Wd1, Wd2, w1h, w2h);

  // ---- CSR build ----
  hipMemsetAsync(cur_src, 0, PN_ * sizeof(int), stream);
  hipMemsetAsync(cur_dst, 0, PM_ * sizeof(int), stream);
  k_count<<<(PE_ + 255) / 256, 256, 0, stream>>>(esrc, edst, cur_src, cur_dst);
  {
    int nb_s = (PN_ + 1023) / 1024;   // 293
    int nb_d = (PM_ + 1023) / 1024;   // 88
    k_scan1<<<nb_s, 256, 0, stream>>>(cur_src, off_src, aux1, PN_);
    k_scan1<<<nb_d, 256, 0, stream>>>(cur_dst, off_dst, aux2, PM_);
    k_scan2<<<1, 1024, 0, stream>>>(aux1, nb_s, off_src + PN_);
    k_scan2<<<1, 1024, 0, stream>>>(aux2, nb_d, off_dst + PM_);
    k_scan3<<<(PN_ + 255) / 256, 256, 0, stream>>>(off_src, aux1, PN_);
    k_scan3<<<(PM_ + 255) / 256, 256, 0, stream>>>(off_dst, aux2, PM_);
  }
  hipMemcpyAsync(cur_src, off_src, PN_ * sizeof(int), hipMemcpyDeviceToDevice, stream);
  hipMemcpyAsync(cur_dst, off_dst, PM_ * sizeof(int), hipMemcpyDeviceToDevice, stream);
  k_fill<<<(PE_ + 255) / 256, 256, 0, stream>>>(esrc, edst, cur_src, cur_dst,
                                                list_src, list_dst);

  // ---- stages ----
  k_projx<<<P_ * TILES_, 320, 0, stream>>>(x, Wn1, We, ybuf, xdot);
  k_nexus<<<M_, 320, 0, stream>>>(ybuf, off_dst, list_dst, bn1, Wn2, bn2, We,
                                  nout, ndot);
  k_aggr<<<(PN_ + 3) / 4, 256, 0, stream>>>(nout, off_src, list_src, xdot, ndot,
                                            be, aggr);
  k_dec<<<P_ * C_ * TILESD_, 256, 0, stream>>>(x, aggr, w1h, bd1, w2h, bd2, out);
}

// Round 11
// 962.239 us; speedup vs baseline: 9.3014x; 1.0069x over previous
//
#include <hip/hip_runtime.h>
#include <hip/hip_fp16.h>

#define P_ 3
#define N_ 100000
#define M_ 30000
#define E_ 200000
#define C_ 5
#define FP_ 64
#define FN_ 32
#define PFP_ 192     // P*FP
#define FPFN_ 96     // FP+FN
#define PE_ 600000   // P*E
#define PN_ 300000   // P*N
#define PM_ 90000    // P*M
#define NT_ 64       // nodes per projx tile
#define TILES_ ((N_ + NT_ - 1) / NT_)     // 1563
#define NTD_ 64      // nodes per decoder tile
#define TILESD_ ((N_ + NTD_ - 1) / NTD_)  // 1563
#define CFN_ 160     // C*FN
#define NW1_ 92160   // 15*64*96
#define NW2_ 61440   // 15*64*64

typedef _Float16 f16x8 __attribute__((ext_vector_type(8)));
typedef float f32x4 __attribute__((ext_vector_type(4)));

__device__ __forceinline__ float fast_tanh(float v) {
  float x = fminf(fmaxf(v, -15.0f), 15.0f);
  float t = __expf(2.0f * x);
  return __fdividef(t - 1.0f, t + 1.0f);
}

__device__ __forceinline__ f16x8 ld8(const __half* p) {
  return *(const f16x8*)(const void*)p;
}

// ====================== CSR build ======================
__global__ void k_count(const int* __restrict__ esrc, const int* __restrict__ edst,
                        int* __restrict__ cnt_src, int* __restrict__ cnt_dst) {
  int i = blockIdx.x * 256 + threadIdx.x;
  if (i >= PE_) return;
  int p = i / E_;
  atomicAdd(&cnt_src[p * N_ + esrc[i]], 1);
  atomicAdd(&cnt_dst[p * M_ + edst[i]], 1);
}

// 3-pass exclusive scan (1024 elems/block)
__global__ void k_scan1(const int* __restrict__ in, int* __restrict__ out,
                        int* __restrict__ aux, int n) {
  __shared__ int lds[256];
  int b = blockIdx.x, t = threadIdx.x;
  int base = b * 1024 + t * 4;
  int v0 = (base + 0 < n) ? in[base + 0] : 0;
  int v1 = (base + 1 < n) ? in[base + 1] : 0;
  int v2 = (base + 2 < n) ? in[base + 2] : 0;
  int v3 = (base + 3 < n) ? in[base + 3] : 0;
  lds[t] = v0 + v1 + v2 + v3;
  __syncthreads();
  for (int off = 1; off < 256; off <<= 1) {
    int xv = (t >= off) ? lds[t - off] : 0;
    __syncthreads();
    lds[t] += xv;
    __syncthreads();
  }
  if (t == 255) aux[b] = lds[255];
  int run = (t == 0) ? 0 : lds[t - 1];
  if (base + 0 < n) out[base + 0] = run; run += v0;
  if (base + 1 < n) out[base + 1] = run; run += v1;
  if (base + 2 < n) out[base + 2] = run; run += v2;
  if (base + 3 < n) out[base + 3] = run;
}

__global__ void k_scan2(int* __restrict__ aux, int nb, int* __restrict__ off_end) {
  __shared__ int lds[1024];
  int t = threadIdx.x;
  lds[t] = (t < nb) ? aux[t] : 0;
  __syncthreads();
  for (int off = 1; off < 1024; off <<= 1) {
    int xv = (t >= off) ? lds[t - off] : 0;
    __syncthreads();
    lds[t] += xv;
    __syncthreads();
  }
  if (t < nb) aux[t] = (t == 0) ? 0 : lds[t - 1];
  if (t == 0) off_end[0] = lds[nb - 1];
}

__global__ void k_scan3(int* __restrict__ out, const int* __restrict__ aux, int n) {
  int i = blockIdx.x * 256 + threadIdx.x;
  if (i < n) out[i] += aux[i >> 10];
}

__global__ void k_fill(const int* __restrict__ esrc, const int* __restrict__ edst,
                       int* __restrict__ cur_src, int* __restrict__ cur_dst,
                       int* __restrict__ list_src, int* __restrict__ list_dst) {
  int i = blockIdx.x * 256 + threadIdx.x;
  if (i >= PE_) return;
  int p = i / E_;
  int s = esrc[i], d = edst[i];
  int ps = atomicAdd(&cur_src[p * N_ + s], 1);
  list_src[ps] = d;
  int pd = atomicAdd(&cur_dst[p * M_ + d], 1);
  list_dst[pd] = s;
}

// ====================== wconv: decoder weights fp32 -> fp16 ====================
__global__ void k_wconv(const float* __restrict__ Wd1, const float* __restrict__ Wd2,
                        __half* __restrict__ w1h, __half* __restrict__ w2h) {
  int i = blockIdx.x * 256 + threadIdx.x;
  if (i < NW1_) w1h[i] = __float2half(Wd1[i]);
  if (i < NW2_) w2h[i] = __float2half(Wd2[i]);
}

// ====================== projx: y = Wn1_p-block . x  (+ fused xdot) =============
__global__ __launch_bounds__(320) void k_projx(
    const float* __restrict__ x, const float* __restrict__ Wn1,
    const float* __restrict__ We,
    __half* __restrict__ y, float* __restrict__ xdot) {
  __shared__ __half xs[NT_ * 320];   // 40 KB
  int bp = blockIdx.x;
  int p = bp / TILES_, tile = bp % TILES_;
  int base = tile * NT_;
  int rows = min(NT_, N_ - base);
  int t = threadIdx.x;
  int g = t / CFN_, u = t % CFN_;
  int c = u >> 5;

  __half2 w[32];
  {
    const float* wr = &Wn1[(size_t)u * PFP_ + p * FP_];
    #pragma unroll
    for (int i = 0; i < 32; ++i) w[i] = __floats2half2_rn(wr[2*i], wr[2*i+1]);
  }

  const float* xb = x + (size_t)(p * N_ + base) * (C_ * FP_);
  int tot = rows * 320;
  for (int f = t * 4; f < tot; f += 320 * 4) {
    float4 v = *(const float4*)(xb + f);
    __half2* dst = (__half2*)&xs[f];
    dst[0] = __floats2half2_rn(v.x, v.y);
    dst[1] = __floats2half2_rn(v.z, v.w);
  }
  __syncthreads();

  for (int r = g; r < rows; r += 2) {
    const __half2* xr = (const __half2*)&xs[r * 320 + c * FP_];
    __half2 acc = __floats2half2_rn(0.f, 0.f);
    #pragma unroll
    for (int i = 0; i < 32; ++i) acc = __hfma2(xr[i], w[i], acc);
    float s = __low2float(acc) + __high2float(acc);
    y[(size_t)(p * N_ + base + r) * CFN_ + u] = __float2half(s);
  }

  // fused xdot: t -> (cx = t>>6, node = t&63)
  {
    int cx = t >> 6, nodex = t & 63;
    if (nodex < rows) {
      const __half2* xr = (const __half2*)&xs[nodex * 320 + cx * FP_];
      const float2* wer = (const float2*)&We[(p * C_ + cx) * FPFN_];
      float s = 0.f;
      #pragma unroll
      for (int i = 0; i < 32; ++i) {
        float2 wv = wer[i];
        __half2 xv = xr[i];
        s += __low2float(xv) * wv.x + __high2float(xv) * wv.y;
      }
      xdot[(size_t)(p * N_ + base + nodex) * C_ + cx] = s;
    }
  }
}

// ====================== nexus: gather y (half2, 4 edge groups) =================
__global__ __launch_bounds__(320) void k_nexus(
    const __half* __restrict__ y,
    const int* __restrict__ off_dst, const int* __restrict__ list_dst,
    const float* __restrict__ bn1,
    const float* __restrict__ Wn2, const float* __restrict__ bn2,
    const float* __restrict__ We,
    float* __restrict__ nout, float* __restrict__ ndot) {
  __shared__ float part[4][CFN_];
  __shared__ __align__(16) float h1S[CFN_];
  __shared__ __align__(16) float h2S[CFN_];
  int m = blockIdx.x;
  int t = threadIdx.x;               // 320 = 4 groups x 80 half2-lanes
  int g = t / 80, u2 = t % 80;

  float afx = 0.f, afy = 0.f;
  #pragma unroll
  for (int p = 0; p < P_; ++p) {
    int o0 = off_dst[p * M_ + m];
    int o1 = off_dst[p * M_ + m + 1];
    const __half2* yp2 = (const __half2*)(y + (size_t)p * N_ * CFN_);
    for (int e0 = o0 + g; e0 < o1; e0 += 8) {   // batch-2 per group
      int e1 = e0 + 4;
      int s0 = list_dst[e0];
      int s1 = list_dst[e1 < o1 ? e1 : e0];
      __half2 v0 = yp2[(size_t)s0 * 80 + u2];
      __half2 v1 = yp2[(size_t)s1 * 80 + u2];
      afx += __low2float(v0); afy += __high2float(v0);
      if (e1 < o1) { afx += __low2float(v1); afy += __high2float(v1); }
    }
  }
  part[g][2 * u2]     = afx;
  part[g][2 * u2 + 1] = afy;
  __syncthreads();
  if (t < CFN_) {
    float pre = part[0][t] + part[1][t] + part[2][t] + part[3][t] + bn1[t];
    h1S[t] = fast_tanh(pre);
  }
  __syncthreads();
  if (t < CFN_) {
    int c = t >> 5;
    const float4* f4 = (const float4*)&h1S[c * FN_];
    const float4* w4 = (const float4*)&Wn2[(size_t)t * FN_];
    float a = bn2[t];
    #pragma unroll
    for (int i = 0; i < FN_ / 4; ++i) {
      float4 f = f4[i], wv = w4[i];
      a += f.x * wv.x + f.y * wv.y + f.z * wv.z + f.w * wv.w;
    }
    float nv = fast_tanh(a);
    h2S[t] = nv;
    nout[(size_t)m * CFN_ + t] = nv;
  }
  __syncthreads();
  if (t < P_ * C_) {
    int p = t / C_, cc = t % C_;
    const float* wv = &We[(p * C_ + cc) * FPFN_ + FP_];
    float a = 0.f;
    #pragma unroll
    for (int j = 0; j < FN_; ++j) a += h2S[cc * FN_ + j] * wv[j];
    ndot[(size_t)(p * M_ + m) * C_ + cc] = a;
  }
}

// ====================== aggr: softmax-gated mean (unroll-2 edges) ==============
__global__ void k_aggr(const float* __restrict__ nout,
                       const int* __restrict__ off_src, const int* __restrict__ list_src,
                       const float* __restrict__ xdot, const float* __restrict__ ndot,
                       const float* __restrict__ be,
                       __half* __restrict__ aggr) {
  int t = threadIdx.x;
  int pn = blockIdx.x * 4 + (t >> 6);
  if (pn >= PN_) return;
  int lane = t & 63;
  int p = pn / N_;
  int o0 = off_src[pn], o1 = off_src[pn + 1];
  float base_c[C_];
  #pragma unroll
  for (int c = 0; c < C_; ++c) base_c[c] = xdot[pn * C_ + c] + be[p * C_ + c];

  float a0 = 0.f, a1 = 0.f, a2 = 0.f;
  for (int e = o0; e < o1; e += 2) {
    int e1 = e + 1;
    int d0 = list_src[e];
    int d1 = list_src[e1 < o1 ? e1 : e];
    const float* nr0 = &nout[(size_t)d0 * CFN_];
    const float* nr1 = &nout[(size_t)d1 * CFN_];
    const float* nd0 = &ndot[(size_t)(p * M_ + d0) * C_];
    const float* nd1 = &ndot[(size_t)(p * M_ + d1) * C_];
    // issue all loads for both edges up front
    float r00 = nr0[lane], r01 = nr0[64 + lane];
    float r02 = (lane < 32) ? nr0[128 + lane] : 0.f;
    float r10 = nr1[lane], r11 = nr1[64 + lane];
    float r12 = (lane < 32) ? nr1[128 + lane] : 0.f;
    float l0[C_], l1[C_];
    #pragma unroll
    for (int c = 0; c < C_; ++c) { l0[c] = base_c[c] + nd0[c]; l1[c] = base_c[c] + nd1[c]; }
    // edge 0
    {
      float mx = fmaxf(fmaxf(fmaxf(l0[0], l0[1]), fmaxf(l0[2], l0[3])), l0[4]);
      float s = 0.f;
      #pragma unroll
      for (int c = 0; c < C_; ++c) { l0[c] = __expf(l0[c] - mx); s += l0[c]; }
      float inv = __fdividef(1.0f, s);
      float wA = ((lane & 32) ? l0[1] : l0[0]) * inv;
      float wB = ((lane & 32) ? l0[3] : l0[2]) * inv;
      a0 += wA * r00;
      a1 += wB * r01;
      a2 += l0[4] * inv * r02;
    }
    // edge 1 (if real)
    if (e1 < o1) {
      float mx = fmaxf(fmaxf(fmaxf(l1[0], l1[1]), fmaxf(l1[2], l1[3])), l1[4]);
      float s = 0.f;
      #pragma unroll
      for (int c = 0; c < C_; ++c) { l1[c] = __expf(l1[c] - mx); s += l1[c]; }
      float inv = __fdividef(1.0f, s);
      float wA = ((lane & 32) ? l1[1] : l1[0]) * inv;
      float wB = ((lane & 32) ? l1[3] : l1[2]) * inv;
      a0 += wA * r10;
      a1 += wB * r11;
      a2 += l1[4] * inv * r12;
    }
  }
  float invd = __fdividef(1.0f, fmaxf((float)(o1 - o0), 1.0f));
  __half* out = &aggr[(size_t)pn * CFN_];
  out[lane]      = __float2half(a0 * invd);
  out[64 + lane] = __float2half(a1 * invd);
  if (lane < 32) out[128 + lane] = __float2half(a2 * invd);
}

// ====================== MFMA decoder (64-node tiles, 2 waves, 128 threads) =====
// Fragments: A row=l&15, k=8*(l>>4)+j; B col=l&15, k=8*(l>>4)+j;
//            D col=l&15, row=4*(l>>4)+reg.
__global__ __launch_bounds__(128, 4) void k_dec(
    const float* __restrict__ x, const __half* __restrict__ aggr,
    const __half* __restrict__ w1h, const float* __restrict__ bd1,
    const __half* __restrict__ w2h, const float* __restrict__ bd2,
    float* __restrict__ out) {
  __shared__ __half featS[NTD_ * 104];   // 13.3 KB  (96 used: x 64 | aggr 32)
  __shared__ __half hS[NTD_ * 72];       // 9.2 KB   (64 used)

  int bp = blockIdx.x;
  int pc = bp / TILESD_;
  int tile = bp % TILESD_;
  int p = pc / C_, c = pc % C_;
  int base = tile * NTD_;
  int rows = min(NTD_, N_ - base);

  int t = threadIdx.x;
  int w = t >> 6, l = t & 63;
  int l15 = l & 15, l4 = l >> 4;

  // ---- stage feat: x (fp32->fp16) + aggr (fp16 copy) ----
  for (int idx = t; idx < NTD_ * 16; idx += 128) {
    int node = idx >> 4, fq = idx & 15;
    if (node < rows) {
      float4 v = *(const float4*)&x[(size_t)(p * N_ + base + node) * 320 + c * 64 + fq * 4];
      __half2* dst = (__half2*)&featS[node * 104 + fq * 4];
      dst[0] = __floats2half2_rn(v.x, v.y);
      dst[1] = __floats2half2_rn(v.z, v.w);
    }
  }
  for (int idx = t; idx < NTD_ * 4; idx += 128) {
    int node = idx >> 2, q = idx & 3;
    if (node < rows) {
      float4 v = *(const float4*)&aggr[(size_t)(p * N_ + base + node) * CFN_ + c * 32 + q * 8];
      *(float4*)&featS[node * 104 + 64 + q * 8] = v;
    }
  }
  __syncthreads();

  int rbase = w * 32;   // this wave's node window [rbase, rbase+32)
  const __half* w1g = w1h + (size_t)(p * C_ + c) * 64 * 96;
  const __half* w2g = w2h + (size_t)(p * C_ + c) * 64 * 64;

  // ---- L1: acc[rt][tt] += A(feat) x B(W1) ----
  f32x4 acc[2][4];
  #pragma unroll
  for (int tt = 0; tt < 4; ++tt) {
    float bv = bd1[(p * C_ + c) * FP_ + tt * 16 + l15];
    #pragma unroll
    for (int rt = 0; rt < 2; ++rt) acc[rt][tt] = (f32x4){bv, bv, bv, bv};
  }
  #pragma unroll
  for (int s = 0; s < 3; ++s) {
    f16x8 a0 = ld8(&featS[(rbase + l15) * 104 + s * 32 + l4 * 8]);
    f16x8 a1 = ld8(&featS[(rbase + 16 + l15) * 104 + s * 32 + l4 * 8]);
    #pragma unroll
    for (int tt = 0; tt < 4; ++tt) {
      f16x8 b = ld8(&w1g[(tt * 16 + l15) * 96 + s * 32 + l4 * 8]);
      acc[0][tt] = __builtin_amdgcn_mfma_f32_16x16x32_f16(a0, b, acc[0][tt], 0, 0, 0);
      acc[1][tt] = __builtin_amdgcn_mfma_f32_16x16x32_f16(a1, b, acc[1][tt], 0, 0, 0);
    }
  }
  // tanh -> hS (same-wave rows only; lgkmcnt ordering suffices, no barrier)
  #pragma unroll
  for (int rt = 0; rt < 2; ++rt)
    #pragma unroll
    for (int tt = 0; tt < 4; ++tt) {
      #pragma unroll
      for (int r = 0; r < 4; ++r) {
        int nrow = rbase + rt * 16 + l4 * 4 + r;
        hS[nrow * 72 + tt * 16 + l15] = __float2half(fast_tanh(acc[rt][tt][r]));
      }
    }

  // ---- L2: acc2 += A(hS) x B(W2) ----
  f32x4 acc2[2][4];
  #pragma unroll
  for (int tt = 0; tt < 4; ++tt) {
    float bv = bd2[(p * C_ + c) * FP_ + tt * 16 + l15];
    #pragma unroll
    for (int rt = 0; rt < 2; ++rt) acc2[rt][tt] = (f32x4){bv, bv, bv, bv};
  }
  #pragma unroll
  for (int s = 0; s < 2; ++s) {
    f16x8 a0 = ld8(&hS[(rbase + l15) * 72 + s * 32 + l4 * 8]);
    f16x8 a1 = ld8(&hS[(rbase + 16 + l15) * 72 + s * 32 + l4 * 8]);
    #pragma unroll
    for (int tt = 0; tt < 4; ++tt) {
      f16x8 b = ld8(&w2g[(tt * 16 + l15) * 64 + s * 32 + l4 * 8]);
      acc2[0][tt] = __builtin_amdgcn_mfma_f32_16x16x32_f16(a0, b, acc2[0][tt], 0, 0, 0);
      acc2[1][tt] = __builtin_amdgcn_mfma_f32_16x16x32_f16(a1, b, acc2[1][tt], 0, 0, 0);
    }
  }
  // tanh -> global
  #pragma unroll
  for (int rt = 0; rt < 2; ++rt)
    #pragma unroll
    for (int tt = 0; tt < 4; ++tt) {
      #pragma unroll
      for (int r = 0; r < 4; ++r) {
        int nrow = rbase + rt * 16 + l4 * 4 + r;
        int node = base + nrow;
        if (node < N_) {
          out[(size_t)(p * N_ + node) * 320 + c * 64 + tt * 16 + l15] =
              fast_tanh(acc2[rt][tt][r]);
        }
      }
    }
}

// ====================== launch ======================
// workspace layout (4-byte words):
//   [0, 24M words) : y (half[48M]) during projx/nexus, THEN aggr (half[48M])
#define WS_AGGR  0ll          // half[48,000,000] = 24,000,000 words (also y)
#define WS_NOUT  24000000ll   // float[4,800,000]
#define WS_XDOT  28800000ll   // float[1,500,000]
#define WS_NDOT  30300000ll   // float[450,000]
#define WS_OFFS  30750000ll   // int[300,001]
#define WS_OFFD  31050001ll   // int[90,001]
#define WS_CURS  31140002ll   // int[300,000]
#define WS_CURD  31440002ll   // int[90,000]
#define WS_LISTS 31530002ll   // int[600,000]
#define WS_LISTD 32130002ll   // int[600,000]
#define WS_AUX1  32730002ll   // int[512]
#define WS_AUX2  32730514ll   // int[512]
#define WS_W1H   32731026ll   // half[92,160] = 46,080 words
#define WS_W2H   32777106ll   // half[61,440] = 30,720 words

extern "C" void kernel_launch(void* const* d_in, const int* in_sizes, int n_in,
                              void* d_out, int out_size, void* d_ws, size_t ws_size,
                              hipStream_t stream) {
  const float* x   = (const float*)d_in[0];
  const int* esrc  = (const int*)d_in[2];
  const int* edst  = (const int*)d_in[3];
  const float* Wn1 = (const float*)d_in[4];
  const float* bn1 = (const float*)d_in[5];
  const float* Wn2 = (const float*)d_in[6];
  const float* bn2 = (const float*)d_in[7];
  const float* We  = (const float*)d_in[8];
  const float* be  = (const float*)d_in[9];
  const float* Wd1 = (const float*)d_in[10];
  const float* bd1 = (const float*)d_in[11];
  const float* Wd2 = (const float*)d_in[12];
  const float* bd2 = (const float*)d_in[13];
  float* out = (float*)d_out;

  float* wsf = (float*)d_ws;
  int*   wsi = (int*)d_ws;
  __half* aggr = (__half*)d_ws;      // and y, time-shared
  __half* ybuf = (__half*)d_ws;
  float* nout = wsf + WS_NOUT;
  float* xdot = wsf + WS_XDOT;
  float* ndot = wsf + WS_NDOT;
  int* off_src = wsi + WS_OFFS;
  int* off_dst = wsi + WS_OFFD;
  int* cur_src = wsi + WS_CURS;
  int* cur_dst = wsi + WS_CURD;
  int* list_src = wsi + WS_LISTS;
  int* list_dst = wsi + WS_LISTD;
  int* aux1 = wsi + WS_AUX1;
  int* aux2 = wsi + WS_AUX2;
  __half* w1h = (__half*)(wsi + WS_W1H);
  __half* w2h = (__half*)(wsi + WS_W2H);

  // ---- independent precompute ----
  k_wconv<<<(NW1_ + 255) / 256, 256, 0, stream>>>(Wd1, Wd2, w1h, w2h);

  // ---- CSR build ----
  hipMemsetAsync(cur_src, 0, PN_ * sizeof(int), stream);
  hipMemsetAsync(cur_dst, 0, PM_ * sizeof(int), stream);
  k_count<<<(PE_ + 255) / 256, 256, 0, stream>>>(esrc, edst, cur_src, cur_dst);
  {
    int nb_s = (PN_ + 1023) / 1024;   // 293
    int nb_d = (PM_ + 1023) / 1024;   // 88
    k_scan1<<<nb_s, 256, 0, stream>>>(cur_src, off_src, aux1, PN_);
    k_scan1<<<nb_d, 256, 0, stream>>>(cur_dst, off_dst, aux2, PM_);
    k_scan2<<<1, 1024, 0, stream>>>(aux1, nb_s, off_src + PN_);
    k_scan2<<<1, 1024, 0, stream>>>(aux2, nb_d, off_dst + PM_);
    k_scan3<<<(PN_ + 255) / 256, 256, 0, stream>>>(off_src, aux1, PN_);
    k_scan3<<<(PM_ + 255) / 256, 256, 0, stream>>>(off_dst, aux2, PM_);
  }
  hipMemcpyAsync(cur_src, off_src, PN_ * sizeof(int), hipMemcpyDeviceToDevice, stream);
  hipMemcpyAsync(cur_dst, off_dst, PM_ * sizeof(int), hipMemcpyDeviceToDevice, stream);
  k_fill<<<(PE_ + 255) / 256, 256, 0, stream>>>(esrc, edst, cur_src, cur_dst,
                                                list_src, list_dst);

  // ---- stages ----
  k_projx<<<P_ * TILES_, 320, 0, stream>>>(x, Wn1, We, ybuf, xdot);
  k_nexus<<<M_, 320, 0, stream>>>(ybuf, off_dst, list_dst, bn1, Wn2, bn2, We,
                                  nout, ndot);
  k_aggr<<<(PN_ + 3) / 4, 256, 0, stream>>>(nout, off_src, list_src, xdot, ndot,
                                            be, aggr);
  k_dec<<<P_ * C_ * TILESD_, 128, 0, stream>>>(x, aggr, w1h, bd1, w2h, bd2, out);
}

// Round 12
// 890.710 us; speedup vs baseline: 10.0484x; 1.0803x over previous
//
#include <hip/hip_runtime.h>
#include <hip/hip_fp16.h>

#define P_ 3
#define N_ 100000
#define M_ 30000
#define E_ 200000
#define C_ 5
#define FP_ 64
#define FN_ 32
#define PFP_ 192     // P*FP
#define FPFN_ 96     // FP+FN
#define PE_ 600000   // P*E
#define PN_ 300000   // P*N
#define PM_ 90000    // P*M
#define NT_ 64       // nodes per projx tile
#define TILES_ ((N_ + NT_ - 1) / NT_)     // 1563
#define NTD_ 64      // nodes per decoder tile
#define TILESD_ ((N_ + NTD_ - 1) / NTD_)  // 1563
#define CFN_ 160     // C*FN
#define NW1_ 92160   // 15*64*96
#define NW2_ 61440   // 15*64*64

typedef _Float16 f16x8 __attribute__((ext_vector_type(8)));
typedef float f32x4 __attribute__((ext_vector_type(4)));

__device__ __forceinline__ float fast_tanh(float v) {
  float x = fminf(fmaxf(v, -15.0f), 15.0f);
  float t = __expf(2.0f * x);
  return __fdividef(t - 1.0f, t + 1.0f);
}

__device__ __forceinline__ f16x8 ld8(const __half* p) {
  return *(const f16x8*)(const void*)p;
}

// ====================== CSR build ======================
__global__ void k_count(const int* __restrict__ esrc, const int* __restrict__ edst,
                        int* __restrict__ cnt_src, int* __restrict__ cnt_dst) {
  int i = blockIdx.x * 256 + threadIdx.x;
  if (i >= PE_) return;
  int p = i / E_;
  atomicAdd(&cnt_src[p * N_ + esrc[i]], 1);
  atomicAdd(&cnt_dst[p * M_ + edst[i]], 1);
}

// 3-pass exclusive scan (1024 elems/block)
__global__ void k_scan1(const int* __restrict__ in, int* __restrict__ out,
                        int* __restrict__ aux, int n) {
  __shared__ int lds[256];
  int b = blockIdx.x, t = threadIdx.x;
  int base = b * 1024 + t * 4;
  int v0 = (base + 0 < n) ? in[base + 0] : 0;
  int v1 = (base + 1 < n) ? in[base + 1] : 0;
  int v2 = (base + 2 < n) ? in[base + 2] : 0;
  int v3 = (base + 3 < n) ? in[base + 3] : 0;
  lds[t] = v0 + v1 + v2 + v3;
  __syncthreads();
  for (int off = 1; off < 256; off <<= 1) {
    int xv = (t >= off) ? lds[t - off] : 0;
    __syncthreads();
    lds[t] += xv;
    __syncthreads();
  }
  if (t == 255) aux[b] = lds[255];
  int run = (t == 0) ? 0 : lds[t - 1];
  if (base + 0 < n) out[base + 0] = run; run += v0;
  if (base + 1 < n) out[base + 1] = run; run += v1;
  if (base + 2 < n) out[base + 2] = run; run += v2;
  if (base + 3 < n) out[base + 3] = run;
}

__global__ void k_scan2(int* __restrict__ aux, int nb, int* __restrict__ off_end) {
  __shared__ int lds[1024];
  int t = threadIdx.x;
  lds[t] = (t < nb) ? aux[t] : 0;
  __syncthreads();
  for (int off = 1; off < 1024; off <<= 1) {
    int xv = (t >= off) ? lds[t - off] : 0;
    __syncthreads();
    lds[t] += xv;
    __syncthreads();
  }
  if (t < nb) aux[t] = (t == 0) ? 0 : lds[t - 1];
  if (t == 0) off_end[0] = lds[nb - 1];
}

__global__ void k_scan3(int* __restrict__ out, const int* __restrict__ aux, int n) {
  int i = blockIdx.x * 256 + threadIdx.x;
  if (i < n) out[i] += aux[i >> 10];
}

__global__ void k_fill(const int* __restrict__ esrc, const int* __restrict__ edst,
                       int* __restrict__ cur_src, int* __restrict__ cur_dst,
                       int* __restrict__ list_src, int* __restrict__ list_dst) {
  int i = blockIdx.x * 256 + threadIdx.x;
  if (i >= PE_) return;
  int p = i / E_;
  int s = esrc[i], d = edst[i];
  int ps = atomicAdd(&cur_src[p * N_ + s], 1);
  list_src[ps] = d;
  int pd = atomicAdd(&cur_dst[p * M_ + d], 1);
  list_dst[pd] = s;
}

// ====================== wconv: decoder weights fp32 -> fp16 ====================
__global__ void k_wconv(const float* __restrict__ Wd1, const float* __restrict__ Wd2,
                        __half* __restrict__ w1h, __half* __restrict__ w2h) {
  int i = blockIdx.x * 256 + threadIdx.x;
  if (i < NW1_) w1h[i] = __float2half(Wd1[i]);
  if (i < NW2_) w2h[i] = __float2half(Wd2[i]);
}

// ====================== projx: y = Wn1_p-block . x  (+ fused xdot) =============
__global__ __launch_bounds__(320) void k_projx(
    const float* __restrict__ x, const float* __restrict__ Wn1,
    const float* __restrict__ We,
    __half* __restrict__ y, float* __restrict__ xdot) {
  __shared__ __half xs[NT_ * 320];   // 40 KB
  int bp = blockIdx.x;
  int p = bp / TILES_, tile = bp % TILES_;
  int base = tile * NT_;
  int rows = min(NT_, N_ - base);
  int t = threadIdx.x;
  int g = t / CFN_, u = t % CFN_;
  int c = u >> 5;

  __half2 w[32];
  {
    const float* wr = &Wn1[(size_t)u * PFP_ + p * FP_];
    #pragma unroll
    for (int i = 0; i < 32; ++i) w[i] = __floats2half2_rn(wr[2*i], wr[2*i+1]);
  }

  const float* xb = x + (size_t)(p * N_ + base) * (C_ * FP_);
  int tot = rows * 320;
  for (int f = t * 4; f < tot; f += 320 * 4) {
    float4 v = *(const float4*)(xb + f);
    __half2* dst = (__half2*)&xs[f];
    dst[0] = __floats2half2_rn(v.x, v.y);
    dst[1] = __floats2half2_rn(v.z, v.w);
  }
  __syncthreads();

  for (int r = g; r < rows; r += 2) {
    const __half2* xr = (const __half2*)&xs[r * 320 + c * FP_];
    __half2 acc = __floats2half2_rn(0.f, 0.f);
    #pragma unroll
    for (int i = 0; i < 32; ++i) acc = __hfma2(xr[i], w[i], acc);
    float s = __low2float(acc) + __high2float(acc);
    y[(size_t)(p * N_ + base + r) * CFN_ + u] = __float2half(s);
  }

  // fused xdot: t -> (cx = t>>6, node = t&63)
  {
    int cx = t >> 6, nodex = t & 63;
    if (nodex < rows) {
      const __half2* xr = (const __half2*)&xs[nodex * 320 + cx * FP_];
      const float2* wer = (const float2*)&We[(p * C_ + cx) * FPFN_];
      float s = 0.f;
      #pragma unroll
      for (int i = 0; i < 32; ++i) {
        float2 wv = wer[i];
        __half2 xv = xr[i];
        s += __low2float(xv) * wv.x + __high2float(xv) * wv.y;
      }
      xdot[(size_t)(p * N_ + base + nodex) * C_ + cx] = s;
    }
  }
}

// ====================== nexus: gather y = layer-1 preact; nout stored fp16 =====
__global__ __launch_bounds__(320) void k_nexus(
    const __half* __restrict__ y,
    const int* __restrict__ off_dst, const int* __restrict__ list_dst,
    const float* __restrict__ bn1,
    const float* __restrict__ Wn2, const float* __restrict__ bn2,
    const float* __restrict__ We,
    __half* __restrict__ nout, float* __restrict__ ndot) {
  __shared__ float part[4][CFN_];
  __shared__ __align__(16) float h1S[CFN_];
  __shared__ __align__(16) float h2S[CFN_];
  int m = blockIdx.x;
  int t = threadIdx.x;               // 320 = 4 groups x 80 half2-lanes
  int g = t / 80, u2 = t % 80;

  float afx = 0.f, afy = 0.f;
  #pragma unroll
  for (int p = 0; p < P_; ++p) {
    int o0 = off_dst[p * M_ + m];
    int o1 = off_dst[p * M_ + m + 1];
    const __half2* yp2 = (const __half2*)(y + (size_t)p * N_ * CFN_);
    for (int e0 = o0 + g; e0 < o1; e0 += 8) {   // batch-2 per group
      int e1 = e0 + 4;
      int s0 = list_dst[e0];
      int s1 = list_dst[e1 < o1 ? e1 : e0];
      __half2 v0 = yp2[(size_t)s0 * 80 + u2];
      __half2 v1 = yp2[(size_t)s1 * 80 + u2];
      afx += __low2float(v0); afy += __high2float(v0);
      if (e1 < o1) { afx += __low2float(v1); afy += __high2float(v1); }
    }
  }
  part[g][2 * u2]     = afx;
  part[g][2 * u2 + 1] = afy;
  __syncthreads();
  if (t < CFN_) {
    float pre = part[0][t] + part[1][t] + part[2][t] + part[3][t] + bn1[t];
    h1S[t] = fast_tanh(pre);
  }
  __syncthreads();
  if (t < CFN_) {
    int c = t >> 5;
    const float4* f4 = (const float4*)&h1S[c * FN_];
    const float4* w4 = (const float4*)&Wn2[(size_t)t * FN_];
    float a = bn2[t];
    #pragma unroll
    for (int i = 0; i < FN_ / 4; ++i) {
      float4 f = f4[i], wv = w4[i];
      a += f.x * wv.x + f.y * wv.y + f.z * wv.z + f.w * wv.w;
    }
    float nv = fast_tanh(a);
    h2S[t] = nv;
    nout[(size_t)m * CFN_ + t] = __float2half(nv);
  }
  __syncthreads();
  if (t < P_ * C_) {
    int p = t / C_, cc = t % C_;
    const float* wv = &We[(p * C_ + cc) * FPFN_ + FP_];
    float a = 0.f;
    #pragma unroll
    for (int j = 0; j < FN_; ++j) a += h2S[cc * FN_ + j] * wv[j];
    ndot[(size_t)(p * M_ + m) * C_ + cc] = a;
  }
}

// ====================== MFMA decoder with fused softmax aggregation ============
// block = (p, c, 64-node tile), 128 threads = 2 waves.
// Aggregation: 2 threads/node walk src-CSR, recompute 5-class softmax, gather
// nout fp16 slice, write aggr into featS directly (k_aggr eliminated).
// Fragments: A row=l&15, k=8*(l>>4)+j; B col=l&15, k=8*(l>>4)+j;
//            D col=l&15, row=4*(l>>4)+reg.
__global__ __launch_bounds__(128, 4) void k_dec(
    const float* __restrict__ x,
    const __half* __restrict__ nout, const float* __restrict__ ndot,
    const float* __restrict__ xdot, const float* __restrict__ be,
    const int* __restrict__ off_src, const int* __restrict__ list_src,
    const __half* __restrict__ w1h, const float* __restrict__ bd1,
    const __half* __restrict__ w2h, const float* __restrict__ bd2,
    float* __restrict__ out) {
  __shared__ __half featS[NTD_ * 104];   // 13.3 KB  (96 used: x 64 | aggr 32)
  __shared__ __half hS[NTD_ * 72];       // 9.2 KB   (64 used)

  int bp = blockIdx.x;
  int pc = bp / TILESD_;
  int tile = bp % TILESD_;
  int p = pc / C_, c = pc % C_;
  int base = tile * NTD_;
  int rows = min(NTD_, N_ - base);

  int t = threadIdx.x;
  int w = t >> 6, l = t & 63;
  int l15 = l & 15, l4 = l >> 4;

  // ---- stage x (fp32->fp16) ----
  for (int idx = t; idx < NTD_ * 16; idx += 128) {
    int node = idx >> 4, fq = idx & 15;
    if (node < rows) {
      float4 v = *(const float4*)&x[(size_t)(p * N_ + base + node) * 320 + c * 64 + fq * 4];
      __half2* dst = (__half2*)&featS[node * 104 + fq * 4];
      dst[0] = __floats2half2_rn(v.x, v.y);
      dst[1] = __floats2half2_rn(v.z, v.w);
    }
  }
  // ---- fused aggregation: 2 threads per node, 16 features each ----
  {
    int nd = t >> 1, hf = t & 1;
    if (nd < rows) {
      int pn = p * N_ + base + nd;
      int o0 = off_src[pn], o1 = off_src[pn + 1];
      float base_c[C_];
      #pragma unroll
      for (int cc = 0; cc < C_; ++cc)
        base_c[cc] = xdot[(size_t)pn * C_ + cc] + be[p * C_ + cc];
      float acc[16];
      #pragma unroll
      for (int i = 0; i < 16; ++i) acc[i] = 0.f;
      for (int e = o0; e < o1; ++e) {
        int dst = list_src[e];
        const float* nd5 = &ndot[(size_t)(p * M_ + dst) * C_];
        float lg[C_];
        #pragma unroll
        for (int cc = 0; cc < C_; ++cc) lg[cc] = base_c[cc] + nd5[cc];
        float mx = fmaxf(fmaxf(fmaxf(lg[0], lg[1]), fmaxf(lg[2], lg[3])), lg[4]);
        float s = 0.f;
        #pragma unroll
        for (int cc = 0; cc < C_; ++cc) { lg[cc] = __expf(lg[cc] - mx); s += lg[cc]; }
        float wgt = __fdividef(lg[c], s);
        const __half2* nr = (const __half2*)&nout[(size_t)dst * CFN_ + c * FN_ + hf * 16];
        #pragma unroll
        for (int i = 0; i < 8; ++i) {
          __half2 v = nr[i];
          acc[2 * i]     += wgt * __low2float(v);
          acc[2 * i + 1] += wgt * __high2float(v);
        }
      }
      float invd = __fdividef(1.0f, fmaxf((float)(o1 - o0), 1.0f));
      __half2* dst2 = (__half2*)&featS[nd * 104 + 64 + hf * 16];
      #pragma unroll
      for (int i = 0; i < 8; ++i)
        dst2[i] = __floats2half2_rn(acc[2 * i] * invd, acc[2 * i + 1] * invd);
    }
  }
  __syncthreads();

  int rbase = w * 32;   // this wave's node window [rbase, rbase+32)
  const __half* w1g = w1h + (size_t)(p * C_ + c) * 64 * 96;
  const __half* w2g = w2h + (size_t)(p * C_ + c) * 64 * 64;

  // ---- L1: acc[rt][tt] += A(feat) x B(W1) ----
  f32x4 acc[2][4];
  #pragma unroll
  for (int tt = 0; tt < 4; ++tt) {
    float bv = bd1[(p * C_ + c) * FP_ + tt * 16 + l15];
    #pragma unroll
    for (int rt = 0; rt < 2; ++rt) acc[rt][tt] = (f32x4){bv, bv, bv, bv};
  }
  #pragma unroll
  for (int s = 0; s < 3; ++s) {
    f16x8 a0 = ld8(&featS[(rbase + l15) * 104 + s * 32 + l4 * 8]);
    f16x8 a1 = ld8(&featS[(rbase + 16 + l15) * 104 + s * 32 + l4 * 8]);
    #pragma unroll
    for (int tt = 0; tt < 4; ++tt) {
      f16x8 b = ld8(&w1g[(tt * 16 + l15) * 96 + s * 32 + l4 * 8]);
      acc[0][tt] = __builtin_amdgcn_mfma_f32_16x16x32_f16(a0, b, acc[0][tt], 0, 0, 0);
      acc[1][tt] = __builtin_amdgcn_mfma_f32_16x16x32_f16(a1, b, acc[1][tt], 0, 0, 0);
    }
  }
  // tanh -> hS (same-wave rows only; lgkmcnt ordering suffices, no barrier)
  #pragma unroll
  for (int rt = 0; rt < 2; ++rt)
    #pragma unroll
    for (int tt = 0; tt < 4; ++tt) {
      #pragma unroll
      for (int r = 0; r < 4; ++r) {
        int nrow = rbase + rt * 16 + l4 * 4 + r;
        hS[nrow * 72 + tt * 16 + l15] = __float2half(fast_tanh(acc[rt][tt][r]));
      }
    }

  // ---- L2: acc2 += A(hS) x B(W2) ----
  f32x4 acc2[2][4];
  #pragma unroll
  for (int tt = 0; tt < 4; ++tt) {
    float bv = bd2[(p * C_ + c) * FP_ + tt * 16 + l15];
    #pragma unroll
    for (int rt = 0; rt < 2; ++rt) acc2[rt][tt] = (f32x4){bv, bv, bv, bv};
  }
  #pragma unroll
  for (int s = 0; s < 2; ++s) {
    f16x8 a0 = ld8(&hS[(rbase + l15) * 72 + s * 32 + l4 * 8]);
    f16x8 a1 = ld8(&hS[(rbase + 16 + l15) * 72 + s * 32 + l4 * 8]);
    #pragma unroll
    for (int tt = 0; tt < 4; ++tt) {
      f16x8 b = ld8(&w2g[(tt * 16 + l15) * 64 + s * 32 + l4 * 8]);
      acc2[0][tt] = __builtin_amdgcn_mfma_f32_16x16x32_f16(a0, b, acc2[0][tt], 0, 0, 0);
      acc2[1][tt] = __builtin_amdgcn_mfma_f32_16x16x32_f16(a1, b, acc2[1][tt], 0, 0, 0);
    }
  }
  // tanh -> global
  #pragma unroll
  for (int rt = 0; rt < 2; ++rt)
    #pragma unroll
    for (int tt = 0; tt < 4; ++tt) {
      #pragma unroll
      for (int r = 0; r < 4; ++r) {
        int nrow = rbase + rt * 16 + l4 * 4 + r;
        int node = base + nrow;
        if (node < N_) {
          out[(size_t)(p * N_ + node) * 320 + c * 64 + tt * 16 + l15] =
              fast_tanh(acc2[rt][tt][r]);
        }
      }
    }
}

// ====================== launch ======================
// workspace layout (4-byte words):
//   [0, 24M words) : y (half[48M]) during projx/nexus
#define WS_Y     0ll          // half[48,000,000] = 24,000,000 words
#define WS_NOUT  24000000ll   // half[4,800,000] = 2,400,000 words
#define WS_XDOT  28800000ll   // float[1,500,000]
#define WS_NDOT  30300000ll   // float[450,000]
#define WS_OFFS  30750000ll   // int[300,001]
#define WS_OFFD  31050001ll   // int[90,001]
#define WS_CURS  31140002ll   // int[300,000]
#define WS_CURD  31440002ll   // int[90,000]
#define WS_LISTS 31530002ll   // int[600,000]
#define WS_LISTD 32130002ll   // int[600,000]
#define WS_AUX1  32730002ll   // int[512]
#define WS_AUX2  32730514ll   // int[512]
#define WS_W1H   32731026ll   // half[92,160] = 46,080 words
#define WS_W2H   32777106ll   // half[61,440] = 30,720 words

extern "C" void kernel_launch(void* const* d_in, const int* in_sizes, int n_in,
                              void* d_out, int out_size, void* d_ws, size_t ws_size,
                              hipStream_t stream) {
  const float* x   = (const float*)d_in[0];
  const int* esrc  = (const int*)d_in[2];
  const int* edst  = (const int*)d_in[3];
  const float* Wn1 = (const float*)d_in[4];
  const float* bn1 = (const float*)d_in[5];
  const float* Wn2 = (const float*)d_in[6];
  const float* bn2 = (const float*)d_in[7];
  const float* We  = (const float*)d_in[8];
  const float* be  = (const float*)d_in[9];
  const float* Wd1 = (const float*)d_in[10];
  const float* bd1 = (const float*)d_in[11];
  const float* Wd2 = (const float*)d_in[12];
  const float* bd2 = (const float*)d_in[13];
  float* out = (float*)d_out;

  float* wsf = (float*)d_ws;
  int*   wsi = (int*)d_ws;
  __half* ybuf = (__half*)d_ws;
  __half* nout = (__half*)(wsi + WS_NOUT);
  float* xdot = wsf + WS_XDOT;
  float* ndot = wsf + WS_NDOT;
  int* off_src = wsi + WS_OFFS;
  int* off_dst = wsi + WS_OFFD;
  int* cur_src = wsi + WS_CURS;
  int* cur_dst = wsi + WS_CURD;
  int* list_src = wsi + WS_LISTS;
  int* list_dst = wsi + WS_LISTD;
  int* aux1 = wsi + WS_AUX1;
  int* aux2 = wsi + WS_AUX2;
  __half* w1h = (__half*)(wsi + WS_W1H);
  __half* w2h = (__half*)(wsi + WS_W2H);

  // ---- independent precompute ----
  k_wconv<<<(NW1_ + 255) / 256, 256, 0, stream>>>(Wd1, Wd2, w1h, w2h);

  // ---- CSR build ----
  hipMemsetAsync(cur_src, 0, PN_ * sizeof(int), stream);
  hipMemsetAsync(cur_dst, 0, PM_ * sizeof(int), stream);
  k_count<<<(PE_ + 255) / 256, 256, 0, stream>>>(esrc, edst, cur_src, cur_dst);
  {
    int nb_s = (PN_ + 1023) / 1024;   // 293
    int nb_d = (PM_ + 1023) / 1024;   // 88
    k_scan1<<<nb_s, 256, 0, stream>>>(cur_src, off_src, aux1, PN_);
    k_scan1<<<nb_d, 256, 0, stream>>>(cur_dst, off_dst, aux2, PM_);
    k_scan2<<<1, 1024, 0, stream>>>(aux1, nb_s, off_src + PN_);
    k_scan2<<<1, 1024, 0, stream>>>(aux2, nb_d, off_dst + PM_);
    k_scan3<<<(PN_ + 255) / 256, 256, 0, stream>>>(off_src, aux1, PN_);
    k_scan3<<<(PM_ + 255) / 256, 256, 0, stream>>>(off_dst, aux2, PM_);
  }
  hipMemcpyAsync(cur_src, off_src, PN_ * sizeof(int), hipMemcpyDeviceToDevice, stream);
  hipMemcpyAsync(cur_dst, off_dst, PM_ * sizeof(int), hipMemcpyDeviceToDevice, stream);
  k_fill<<<(PE_ + 255) / 256, 256, 0, stream>>>(esrc, edst, cur_src, cur_dst,
                                                list_src, list_dst);

  // ---- stages ----
  k_projx<<<P_ * TILES_, 320, 0, stream>>>(x, Wn1, We, ybuf, xdot);
  k_nexus<<<M_, 320, 0, stream>>>(ybuf, off_dst, list_dst, bn1, Wn2, bn2, We,
                                  nout, ndot);
  k_dec<<<P_ * C_ * TILESD_, 128, 0, stream>>>(x, nout, ndot, xdot, be,
                                               off_src, list_src,
                                               w1h, bd1, w2h, bd2, out);
}

// Round 13
// 855.157 us; speedup vs baseline: 10.4662x; 1.0416x over previous
//
#include <hip/hip_runtime.h>
#include <hip/hip_fp16.h>

#define P_ 3
#define N_ 100000
#define M_ 30000
#define E_ 200000
#define C_ 5
#define FP_ 64
#define FN_ 32
#define PFP_ 192     // P*FP
#define FPFN_ 96     // FP+FN
#define PE_ 600000   // P*E
#define PN_ 300000   // P*N
#define PM_ 90000    // P*M
#define NT_ 64       // nodes per projx tile
#define TILES_ ((N_ + NT_ - 1) / NT_)     // 1563
#define NTD_ 64      // nodes per decoder tile
#define TILESD_ ((N_ + NTD_ - 1) / NTD_)  // 1563
#define CFN_ 160     // C*FN
#define NW1_ 92160   // 15*64*96
#define NW2_ 61440   // 15*64*64
#define NB_S_ ((PN_ + 1023) / 1024)       // 293
#define NB_D_ ((PM_ + 1023) / 1024)       // 88

typedef _Float16 f16x8 __attribute__((ext_vector_type(8)));
typedef float f32x4 __attribute__((ext_vector_type(4)));

__device__ __forceinline__ float fast_tanh(float v) {
  float x = fminf(fmaxf(v, -15.0f), 15.0f);
  float t = __expf(2.0f * x);
  return __fdividef(t - 1.0f, t + 1.0f);
}

__device__ __forceinline__ f16x8 ld8(const __half* p) {
  return *(const f16x8*)(const void*)p;
}

// ====================== CSR build ======================
__global__ void k_count(const int* __restrict__ esrc, const int* __restrict__ edst,
                        int* __restrict__ cnt_src, int* __restrict__ cnt_dst) {
  int i = blockIdx.x * 256 + threadIdx.x;
  if (i >= PE_) return;
  int p = i / E_;
  atomicAdd(&cnt_src[p * N_ + esrc[i]], 1);
  atomicAdd(&cnt_dst[p * M_ + edst[i]], 1);
}

// combined per-1024-chunk scan for both arrays
__global__ void k_scan1c(const int* __restrict__ in_s, int* __restrict__ out_s,
                         int* __restrict__ aux_s,
                         const int* __restrict__ in_d, int* __restrict__ out_d,
                         int* __restrict__ aux_d) {
  __shared__ int lds[256];
  int b = blockIdx.x, t = threadIdx.x;
  const int* in;
  int* out;
  int* aux;
  int n;
  if (b < NB_S_) { in = in_s; out = out_s; aux = aux_s; n = PN_; }
  else           { b -= NB_S_; in = in_d; out = out_d; aux = aux_d; n = PM_; }
  int base = b * 1024 + t * 4;
  int v0 = (base + 0 < n) ? in[base + 0] : 0;
  int v1 = (base + 1 < n) ? in[base + 1] : 0;
  int v2 = (base + 2 < n) ? in[base + 2] : 0;
  int v3 = (base + 3 < n) ? in[base + 3] : 0;
  lds[t] = v0 + v1 + v2 + v3;
  __syncthreads();
  for (int off = 1; off < 256; off <<= 1) {
    int xv = (t >= off) ? lds[t - off] : 0;
    __syncthreads();
    lds[t] += xv;
    __syncthreads();
  }
  if (t == 255) aux[b] = lds[255];
  int run = (t == 0) ? 0 : lds[t - 1];
  if (base + 0 < n) out[base + 0] = run; run += v0;
  if (base + 1 < n) out[base + 1] = run; run += v1;
  if (base + 2 < n) out[base + 2] = run; run += v2;
  if (base + 3 < n) out[base + 3] = run;
}

// combined aux scan: block 0 -> aux_s, block 1 -> aux_d
__global__ void k_scan2c(int* __restrict__ aux_s, int* __restrict__ end_s,
                         int* __restrict__ aux_d, int* __restrict__ end_d) {
  __shared__ int lds[1024];
  int t = threadIdx.x;
  int* aux = (blockIdx.x == 0) ? aux_s : aux_d;
  int* offe = (blockIdx.x == 0) ? end_s : end_d;
  int nb = (blockIdx.x == 0) ? NB_S_ : NB_D_;
  lds[t] = (t < nb) ? aux[t] : 0;
  __syncthreads();
  for (int off = 1; off < 1024; off <<= 1) {
    int xv = (t >= off) ? lds[t - off] : 0;
    __syncthreads();
    lds[t] += xv;
    __syncthreads();
  }
  if (t < nb) aux[t] = (t == 0) ? 0 : lds[t - 1];
  if (t == 0) offe[0] = lds[nb - 1];
}

// combined add-aux + cursor init (replaces 2x scan3 + 2x memcpy)
__global__ void k_scan3c(int* __restrict__ off_s, const int* __restrict__ aux_s,
                         int* __restrict__ cur_s,
                         int* __restrict__ off_d, const int* __restrict__ aux_d,
                         int* __restrict__ cur_d) {
  int i = blockIdx.x * 256 + threadIdx.x;
  if (i < PN_) {
    int v = off_s[i] + aux_s[i >> 10];
    off_s[i] = v;
    cur_s[i] = v;
  } else if (i < PN_ + PM_) {
    int j = i - PN_;
    int v = off_d[j] + aux_d[j >> 10];
    off_d[j] = v;
    cur_d[j] = v;
  }
}

__global__ void k_fill(const int* __restrict__ esrc, const int* __restrict__ edst,
                       int* __restrict__ cur_src, int* __restrict__ cur_dst,
                       int* __restrict__ list_src, int* __restrict__ list_dst) {
  int i = blockIdx.x * 256 + threadIdx.x;
  if (i >= PE_) return;
  int p = i / E_;
  int s = esrc[i], d = edst[i];
  int ps = atomicAdd(&cur_src[p * N_ + s], 1);
  list_src[ps] = d;
  int pd = atomicAdd(&cur_dst[p * M_ + d], 1);
  list_dst[pd] = s;
}

// ====================== wconv: decoder weights fp32 -> fp16 ====================
__global__ void k_wconv(const float* __restrict__ Wd1, const float* __restrict__ Wd2,
                        __half* __restrict__ w1h, __half* __restrict__ w2h) {
  int i = blockIdx.x * 256 + threadIdx.x;
  if (i < NW1_) w1h[i] = __float2half(Wd1[i]);
  if (i < NW2_) w2h[i] = __float2half(Wd2[i]);
}

// ====================== projx: y = Wn1_p-block . x  (+ fused xdot) =============
__global__ __launch_bounds__(320) void k_projx(
    const float* __restrict__ x, const float* __restrict__ Wn1,
    const float* __restrict__ We,
    __half* __restrict__ y, float* __restrict__ xdot) {
  __shared__ __half xs[NT_ * 320];   // 40 KB
  int bp = blockIdx.x;
  int p = bp / TILES_, tile = bp % TILES_;
  int base = tile * NT_;
  int rows = min(NT_, N_ - base);
  int t = threadIdx.x;
  int g = t / CFN_, u = t % CFN_;
  int c = u >> 5;

  __half2 w[32];
  {
    const float* wr = &Wn1[(size_t)u * PFP_ + p * FP_];
    #pragma unroll
    for (int i = 0; i < 32; ++i) w[i] = __floats2half2_rn(wr[2*i], wr[2*i+1]);
  }

  const float* xb = x + (size_t)(p * N_ + base) * (C_ * FP_);
  int tot = rows * 320;
  for (int f = t * 4; f < tot; f += 320 * 4) {
    float4 v = *(const float4*)(xb + f);
    __half2* dst = (__half2*)&xs[f];
    dst[0] = __floats2half2_rn(v.x, v.y);
    dst[1] = __floats2half2_rn(v.z, v.w);
  }
  __syncthreads();

  for (int r = g; r < rows; r += 2) {
    const __half2* xr = (const __half2*)&xs[r * 320 + c * FP_];
    __half2 acc = __floats2half2_rn(0.f, 0.f);
    #pragma unroll
    for (int i = 0; i < 32; ++i) acc = __hfma2(xr[i], w[i], acc);
    float s = __low2float(acc) + __high2float(acc);
    y[(size_t)(p * N_ + base + r) * CFN_ + u] = __float2half(s);
  }

  // fused xdot: t -> (cx = t>>6, node = t&63)
  {
    int cx = t >> 6, nodex = t & 63;
    if (nodex < rows) {
      const __half2* xr = (const __half2*)&xs[nodex * 320 + cx * FP_];
      const float2* wer = (const float2*)&We[(p * C_ + cx) * FPFN_];
      float s = 0.f;
      #pragma unroll
      for (int i = 0; i < 32; ++i) {
        float2 wv = wer[i];
        __half2 xv = xr[i];
        s += __low2float(xv) * wv.x + __high2float(xv) * wv.y;
      }
      xdot[(size_t)(p * N_ + base + nodex) * C_ + cx] = s;
    }
  }
}

// ====================== nexus: gather y = layer-1 preact; nout stored fp16 =====
__global__ __launch_bounds__(320) void k_nexus(
    const __half* __restrict__ y,
    const int* __restrict__ off_dst, const int* __restrict__ list_dst,
    const float* __restrict__ bn1,
    const float* __restrict__ Wn2, const float* __restrict__ bn2,
    const float* __restrict__ We,
    __half* __restrict__ nout, float* __restrict__ ndot) {
  __shared__ float part[4][CFN_];
  __shared__ __align__(16) float h1S[CFN_];
  __shared__ __align__(16) float h2S[CFN_];
  int m = blockIdx.x;
  int t = threadIdx.x;               // 320 = 4 groups x 80 half2-lanes
  int g = t / 80, u2 = t % 80;

  float afx = 0.f, afy = 0.f;
  #pragma unroll
  for (int p = 0; p < P_; ++p) {
    int o0 = off_dst[p * M_ + m];
    int o1 = off_dst[p * M_ + m + 1];
    const __half2* yp2 = (const __half2*)(y + (size_t)p * N_ * CFN_);
    for (int e0 = o0 + g; e0 < o1; e0 += 8) {   // batch-2 per group
      int e1 = e0 + 4;
      int s0 = list_dst[e0];
      int s1 = list_dst[e1 < o1 ? e1 : e0];
      __half2 v0 = yp2[(size_t)s0 * 80 + u2];
      __half2 v1 = yp2[(size_t)s1 * 80 + u2];
      afx += __low2float(v0); afy += __high2float(v0);
      if (e1 < o1) { afx += __low2float(v1); afy += __high2float(v1); }
    }
  }
  part[g][2 * u2]     = afx;
  part[g][2 * u2 + 1] = afy;
  __syncthreads();
  if (t < CFN_) {
    float pre = part[0][t] + part[1][t] + part[2][t] + part[3][t] + bn1[t];
    h1S[t] = fast_tanh(pre);
  }
  __syncthreads();
  if (t < CFN_) {
    int c = t >> 5;
    const float4* f4 = (const float4*)&h1S[c * FN_];
    const float4* w4 = (const float4*)&Wn2[(size_t)t * FN_];
    float a = bn2[t];
    #pragma unroll
    for (int i = 0; i < FN_ / 4; ++i) {
      float4 f = f4[i], wv = w4[i];
      a += f.x * wv.x + f.y * wv.y + f.z * wv.z + f.w * wv.w;
    }
    float nv = fast_tanh(a);
    h2S[t] = nv;
    nout[(size_t)m * CFN_ + t] = __float2half(nv);
  }
  __syncthreads();
  if (t < P_ * C_) {
    int p = t / C_, cc = t % C_;
    const float* wv = &We[(p * C_ + cc) * FPFN_ + FP_];
    float a = 0.f;
    #pragma unroll
    for (int j = 0; j < FN_; ++j) a += h2S[cc * FN_ + j] * wv[j];
    ndot[(size_t)(p * M_ + m) * C_ + cc] = a;
  }
}

// ====================== MFMA decoder, fused aggregation, hS-in-featS overlay ===
// block = (p, c, 64-node tile), 128 threads = 2 waves. LDS = featS only (13.3KB).
// After a wave's L1 MFMAs consume its featS rows, tanh(h) is written back into
// the SAME per-wave 32-row window (cols 0..63) — no cross-wave overlap, and
// same-wave ds-op program ordering makes it barrier-free.
// Fragments: A row=l&15, k=8*(l>>4)+j; B col=l&15, k=8*(l>>4)+j;
//            D col=l&15, row=4*(l>>4)+reg.
__global__ __launch_bounds__(128, 8) void k_dec(
    const float* __restrict__ x,
    const __half* __restrict__ nout, const float* __restrict__ ndot,
    const float* __restrict__ xdot, const float* __restrict__ be,
    const int* __restrict__ off_src, const int* __restrict__ list_src,
    const __half* __restrict__ w1h, const float* __restrict__ bd1,
    const __half* __restrict__ w2h, const float* __restrict__ bd2,
    float* __restrict__ out) {
  __shared__ __half featS[NTD_ * 104];   // 13.3 KB (x:0..63 | aggr:64..95; h overlays 0..63)

  int bp = blockIdx.x;
  int pc = bp / TILESD_;
  int tile = bp % TILESD_;
  int p = pc / C_, c = pc % C_;
  int base = tile * NTD_;
  int rows = min(NTD_, N_ - base);

  int t = threadIdx.x;
  int w = t >> 6, l = t & 63;
  int l15 = l & 15, l4 = l >> 4;

  // ---- stage x (fp32->fp16) ----
  for (int idx = t; idx < NTD_ * 16; idx += 128) {
    int node = idx >> 4, fq = idx & 15;
    if (node < rows) {
      float4 v = *(const float4*)&x[(size_t)(p * N_ + base + node) * 320 + c * 64 + fq * 4];
      __half2* dst = (__half2*)&featS[node * 104 + fq * 4];
      dst[0] = __floats2half2_rn(v.x, v.y);
      dst[1] = __floats2half2_rn(v.z, v.w);
    }
  }
  // ---- fused aggregation: 2 threads per node, 16 features each ----
  {
    int nd = t >> 1, hf = t & 1;
    if (nd < rows) {
      int pn = p * N_ + base + nd;
      int o0 = off_src[pn], o1 = off_src[pn + 1];
      float base_c[C_];
      #pragma unroll
      for (int cc = 0; cc < C_; ++cc)
        base_c[cc] = xdot[(size_t)pn * C_ + cc] + be[p * C_ + cc];
      float acc[16];
      #pragma unroll
      for (int i = 0; i < 16; ++i) acc[i] = 0.f;
      for (int e = o0; e < o1; ++e) {
        int dst = list_src[e];
        const float* nd5 = &ndot[(size_t)(p * M_ + dst) * C_];
        float lg[C_];
        #pragma unroll
        for (int cc = 0; cc < C_; ++cc) lg[cc] = base_c[cc] + nd5[cc];
        float mx = fmaxf(fmaxf(fmaxf(lg[0], lg[1]), fmaxf(lg[2], lg[3])), lg[4]);
        float s = 0.f;
        #pragma unroll
        for (int cc = 0; cc < C_; ++cc) { lg[cc] = __expf(lg[cc] - mx); s += lg[cc]; }
        float wgt = __fdividef(lg[c], s);
        const __half2* nr = (const __half2*)&nout[(size_t)dst * CFN_ + c * FN_ + hf * 16];
        #pragma unroll
        for (int i = 0; i < 8; ++i) {
          __half2 v = nr[i];
          acc[2 * i]     += wgt * __low2float(v);
          acc[2 * i + 1] += wgt * __high2float(v);
        }
      }
      float invd = __fdividef(1.0f, fmaxf((float)(o1 - o0), 1.0f));
      __half2* dst2 = (__half2*)&featS[nd * 104 + 64 + hf * 16];
      #pragma unroll
      for (int i = 0; i < 8; ++i)
        dst2[i] = __floats2half2_rn(acc[2 * i] * invd, acc[2 * i + 1] * invd);
    }
  }
  __syncthreads();

  int rbase = w * 32;   // this wave's node window [rbase, rbase+32)
  const __half* w1g = w1h + (size_t)(p * C_ + c) * 64 * 96;
  const __half* w2g = w2h + (size_t)(p * C_ + c) * 64 * 64;

  // ---- L1: acc[rt][tt] += A(feat) x B(W1) ----
  f32x4 acc[2][4];
  #pragma unroll
  for (int tt = 0; tt < 4; ++tt) {
    float bv = bd1[(p * C_ + c) * FP_ + tt * 16 + l15];
    #pragma unroll
    for (int rt = 0; rt < 2; ++rt) acc[rt][tt] = (f32x4){bv, bv, bv, bv};
  }
  #pragma unroll
  for (int s = 0; s < 3; ++s) {
    f16x8 a0 = ld8(&featS[(rbase + l15) * 104 + s * 32 + l4 * 8]);
    f16x8 a1 = ld8(&featS[(rbase + 16 + l15) * 104 + s * 32 + l4 * 8]);
    #pragma unroll
    for (int tt = 0; tt < 4; ++tt) {
      f16x8 b = ld8(&w1g[(tt * 16 + l15) * 96 + s * 32 + l4 * 8]);
      acc[0][tt] = __builtin_amdgcn_mfma_f32_16x16x32_f16(a0, b, acc[0][tt], 0, 0, 0);
      acc[1][tt] = __builtin_amdgcn_mfma_f32_16x16x32_f16(a1, b, acc[1][tt], 0, 0, 0);
    }
  }
  // tanh -> h overlaid into featS cols 0..63 (same-wave rows only)
  #pragma unroll
  for (int rt = 0; rt < 2; ++rt)
    #pragma unroll
    for (int tt = 0; tt < 4; ++tt) {
      #pragma unroll
      for (int r = 0; r < 4; ++r) {
        int nrow = rbase + rt * 16 + l4 * 4 + r;
        featS[nrow * 104 + tt * 16 + l15] = __float2half(fast_tanh(acc[rt][tt][r]));
      }
    }

  // ---- L2: acc2 += A(h in featS) x B(W2) ----
  f32x4 acc2[2][4];
  #pragma unroll
  for (int tt = 0; tt < 4; ++tt) {
    float bv = bd2[(p * C_ + c) * FP_ + tt * 16 + l15];
    #pragma unroll
    for (int rt = 0; rt < 2; ++rt) acc2[rt][tt] = (f32x4){bv, bv, bv, bv};
  }
  #pragma unroll
  for (int s = 0; s < 2; ++s) {
    f16x8 a0 = ld8(&featS[(rbase + l15) * 104 + s * 32 + l4 * 8]);
    f16x8 a1 = ld8(&featS[(rbase + 16 + l15) * 104 + s * 32 + l4 * 8]);
    #pragma unroll
    for (int tt = 0; tt < 4; ++tt) {
      f16x8 b = ld8(&w2g[(tt * 16 + l15) * 64 + s * 32 + l4 * 8]);
      acc2[0][tt] = __builtin_amdgcn_mfma_f32_16x16x32_f16(a0, b, acc2[0][tt], 0, 0, 0);
      acc2[1][tt] = __builtin_amdgcn_mfma_f32_16x16x32_f16(a1, b, acc2[1][tt], 0, 0, 0);
    }
  }
  // tanh -> global
  #pragma unroll
  for (int rt = 0; rt < 2; ++rt)
    #pragma unroll
    for (int tt = 0; tt < 4; ++tt) {
      #pragma unroll
      for (int r = 0; r < 4; ++r) {
        int nrow = rbase + rt * 16 + l4 * 4 + r;
        int node = base + nrow;
        if (node < N_) {
          out[(size_t)(p * N_ + node) * 320 + c * 64 + tt * 16 + l15] =
              fast_tanh(acc2[rt][tt][r]);
        }
      }
    }
}

// ====================== launch ======================
// workspace layout (4-byte words):
#define WS_Y     0ll          // half[48,000,000] = 24,000,000 words
#define WS_NOUT  24000000ll   // half[4,800,000] = 2,400,000 words
#define WS_XDOT  28800000ll   // float[1,500,000]
#define WS_NDOT  30300000ll   // float[450,000]
#define WS_OFFS  30750000ll   // int[300,001]
#define WS_OFFD  31050001ll   // int[90,001]
#define WS_CURS  31140002ll   // int[300,000]
#define WS_CURD  31440002ll   // int[90,000]  (contiguous with CURS)
#define WS_LISTS 31530002ll   // int[600,000]
#define WS_LISTD 32130002ll   // int[600,000]
#define WS_AUX1  32730002ll   // int[512]
#define WS_AUX2  32730514ll   // int[512]
#define WS_W1H   32731026ll   // half[92,160] = 46,080 words
#define WS_W2H   32777106ll   // half[61,440] = 30,720 words

extern "C" void kernel_launch(void* const* d_in, const int* in_sizes, int n_in,
                              void* d_out, int out_size, void* d_ws, size_t ws_size,
                              hipStream_t stream) {
  const float* x   = (const float*)d_in[0];
  const int* esrc  = (const int*)d_in[2];
  const int* edst  = (const int*)d_in[3];
  const float* Wn1 = (const float*)d_in[4];
  const float* bn1 = (const float*)d_in[5];
  const float* Wn2 = (const float*)d_in[6];
  const float* bn2 = (const float*)d_in[7];
  const float* We  = (const float*)d_in[8];
  const float* be  = (const float*)d_in[9];
  const float* Wd1 = (const float*)d_in[10];
  const float* bd1 = (const float*)d_in[11];
  const float* Wd2 = (const float*)d_in[12];
  const float* bd2 = (const float*)d_in[13];
  float* out = (float*)d_out;

  float* wsf = (float*)d_ws;
  int*   wsi = (int*)d_ws;
  __half* ybuf = (__half*)d_ws;
  __half* nout = (__half*)(wsi + WS_NOUT);
  float* xdot = wsf + WS_XDOT;
  float* ndot = wsf + WS_NDOT;
  int* off_src = wsi + WS_OFFS;
  int* off_dst = wsi + WS_OFFD;
  int* cur_src = wsi + WS_CURS;
  int* cur_dst = wsi + WS_CURD;
  int* list_src = wsi + WS_LISTS;
  int* list_dst = wsi + WS_LISTD;
  int* aux1 = wsi + WS_AUX1;
  int* aux2 = wsi + WS_AUX2;
  __half* w1h = (__half*)(wsi + WS_W1H);
  __half* w2h = (__half*)(wsi + WS_W2H);

  // ---- independent precompute ----
  k_wconv<<<(NW1_ + 255) / 256, 256, 0, stream>>>(Wd1, Wd2, w1h, w2h);

  // ---- CSR build (consolidated) ----
  hipMemsetAsync(cur_src, 0, (PN_ + PM_) * sizeof(int), stream);  // cur_src+cur_dst contiguous
  k_count<<<(PE_ + 255) / 256, 256, 0, stream>>>(esrc, edst, cur_src, cur_dst);
  k_scan1c<<<NB_S_ + NB_D_, 256, 0, stream>>>(cur_src, off_src, aux1,
                                              cur_dst, off_dst, aux2);
  k_scan2c<<<2, 1024, 0, stream>>>(aux1, off_src + PN_, aux2, off_dst + PM_);
  k_scan3c<<<(PN_ + PM_ + 255) / 256, 256, 0, stream>>>(off_src, aux1, cur_src,
                                                        off_dst, aux2, cur_dst);
  k_fill<<<(PE_ + 255) / 256, 256, 0, stream>>>(esrc, edst, cur_src, cur_dst,
                                                list_src, list_dst);

  // ---- stages ----
  k_projx<<<P_ * TILES_, 320, 0, stream>>>(x, Wn1, We, ybuf, xdot);
  k_nexus<<<M_, 320, 0, stream>>>(ybuf, off_dst, list_dst, bn1, Wn2, bn2, We,
                                  nout, ndot);
  k_dec<<<P_ * C_ * TILESD_, 128, 0, stream>>>(x, nout, ndot, xdot, be,
                                               off_src, list_src,
                                               w1h, bd1, w2h, bd2, out);
}